// Round 9
// baseline (660.578 us; speedup 1.0000x reference)
//
#include <hip/hip_runtime.h>
#include <cstdint>
#include <cstddef>

#define NN 262144
#define EE 2097152
#define BB 64
#define CCROSS 32
#define PCC 128
#define PP 2048
#define NBUCK 256
#define BCAP 12288

typedef _Float16 f16;
typedef __attribute__((ext_vector_type(4))) _Float16 f16x4;
typedef __attribute__((ext_vector_type(8))) _Float16 f16x8;

static __device__ __forceinline__ float lrelu(float x, float s) { return x > 0.f ? x : s * x; }

// ---------------- bucketed CSR build ----------------
__global__ __launch_bounds__(256) void bucket_a_k(const int* __restrict__ src, const int* __restrict__ dst,
                                                  unsigned* __restrict__ buckets, int* __restrict__ gcnt) {
    __shared__ int hist[NBUCK];
    __shared__ int base[NBUCK];
    __shared__ unsigned short rankbuf[8192];
    const int tid = threadIdx.x;
    const int e0 = blockIdx.x * 8192;
    hist[tid] = 0;
    __syncthreads();
    for (int i = tid; i < 8192; i += 256) {
        int d = dst[e0 + i];
        rankbuf[i] = (unsigned short)atomicAdd(&hist[d >> 10], 1);
    }
    __syncthreads();
    base[tid] = tid * BCAP + atomicAdd(&gcnt[tid], hist[tid]);
    __syncthreads();
    for (int i = tid; i < 8192; i += 256) {
        int s = src[e0 + i];
        int d = dst[e0 + i];
        int b = d >> 10;
        buckets[base[b] + rankbuf[i]] = ((unsigned)s << 10) | (unsigned)(d & 1023);
    }
}

__global__ void bucket_scan_k(const int* __restrict__ gcnt, int* __restrict__ bbase, int* __restrict__ rp) {
    __shared__ int tmp[256];
    int tid = threadIdx.x;
    int v = gcnt[tid];
    tmp[tid] = v;
    __syncthreads();
    for (int off = 1; off < 256; off <<= 1) {
        int t = (tid >= off) ? tmp[tid - off] : 0;
        __syncthreads();
        tmp[tid] += t;
        __syncthreads();
    }
    bbase[tid] = tmp[tid] - v;
    if (tid == 0) rp[NN] = EE;
}

__global__ __launch_bounds__(256) void bucket_b_k(const unsigned* __restrict__ buckets, const int* __restrict__ gcnt,
                                                  const int* __restrict__ bbase, int* __restrict__ rp,
                                                  float* __restrict__ dinv, int* __restrict__ col) {
    __shared__ int cnt[1024];
    __shared__ int scan[1024];
    __shared__ int wsum[256];
    const int b = blockIdx.x;
    const int tid = threadIdx.x;
    int n = gcnt[b];
    if (n > BCAP) n = BCAP;
    const unsigned* eb = buckets + (size_t)b * BCAP;
    const int gb = bbase[b];
    for (int i = tid; i < 1024; i += 256) cnt[i] = 0;
    __syncthreads();
    for (int i = tid; i < n; i += 256) atomicAdd(&cnt[eb[i] & 1023], 1);
    __syncthreads();
    int b4 = tid * 4;
    int c0 = cnt[b4], c1 = cnt[b4 + 1], c2 = cnt[b4 + 2], c3 = cnt[b4 + 3];
    int tsum = c0 + c1 + c2 + c3;
    wsum[tid] = tsum;
    __syncthreads();
    for (int off = 1; off < 256; off <<= 1) {
        int t = (tid >= off) ? wsum[tid - off] : 0;
        __syncthreads();
        wsum[tid] += t;
        __syncthreads();
    }
    int excl = wsum[tid] - tsum;
    scan[b4] = excl;
    scan[b4 + 1] = excl + c0;
    scan[b4 + 2] = excl + c0 + c1;
    scan[b4 + 3] = excl + c0 + c1 + c2;
    int vbase = b * 1024 + b4;
    rp[vbase + 0] = gb + scan[b4 + 0];
    rp[vbase + 1] = gb + scan[b4 + 1];
    rp[vbase + 2] = gb + scan[b4 + 2];
    rp[vbase + 3] = gb + scan[b4 + 3];
    dinv[vbase + 0] = rsqrtf((float)(c0 + 1));
    dinv[vbase + 1] = rsqrtf((float)(c1 + 1));
    dinv[vbase + 2] = rsqrtf((float)(c2 + 1));
    dinv[vbase + 3] = rsqrtf((float)(c3 + 1));
    __syncthreads();
    for (int i = tid; i < 1024; i += 256) cnt[i] = 0;
    __syncthreads();
    for (int i = tid; i < n; i += 256) {
        unsigned p = eb[i];
        int dl = p & 1023;
        int r = atomicAdd(&cnt[dl], 1);
        col[gb + scan[dl] + r] = (int)(p >> 10);
    }
}

// ---------------- z-prep: z1[v] = dinv[v]*x[v] fp16, padded 19 -> 32 halfs ----------------
__global__ void zprep_k(const float* __restrict__ x, const float* __restrict__ dinv, f16* __restrict__ z) {
    int v = blockIdx.x * 256 + threadIdx.x;
    if (v >= NN) return;
    float dv = dinv[v];
    const float* xr = x + (size_t)v * 19;
    float vv[20];
#pragma unroll
    for (int k = 0; k < 19; k++) vv[k] = dv * xr[k];
    vv[19] = 0.f;
    f16x4* zr = (f16x4*)(z + (size_t)v * 32);
#pragma unroll
    for (int c = 0; c < 5; c++) {
        f16x4 t = {(f16)vv[4 * c], (f16)vv[4 * c + 1], (f16)vv[4 * c + 2], (f16)vv[4 * c + 3]};
        zr[c] = t;
    }
    f16x4 zz = {(f16)0.f, (f16)0.f, (f16)0.f, (f16)0.f};
#pragma unroll
    for (int c = 5; c < 8; c++) zr[c] = zz;
}

// ---------------- fused agg (64B fp16 rows) + gemm ----------------
// 32 rows/block; phase1: 8 lanes/row gather -> zrow LDS (stride 36: bank = (4r+k)%32, conflict-free);
// phase2: 8 thr/row, KOUT/8 outs each.
#define ZSTR1 36
template <int KINR, int KOUT, int ACT>
__global__ __launch_bounds__(256) void fused_agg_gemm_k(const f16* __restrict__ z, const int* __restrict__ rp,
                                                        const int* __restrict__ col, const float* __restrict__ Wg,
                                                        const float* __restrict__ dinv, const float* __restrict__ bias,
                                                        f16* __restrict__ zout) {
    constexpr int NO = KOUT / 8;
    __shared__ float Wl[32 * KOUT];
    __shared__ float zrow[32 * ZSTR1];
    const int tid = threadIdx.x;
    for (int i = tid; i < 32 * KOUT; i += 256) Wl[i] = (i < KINR * KOUT) ? Wg[i] : 0.f;

    const int r = tid >> 3;
    const int idx = tid & 7;
    const int v = blockIdx.x * 32 + r;
    const f16x4* z4 = (const f16x4*)z;
    f16x4 a = z4[(size_t)v * 8 + idx];
    float ax = (float)a.x, ay = (float)a.y, az = (float)a.z, aw = (float)a.w;
    int st = rp[v], e = rp[v + 1];
    int i = st;
    for (; i + 4 <= e; i += 4) {
        int u0 = col[i], u1 = col[i + 1], u2 = col[i + 2], u3 = col[i + 3];
        f16x4 a0 = z4[(size_t)u0 * 8 + idx];
        f16x4 a1 = z4[(size_t)u1 * 8 + idx];
        f16x4 a2 = z4[(size_t)u2 * 8 + idx];
        f16x4 a3 = z4[(size_t)u3 * 8 + idx];
        ax += ((float)a0.x + (float)a1.x) + ((float)a2.x + (float)a3.x);
        ay += ((float)a0.y + (float)a1.y) + ((float)a2.y + (float)a3.y);
        az += ((float)a0.z + (float)a1.z) + ((float)a2.z + (float)a3.z);
        aw += ((float)a0.w + (float)a1.w) + ((float)a2.w + (float)a3.w);
    }
    for (; i < e; i++) {
        f16x4 aa = z4[(size_t)col[i] * 8 + idx];
        ax += (float)aa.x; ay += (float)aa.y; az += (float)aa.z; aw += (float)aa.w;
    }
    float4 s; s.x = ax; s.y = ay; s.z = az; s.w = aw;
    *(float4*)&zrow[r * ZSTR1 + idx * 4] = s;
    __syncthreads();

    // phase 2: 8 threads/row, NO outs each
    float acc[NO];
#pragma unroll
    for (int j = 0; j < NO; j++) acc[j] = 0.f;
#pragma unroll 4
    for (int k = 0; k < 32; k++) {
        float zv = zrow[r * ZSTR1 + k];
        const float* wr = Wl + k * KOUT + NO * idx;
#pragma unroll
        for (int j = 0; j < NO; j++) acc[j] = fmaf(zv, wr[j], acc[j]);
    }
    float dv = dinv[v];
    f16 hv[NO];
#pragma unroll
    for (int j = 0; j < NO; j++) {
        float o = dv * acc[j] + bias[NO * idx + j];
        o = (ACT == 0) ? fmaxf(o, 0.f) : lrelu(o, 0.01f);
        hv[j] = (f16)(o * dv);
    }
    if constexpr (NO == 4) {
        f16x4 h = {hv[0], hv[1], hv[2], hv[3]};
        *(f16x4*)(zout + (size_t)v * KOUT + NO * idx) = h;
    } else {
        f16x8 h = {hv[0], hv[1], hv[2], hv[3], hv[4], hv[5], hv[6], hv[7]};
        *(f16x8*)(zout + (size_t)v * KOUT + NO * idx) = h;
    }
}

// ---------------- fused agg (128B rows) + gemm W3 + gat gemm Wg1 + es/ed dots ----------------
// 16 rows/block; 16 lanes/row; zrow/hrow stride 68: bank = (4r+k)%32, conflict-free.
#define ZSTR2 68
__global__ __launch_bounds__(256) void fused_agg_gemm_gat_k(const f16* __restrict__ z, const int* __restrict__ rp,
                                                            const int* __restrict__ col, const float* __restrict__ W3,
                                                            const float* __restrict__ dinv, const float* __restrict__ b3,
                                                            const float* __restrict__ Wg1, const float* __restrict__ av,
                                                            const float* __restrict__ ad, f16* __restrict__ xw,
                                                            float* __restrict__ es, float* __restrict__ ed) {
    __shared__ float W3l[64 * 64];
    __shared__ float Wgl[64 * 64];
    __shared__ float zrow[16 * ZSTR2];
    __shared__ float hrow[16 * ZSTR2];
    const int tid = threadIdx.x;
    for (int i = tid; i < 4096; i += 256) { W3l[i] = W3[i]; Wgl[i] = Wg1[i]; }

    const int r = tid >> 4;
    const int idx = tid & 15;
    const int v = blockIdx.x * 16 + r;
    const f16x4* z4 = (const f16x4*)z;
    f16x4 a = z4[(size_t)v * 16 + idx];
    float ax = (float)a.x, ay = (float)a.y, az = (float)a.z, aw = (float)a.w;
    int st = rp[v], e = rp[v + 1];
    int i = st;
    for (; i + 4 <= e; i += 4) {
        int u0 = col[i], u1 = col[i + 1], u2 = col[i + 2], u3 = col[i + 3];
        f16x4 a0 = z4[(size_t)u0 * 16 + idx];
        f16x4 a1 = z4[(size_t)u1 * 16 + idx];
        f16x4 a2 = z4[(size_t)u2 * 16 + idx];
        f16x4 a3 = z4[(size_t)u3 * 16 + idx];
        ax += ((float)a0.x + (float)a1.x) + ((float)a2.x + (float)a3.x);
        ay += ((float)a0.y + (float)a1.y) + ((float)a2.y + (float)a3.y);
        az += ((float)a0.z + (float)a1.z) + ((float)a2.z + (float)a3.z);
        aw += ((float)a0.w + (float)a1.w) + ((float)a2.w + (float)a3.w);
    }
    for (; i < e; i++) {
        f16x4 aa = z4[(size_t)col[i] * 16 + idx];
        ax += (float)aa.x; ay += (float)aa.y; az += (float)aa.z; aw += (float)aa.w;
    }
    float4 s; s.x = ax; s.y = ay; s.z = az; s.w = aw;
    *(float4*)&zrow[r * ZSTR2 + idx * 4] = s;
    __syncthreads();

    // phase 2: gemm W3, 16 thr/row x 4 outs; epilogue -> hrow (h3)
    {
        float4 acc = {0.f, 0.f, 0.f, 0.f};
#pragma unroll 4
        for (int k = 0; k < 64; k++) {
            float zv = zrow[r * ZSTR2 + k];
            float4 wv = *(const float4*)&W3l[k * 64 + 4 * idx];
            acc.x = fmaf(zv, wv.x, acc.x); acc.y = fmaf(zv, wv.y, acc.y);
            acc.z = fmaf(zv, wv.z, acc.z); acc.w = fmaf(zv, wv.w, acc.w);
        }
        float dv = dinv[v];
        const float4 bb = *(const float4*)&b3[4 * idx];
        float4 o;
        o.x = lrelu(dv * acc.x + bb.x, 0.01f);
        o.y = lrelu(dv * acc.y + bb.y, 0.01f);
        o.z = lrelu(dv * acc.z + bb.z, 0.01f);
        o.w = lrelu(dv * acc.w + bb.w, 0.01f);
        *(float4*)&hrow[r * ZSTR2 + 4 * idx] = o;
    }
    __syncthreads();

    // phase 3: gat gemm Wg1 + dots
    {
        float4 g = {0.f, 0.f, 0.f, 0.f};
#pragma unroll 4
        for (int k = 0; k < 64; k++) {
            float hv = hrow[r * ZSTR2 + k];
            float4 wv = *(const float4*)&Wgl[k * 64 + 4 * idx];
            g.x = fmaf(hv, wv.x, g.x); g.y = fmaf(hv, wv.y, g.y);
            g.z = fmaf(hv, wv.z, g.z); g.w = fmaf(hv, wv.w, g.w);
        }
        const float4 v1 = *(const float4*)&av[4 * idx];
        const float4 d1 = *(const float4*)&ad[4 * idx];
        float e1 = g.x * v1.x + g.y * v1.y + g.z * v1.z + g.w * v1.w;
        float e2 = g.x * d1.x + g.y * d1.y + g.z * d1.z + g.w * d1.w;
        e1 += __shfl_xor(e1, 1); e1 += __shfl_xor(e1, 2);
        e1 += __shfl_xor(e1, 4); e1 += __shfl_xor(e1, 8);
        e2 += __shfl_xor(e2, 1); e2 += __shfl_xor(e2, 2);
        e2 += __shfl_xor(e2, 4); e2 += __shfl_xor(e2, 8);
        if (idx == 0) { es[v] = e1; ed[v] = e2; }
        f16x4 h = {(f16)g.x, (f16)g.y, (f16)g.z, (f16)g.w};
        *(f16x4*)(xw + (size_t)v * 64 + 4 * idx) = h;
    }
}

// ---------------- GAT edge softmax weights (fp16 ew) ----------------
__global__ void gat_w_k(const float* __restrict__ es, const float* __restrict__ ed,
                        const int* __restrict__ rp, const int* __restrict__ col,
                        f16* __restrict__ ew, float* __restrict__ wself, float* __restrict__ invden) {
    int v = blockIdx.x * 256 + threadIdx.x;
    if (v >= NN) return;
    float edv = ed[v];
    float eself = lrelu(es[v] + edv, 0.2f);
    float m = eself;
    int s = rp[v], e = rp[v + 1];
    int i = s;
    float lg[32];
    for (; i + 4 <= e; i += 4) {
        int u0 = col[i], u1 = col[i + 1], u2 = col[i + 2], u3 = col[i + 3];
        float t0 = lrelu(es[u0] + edv, 0.2f);
        float t1 = lrelu(es[u1] + edv, 0.2f);
        float t2 = lrelu(es[u2] + edv, 0.2f);
        float t3 = lrelu(es[u3] + edv, 0.2f);
        int k = i - s;
        if (k + 3 < 32) { lg[k] = t0; lg[k + 1] = t1; lg[k + 2] = t2; lg[k + 3] = t3; }
        m = fmaxf(m, fmaxf(fmaxf(t0, t1), fmaxf(t2, t3)));
    }
    for (; i < e; i++) {
        float t = lrelu(es[col[i]] + edv, 0.2f);
        int k = i - s;
        if (k < 32) lg[k] = t;
        m = fmaxf(m, t);
    }
    float wsl = __expf(eself - m);
    float den = wsl;
    for (i = s; i < e; i++) {
        int k = i - s;
        float t = (k < 32) ? lg[k] : lrelu(es[col[i]] + edv, 0.2f);
        float w = __expf(t - m);
        ew[i] = (f16)w;
        den += w;
    }
    wself[v] = wsl;
    invden[v] = 1.f / den;
}

// ---------------- GAT aggregation over fp16 rows (full-row design) ----------------
__global__ __launch_bounds__(256) void gat_agg_h_k(const f16* __restrict__ y, const int* __restrict__ rp,
                                                   const int* __restrict__ col, const f16* __restrict__ ew,
                                                   const float* __restrict__ wself, const float* __restrict__ invden,
                                                   const float* __restrict__ bias, float* __restrict__ out) {
    int gid = blockIdx.x * 256 + threadIdx.x;
    int v = gid >> 4;
    int idx = gid & 15;
    const f16x4* y4 = (const f16x4*)y;
    float ws = wself[v];
    f16x4 self = y4[(size_t)v * 16 + idx];
    float accx = ws * (float)self.x, accy = ws * (float)self.y, accz = ws * (float)self.z, accw = ws * (float)self.w;
    int s = rp[v], e = rp[v + 1];
    int i = s;
    for (; i + 4 <= e; i += 4) {
        int u0 = col[i], u1 = col[i + 1], u2 = col[i + 2], u3 = col[i + 3];
        float w0 = (float)ew[i], w1 = (float)ew[i + 1], w2 = (float)ew[i + 2], w3 = (float)ew[i + 3];
        f16x4 a0 = y4[(size_t)u0 * 16 + idx];
        f16x4 a1 = y4[(size_t)u1 * 16 + idx];
        f16x4 a2 = y4[(size_t)u2 * 16 + idx];
        f16x4 a3 = y4[(size_t)u3 * 16 + idx];
        accx = fmaf(w0, (float)a0.x, fmaf(w1, (float)a1.x, fmaf(w2, (float)a2.x, fmaf(w3, (float)a3.x, accx))));
        accy = fmaf(w0, (float)a0.y, fmaf(w1, (float)a1.y, fmaf(w2, (float)a2.y, fmaf(w3, (float)a3.y, accy))));
        accz = fmaf(w0, (float)a0.z, fmaf(w1, (float)a1.z, fmaf(w2, (float)a2.z, fmaf(w3, (float)a3.z, accz))));
        accw = fmaf(w0, (float)a0.w, fmaf(w1, (float)a1.w, fmaf(w2, (float)a2.w, fmaf(w3, (float)a3.w, accw))));
    }
    for (; i < e; i++) {
        float w = (float)ew[i];
        f16x4 a = y4[(size_t)col[i] * 16 + idx];
        accx = fmaf(w, (float)a.x, accx); accy = fmaf(w, (float)a.y, accy);
        accz = fmaf(w, (float)a.z, accz); accw = fmaf(w, (float)a.w, accw);
    }
    float inv = invden[v];
    const float4* b4 = (const float4*)bias;
    float4 bb = b4[idx];
    float4 r;
    r.x = accx * inv + bb.x; r.y = accy * inv + bb.y;
    r.z = accz * inv + bb.z; r.w = accw * inv + bb.w;
    ((float4*)out)[(size_t)v * 16 + idx] = r;
}

// ---------------- pooling ----------------
__global__ void pool_pieces_k(const float* __restrict__ in, float* __restrict__ out) {
    int gid = blockIdx.x * 256 + threadIdx.x;
    if (gid >= BB * CCROSS * 64) return;
    int f = gid & 63, g = gid >> 6;
    const float* p = in + (size_t)g * PCC * 64 + f;
    float s = 0.f;
#pragma unroll 8
    for (int i = 0; i < PCC; i++) s += p[(size_t)i * 64];
    out[gid] = s * (1.f / 128.f);
}

__global__ void pool_cross_k(const float* __restrict__ in, float* __restrict__ out) {
    int gid = blockIdx.x * 64 + threadIdx.x;
    if (gid >= BB * 64) return;
    int f = gid & 63, b = gid >> 6;
    const float* p = in + (size_t)b * CCROSS * 64 + f;
    float s = 0.f;
#pragma unroll
    for (int i = 0; i < CCROSS; i++) s += p[(size_t)i * 64];
    out[gid] = s * (1.f / 32.f);
}

// ---------------- GAT input gemm (fp32, small cross-graph path) ----------------
template <int KIN, int KOUT>
__global__ void gat_gemm_k(const float* __restrict__ x, const float* __restrict__ W,
                           float* __restrict__ y, const float* __restrict__ av, const float* __restrict__ ad,
                           float* __restrict__ es, float* __restrict__ ed, int n) {
    int v = blockIdx.x * 256 + threadIdx.x;
    if (v >= n) return;
    const float* xr = x + (size_t)v * KIN;
    float acc[KOUT];
#pragma unroll
    for (int j = 0; j < KOUT; j++) acc[j] = 0.f;
#pragma unroll 2
    for (int k = 0; k < KIN; k++) {
        float xv = xr[k];
#pragma unroll
        for (int j = 0; j < KOUT; j++) acc[j] = fmaf(xv, W[k * KOUT + j], acc[j]);
    }
    float e1 = 0.f, e2 = 0.f;
    float4* y4 = (float4*)(y + (size_t)v * KOUT);
#pragma unroll
    for (int j4 = 0; j4 < KOUT / 4; j4++) {
        float4 t;
        t.x = acc[4 * j4 + 0]; t.y = acc[4 * j4 + 1]; t.z = acc[4 * j4 + 2]; t.w = acc[4 * j4 + 3];
        y4[j4] = t;
        e1 = fmaf(t.x, av[4 * j4 + 0], e1); e1 = fmaf(t.y, av[4 * j4 + 1], e1);
        e1 = fmaf(t.z, av[4 * j4 + 2], e1); e1 = fmaf(t.w, av[4 * j4 + 3], e1);
        e2 = fmaf(t.x, ad[4 * j4 + 0], e2); e2 = fmaf(t.y, ad[4 * j4 + 1], e2);
        e2 = fmaf(t.z, ad[4 * j4 + 2], e2); e2 = fmaf(t.w, ad[4 * j4 + 3], e2);
    }
    es[v] = e1; ed[v] = e2;
}

// ---------------- dense cross-graph GAT ----------------
__global__ void cross_att_k(const float* __restrict__ xw, const float* __restrict__ es,
                            const float* __restrict__ ed, const float* __restrict__ bg,
                            float* __restrict__ out) {
    int gid = blockIdx.x * 256 + threadIdx.x;
    if (gid >= BB * CCROSS * 64) return;
    int f = gid & 63;
    int d = (gid >> 6) & 31;
    int g = gid >> 11;
    int base = g * CCROSS;
    float edd = ed[base + d];
    float m = -1e30f;
#pragma unroll
    for (int s = 0; s < CCROSS; s++) {
        float e = lrelu(es[base + s] + edd, 0.2f);
        m = fmaxf(m, e);
    }
    float den = 0.f, acc = 0.f;
#pragma unroll
    for (int s = 0; s < CCROSS; s++) {
        float e = lrelu(es[base + s] + edd, 0.2f);
        float w = __expf(e - m) * ((s == d) ? 1.f : 2.f);
        den += w;
        acc = fmaf(w, xw[(size_t)(base + s) * 64 + f], acc);
    }
    out[gid] = acc / den + bg[f];
}

// ---------------- fused conv branch ----------------
#define S0_STR 264
#define S1_STR 132
#define S2_STR 66
#define S0_OFF 0
#define S1_OFF (3 * S0_STR)
#define S2_OFF (S1_OFF + 32 * S1_STR)
#define SMEM_FLOATS (S2_OFF + 64 * S2_STR)

__global__ __launch_bounds__(256) void conv_fused_k(
        const float* __restrict__ pts, const float* __restrict__ c1W, const float* __restrict__ c1b,
        const float* __restrict__ g1, const float* __restrict__ be1,
        const float* __restrict__ c2W, const float* __restrict__ c2b,
        const float* __restrict__ g2, const float* __restrict__ be2,
        const float* __restrict__ c3W, const float* __restrict__ c3b,
        float* __restrict__ partials) {
    __shared__ float smem[SMEM_FLOATS];
    float* s0 = smem + S0_OFF;
    float* s1 = smem + S1_OFF;
    float* s2 = smem + S2_OFF;
    float* s3 = smem;

    const int b = blockIdx.x >> 3;
    const int q = blockIdx.x & 7;
    const int tid = threadIdx.x;
    const float bnscale = 0.99999500003749968f;

    const int lo0 = 256 * q - 7;
    for (int t = tid; t < 3 * 263; t += 256) {
        int c = t / 263, j = t - c * 263;
        int p = lo0 + j;
        s0[c * S0_STR + j] = (p >= 0 && p < PP) ? pts[((size_t)b * 3 + c) * PP + p] : 0.f;
    }
    __syncthreads();

    const int lo1 = 128 * q - 3;
    for (int t = tid; t < 32 * 131; t += 256) {
        int ch = t / 131, j = t - ch * 131;
        int p1 = lo1 + j;
        float v = 0.f;
        if (p1 >= 0 && p1 < 1024) {
            float acc = c1b[ch];
            const float* w = c1W + ch * 9;
            const float* x0 = s0 + 2 * j;
#pragma unroll
            for (int ci = 0; ci < 3; ci++) {
                acc = fmaf(x0[ci * S0_STR + 0], w[ci * 3 + 0], acc);
                acc = fmaf(x0[ci * S0_STR + 1], w[ci * 3 + 1], acc);
                acc = fmaf(x0[ci * S0_STR + 2], w[ci * 3 + 2], acc);
            }
            acc = lrelu(acc, 0.01f);
            v = fmaf(acc, g1[ch] * bnscale, be1[ch]);
        }
        s1[ch * S1_STR + j] = v;
    }
    __syncthreads();

    const int lo2 = 64 * q - 1;
    for (int t = tid; t < 64 * 65; t += 256) {
        int ch = t / 65, j = t - ch * 65;
        int p2 = lo2 + j;
        float v = 0.f;
        if (p2 >= 0 && p2 < 512) {
            float acc = c2b[ch];
            const float* w = c2W + ch * 96;
            const float* x1 = s1 + 2 * j;
#pragma unroll
            for (int ci = 0; ci < 32; ci++) {
                acc = fmaf(x1[ci * S1_STR + 0], w[ci * 3 + 0], acc);
                acc = fmaf(x1[ci * S1_STR + 1], w[ci * 3 + 1], acc);
                acc = fmaf(x1[ci * S1_STR + 2], w[ci * 3 + 2], acc);
            }
            acc = lrelu(acc, 0.01f);
            v = fmaf(acc, g2[ch] * bnscale, be2[ch]);
        }
        s2[ch * S2_STR + j] = v;
    }
    __syncthreads();

    for (int t = tid; t < 64 * 32; t += 256) {
        int o = t >> 5, j = t & 31;
        float acc = c3b[o];
        const float* w = c3W + o * 192;
        const float* x2 = s2 + 2 * j;
#pragma unroll 16
        for (int ci = 0; ci < 64; ci++) {
            acc = fmaf(x2[ci * S2_STR + 0], w[ci * 3 + 0], acc);
            acc = fmaf(x2[ci * S2_STR + 1], w[ci * 3 + 1], acc);
            acc = fmaf(x2[ci * S2_STR + 2], w[ci * 3 + 2], acc);
        }
        s3[t] = lrelu(acc, 0.01f);
    }
    __syncthreads();

    if (tid < 64) {
        float s = 0.f;
#pragma unroll
        for (int j = 0; j < 32; j++) s += s3[tid * 32 + j];
        partials[((size_t)b * 8 + q) * 64 + tid] = s;
    }
}

// ---------------- head ----------------
__global__ void head_k(const float* __restrict__ hG, const float* __restrict__ partials,
                       const float* __restrict__ Wl2, const float* __restrict__ bl2,
                       const float* __restrict__ Wl3, const float* __restrict__ bl3,
                       float* __restrict__ out) {
    int b = blockIdx.x;
    int f = threadIdx.x;  // 64
    __shared__ float sh[64];
    float p = 0.f;
#pragma unroll
    for (int q = 0; q < 8; q++) p += partials[((size_t)b * 8 + q) * 64 + f];
    float h = hG[b * 64 + f] + p * (1.f / 256.f);
    sh[f] = h;
    __syncthreads();
    float acc = bl2[f];
#pragma unroll
    for (int k = 0; k < 64; k++) acc = fmaf(sh[k], Wl2[k * 64 + f], acc);
    acc = lrelu(acc, 0.01f);
    float pr = acc * Wl3[f];
#pragma unroll
    for (int off = 32; off > 0; off >>= 1) pr += __shfl_down(pr, off, 64);
    if (f == 0) out[b] = 1.f / (1.f + __expf(-(pr + bl3[0])));
}

extern "C" void kernel_launch(void* const* d_in, const int* in_sizes, int n_in,
                              void* d_out, int out_size, void* d_ws, size_t ws_size,
                              hipStream_t stream) {
    const float* x = (const float*)d_in[0];
    const int* ei = (const int*)d_in[1];
    const float* points = (const float*)d_in[2];
    const float* W1 = (const float*)d_in[3];
    const float* b1 = (const float*)d_in[4];
    const float* W2 = (const float*)d_in[5];
    const float* b2 = (const float*)d_in[6];
    const float* W3 = (const float*)d_in[7];
    const float* b3 = (const float*)d_in[8];
    const float* Wg1 = (const float*)d_in[9];
    const float* asrc1 = (const float*)d_in[10];
    const float* adst1 = (const float*)d_in[11];
    const float* bg1 = (const float*)d_in[12];
    const float* Wg2 = (const float*)d_in[13];
    const float* asrc2 = (const float*)d_in[14];
    const float* adst2 = (const float*)d_in[15];
    const float* bg2 = (const float*)d_in[16];
    const float* c1W = (const float*)d_in[17];
    const float* c1b = (const float*)d_in[18];
    const float* g1 = (const float*)d_in[19];
    const float* be1 = (const float*)d_in[20];
    const float* c2W = (const float*)d_in[21];
    const float* c2b = (const float*)d_in[22];
    const float* g2 = (const float*)d_in[23];
    const float* be2 = (const float*)d_in[24];
    const float* c3W = (const float*)d_in[25];
    const float* c3b = (const float*)d_in[26];
    const float* Wl2 = (const float*)d_in[27];
    const float* bl2 = (const float*)d_in[28];
    const float* Wl3 = (const float*)d_in[29];
    const float* bl3 = (const float*)d_in[30];

    const int* src = ei;
    const int* dst = ei + EE;

    // ---- workspace carve-up ----
    char* w = (char*)d_ws;
    size_t off = 0;
    auto A = [&](size_t bytes) -> void* {
        void* p = w + off;
        off = (off + bytes + 255) & ~(size_t)255;
        return p;
    };
    int* colb = (int*)A((size_t)EE * 4);
    int* rp = (int*)A((size_t)(NN + 1) * 4);
    int* gcnt = (int*)A(NBUCK * 4);
    int* bbase = (int*)A(NBUCK * 4);
    float* dinv = (float*)A((size_t)NN * 4);
    float* bufA = (float*)A((size_t)NN * 64 * 4);
    f16* bufH1 = (f16*)A((size_t)NN * 64 * 2);
    f16* bufH2 = (f16*)A((size_t)NN * 64 * 2);
    f16* ew = (f16*)A((size_t)EE * 2);
    float* wself = (float*)A((size_t)NN * 4);
    float* invden = (float*)A((size_t)NN * 4);
    float* es = (float*)A((size_t)NN * 4);
    float* edv = (float*)A((size_t)NN * 4);
    float* pooled = (float*)A((size_t)BB * CCROSS * 64 * 4);
    float* xw2 = (float*)A((size_t)BB * CCROSS * 64 * 4);
    float* es2 = (float*)A((size_t)BB * CCROSS * 4);
    float* ed2 = (float*)A((size_t)BB * CCROSS * 4);
    float* crosso = (float*)A((size_t)BB * CCROSS * 64 * 4);
    float* hG = (float*)A((size_t)BB * 64 * 4);
    float* partials = (float*)A((size_t)BB * 8 * 64 * 4);

    unsigned* buckets = (unsigned*)bufA;   // aliases bufA; dead before bufA's first real use (gat output)

    // ---- CSR build (bucketed) ----
    hipMemsetAsync(gcnt, 0, NBUCK * 4, stream);
    bucket_a_k<<<EE / 8192, 256, 0, stream>>>(src, dst, buckets, gcnt);
    bucket_scan_k<<<1, 256, 0, stream>>>(gcnt, bbase, rp);
    bucket_b_k<<<NBUCK, 256, 0, stream>>>(buckets, gcnt, bbase, rp, dinv, colb);

    // ---- points branch ----
    conv_fused_k<<<BB * 8, 256, 0, stream>>>(points, c1W, c1b, g1, be1, c2W, c2b, g2, be2, c3W, c3b, partials);

    // ---- GCN 1/2/3 + GAT gemm (fused agg+gemm chain, fp16 gather arrays) ----
    zprep_k<<<NN / 256, 256, 0, stream>>>(x, dinv, bufH1);                               // H1 = z1 [NN x 32h]
    fused_agg_gemm_k<19, 32, 0><<<NN / 32, 256, 0, stream>>>(bufH1, rp, colb, W1, dinv, b1, bufH2);  // H2 = z2 [NN x 32h]
    fused_agg_gemm_k<32, 64, 1><<<NN / 32, 256, 0, stream>>>(bufH2, rp, colb, W2, dinv, b2, bufH1);  // H1 = z3 [NN x 64h]
    fused_agg_gemm_gat_k<<<NN / 16, 256, 0, stream>>>(bufH1, rp, colb, W3, dinv, b3, Wg1, asrc1, adst1,
                                                      bufH2, es, edv);                   // H2 = xw [NN x 64h], es/ed

    // ---- GAT 1 softmax + aggregation ----
    gat_w_k<<<NN / 256, 256, 0, stream>>>(es, edv, rp, colb, ew, wself, invden);
    gat_agg_h_k<<<(NN * 16) / 256, 256, 0, stream>>>(bufH2, rp, colb, ew, wself, invden, bg1, bufA);  // bufA = gat out

    // ---- pool pieces -> cross GAT -> pool cross ----
    pool_pieces_k<<<(BB * CCROSS * 64) / 256, 256, 0, stream>>>(bufA, pooled);
    gat_gemm_k<64, 64><<<(BB * CCROSS) / 256, 256, 0, stream>>>(pooled, Wg2, xw2, asrc2, adst2, es2, ed2, BB * CCROSS);
    cross_att_k<<<(BB * CCROSS * 64) / 256, 256, 0, stream>>>(xw2, es2, ed2, bg2, crosso);
    pool_cross_k<<<BB, 64, 0, stream>>>(crosso, hG);

    // ---- head ----
    head_k<<<BB, 64, 0, stream>>>(hG, partials, Wl2, bl2, Wl3, bl3, (float*)d_out);
}

// Round 10
// 621.225 us; speedup vs baseline: 1.0633x; 1.0633x over previous
//
#include <hip/hip_runtime.h>
#include <cstdint>
#include <cstddef>

#define NN 262144
#define EE 2097152
#define BB 64
#define CCROSS 32
#define PCC 128
#define PP 2048
#define NBUCK 256
#define BCAP 12288

typedef _Float16 f16;
typedef __attribute__((ext_vector_type(4))) _Float16 f16x4;
typedef __attribute__((ext_vector_type(8))) _Float16 f16x8;

static __device__ __forceinline__ float lrelu(float x, float s) { return x > 0.f ? x : s * x; }

// ---------------- bucketed CSR build ----------------
__global__ __launch_bounds__(256) void bucket_a_k(const int* __restrict__ src, const int* __restrict__ dst,
                                                  unsigned* __restrict__ buckets, int* __restrict__ gcnt) {
    __shared__ int hist[NBUCK];
    __shared__ int base[NBUCK];
    __shared__ unsigned short rankbuf[8192];
    const int tid = threadIdx.x;
    const int e0 = blockIdx.x * 8192;
    hist[tid] = 0;
    __syncthreads();
    for (int i = tid; i < 8192; i += 256) {
        int d = dst[e0 + i];
        rankbuf[i] = (unsigned short)atomicAdd(&hist[d >> 10], 1);
    }
    __syncthreads();
    base[tid] = tid * BCAP + atomicAdd(&gcnt[tid], hist[tid]);
    __syncthreads();
    for (int i = tid; i < 8192; i += 256) {
        int s = src[e0 + i];
        int d = dst[e0 + i];
        int b = d >> 10;
        buckets[base[b] + rankbuf[i]] = ((unsigned)s << 10) | (unsigned)(d & 1023);
    }
}

__global__ void bucket_scan_k(const int* __restrict__ gcnt, int* __restrict__ bbase, int* __restrict__ rp) {
    __shared__ int tmp[256];
    int tid = threadIdx.x;
    int v = gcnt[tid];
    tmp[tid] = v;
    __syncthreads();
    for (int off = 1; off < 256; off <<= 1) {
        int t = (tid >= off) ? tmp[tid - off] : 0;
        __syncthreads();
        tmp[tid] += t;
        __syncthreads();
    }
    bbase[tid] = tmp[tid] - v;
    if (tid == 0) rp[NN] = EE;
}

__global__ __launch_bounds__(256) void bucket_b_k(const unsigned* __restrict__ buckets, const int* __restrict__ gcnt,
                                                  const int* __restrict__ bbase, int* __restrict__ rp,
                                                  float* __restrict__ dinv, int* __restrict__ col) {
    __shared__ int cnt[1024];
    __shared__ int scan[1024];
    __shared__ int wsum[256];
    const int b = blockIdx.x;
    const int tid = threadIdx.x;
    int n = gcnt[b];
    if (n > BCAP) n = BCAP;
    const unsigned* eb = buckets + (size_t)b * BCAP;
    const int gb = bbase[b];
    for (int i = tid; i < 1024; i += 256) cnt[i] = 0;
    __syncthreads();
    for (int i = tid; i < n; i += 256) atomicAdd(&cnt[eb[i] & 1023], 1);
    __syncthreads();
    int b4 = tid * 4;
    int c0 = cnt[b4], c1 = cnt[b4 + 1], c2 = cnt[b4 + 2], c3 = cnt[b4 + 3];
    int tsum = c0 + c1 + c2 + c3;
    wsum[tid] = tsum;
    __syncthreads();
    for (int off = 1; off < 256; off <<= 1) {
        int t = (tid >= off) ? wsum[tid - off] : 0;
        __syncthreads();
        wsum[tid] += t;
        __syncthreads();
    }
    int excl = wsum[tid] - tsum;
    scan[b4] = excl;
    scan[b4 + 1] = excl + c0;
    scan[b4 + 2] = excl + c0 + c1;
    scan[b4 + 3] = excl + c0 + c1 + c2;
    int vbase = b * 1024 + b4;
    rp[vbase + 0] = gb + scan[b4 + 0];
    rp[vbase + 1] = gb + scan[b4 + 1];
    rp[vbase + 2] = gb + scan[b4 + 2];
    rp[vbase + 3] = gb + scan[b4 + 3];
    dinv[vbase + 0] = rsqrtf((float)(c0 + 1));
    dinv[vbase + 1] = rsqrtf((float)(c1 + 1));
    dinv[vbase + 2] = rsqrtf((float)(c2 + 1));
    dinv[vbase + 3] = rsqrtf((float)(c3 + 1));
    __syncthreads();
    for (int i = tid; i < 1024; i += 256) cnt[i] = 0;
    __syncthreads();
    for (int i = tid; i < n; i += 256) {
        unsigned p = eb[i];
        int dl = p & 1023;
        int r = atomicAdd(&cnt[dl], 1);
        col[gb + scan[dl] + r] = (int)(p >> 10);
    }
}

// ---------------- z-prep: z1[v] = dinv[v]*x[v] fp16, padded 19 -> 32 halfs ----------------
__global__ void zprep_k(const float* __restrict__ x, const float* __restrict__ dinv, f16* __restrict__ z) {
    int v = blockIdx.x * 256 + threadIdx.x;
    if (v >= NN) return;
    float dv = dinv[v];
    const float* xr = x + (size_t)v * 19;
    float vv[20];
#pragma unroll
    for (int k = 0; k < 19; k++) vv[k] = dv * xr[k];
    vv[19] = 0.f;
    f16x4* zr = (f16x4*)(z + (size_t)v * 32);
#pragma unroll
    for (int c = 0; c < 5; c++) {
        f16x4 t = {(f16)vv[4 * c], (f16)vv[4 * c + 1], (f16)vv[4 * c + 2], (f16)vv[4 * c + 3]};
        zr[c] = t;
    }
    f16x4 zz = {(f16)0.f, (f16)0.f, (f16)0.f, (f16)0.f};
#pragma unroll
    for (int c = 5; c < 8; c++) zr[c] = zz;
}

// ---------------- fused agg (64B fp16 rows) + gemm ----------------
// 32 rows/block; phase1: 8 lanes/row gather -> zrow LDS (stride 36: bank = (4r+k)%32, conflict-free);
// phase2: 8 thr/row, KOUT/8 outs each.
#define ZSTR1 36
template <int KINR, int KOUT, int ACT>
__global__ __launch_bounds__(256) void fused_agg_gemm_k(const f16* __restrict__ z, const int* __restrict__ rp,
                                                        const int* __restrict__ col, const float* __restrict__ Wg,
                                                        const float* __restrict__ dinv, const float* __restrict__ bias,
                                                        f16* __restrict__ zout) {
    constexpr int NO = KOUT / 8;
    __shared__ float Wl[32 * KOUT];
    __shared__ float zrow[32 * ZSTR1];
    const int tid = threadIdx.x;
    for (int i = tid; i < 32 * KOUT; i += 256) Wl[i] = (i < KINR * KOUT) ? Wg[i] : 0.f;

    const int r = tid >> 3;
    const int idx = tid & 7;
    const int v = blockIdx.x * 32 + r;
    const f16x4* z4 = (const f16x4*)z;
    f16x4 a = z4[(size_t)v * 8 + idx];
    float ax = (float)a.x, ay = (float)a.y, az = (float)a.z, aw = (float)a.w;
    int st = rp[v], e = rp[v + 1];
    int i = st;
    for (; i + 4 <= e; i += 4) {
        int u0 = col[i], u1 = col[i + 1], u2 = col[i + 2], u3 = col[i + 3];
        f16x4 a0 = z4[(size_t)u0 * 8 + idx];
        f16x4 a1 = z4[(size_t)u1 * 8 + idx];
        f16x4 a2 = z4[(size_t)u2 * 8 + idx];
        f16x4 a3 = z4[(size_t)u3 * 8 + idx];
        ax += ((float)a0.x + (float)a1.x) + ((float)a2.x + (float)a3.x);
        ay += ((float)a0.y + (float)a1.y) + ((float)a2.y + (float)a3.y);
        az += ((float)a0.z + (float)a1.z) + ((float)a2.z + (float)a3.z);
        aw += ((float)a0.w + (float)a1.w) + ((float)a2.w + (float)a3.w);
    }
    for (; i < e; i++) {
        f16x4 aa = z4[(size_t)col[i] * 8 + idx];
        ax += (float)aa.x; ay += (float)aa.y; az += (float)aa.z; aw += (float)aa.w;
    }
    float4 s; s.x = ax; s.y = ay; s.z = az; s.w = aw;
    *(float4*)&zrow[r * ZSTR1 + idx * 4] = s;
    __syncthreads();

    // phase 2: 8 threads/row, NO outs each
    float acc[NO];
#pragma unroll
    for (int j = 0; j < NO; j++) acc[j] = 0.f;
#pragma unroll 4
    for (int k = 0; k < 32; k++) {
        float zv = zrow[r * ZSTR1 + k];
        const float* wr = Wl + k * KOUT + NO * idx;
#pragma unroll
        for (int j = 0; j < NO; j++) acc[j] = fmaf(zv, wr[j], acc[j]);
    }
    float dv = dinv[v];
    f16 hv[NO];
#pragma unroll
    for (int j = 0; j < NO; j++) {
        float o = dv * acc[j] + bias[NO * idx + j];
        o = (ACT == 0) ? fmaxf(o, 0.f) : lrelu(o, 0.01f);
        hv[j] = (f16)(o * dv);
    }
    if constexpr (NO == 4) {
        f16x4 h = {hv[0], hv[1], hv[2], hv[3]};
        *(f16x4*)(zout + (size_t)v * KOUT + NO * idx) = h;
    } else {
        f16x8 h = {hv[0], hv[1], hv[2], hv[3], hv[4], hv[5], hv[6], hv[7]};
        *(f16x8*)(zout + (size_t)v * KOUT + NO * idx) = h;
    }
}

// ---------------- fused agg (128B rows) + gemm W3 + gat gemm Wg1 + es/ed dots ----------------
// 16 rows/block; 16 lanes/row; zrow/hrow stride 68 (conflict-free).
// ONE 16KB weight buffer, reloaded W3 -> Wg1 mid-kernel: LDS 25088 B -> 6 blocks/CU.
#define ZSTR2 68
__global__ __launch_bounds__(256) void fused_agg_gemm_gat_k(const f16* __restrict__ z, const int* __restrict__ rp,
                                                            const int* __restrict__ col, const float* __restrict__ W3,
                                                            const float* __restrict__ dinv, const float* __restrict__ b3,
                                                            const float* __restrict__ Wg1, const float* __restrict__ av,
                                                            const float* __restrict__ ad, f16* __restrict__ xw,
                                                            float* __restrict__ es, float* __restrict__ ed) {
    __shared__ float Wl[64 * 64];
    __shared__ float zrow[16 * ZSTR2];
    __shared__ float hrow[16 * ZSTR2];
    const int tid = threadIdx.x;
    for (int i = tid; i < 4096; i += 256) Wl[i] = W3[i];

    const int r = tid >> 4;
    const int idx = tid & 15;
    const int v = blockIdx.x * 16 + r;
    const f16x4* z4 = (const f16x4*)z;
    f16x4 a = z4[(size_t)v * 16 + idx];
    float ax = (float)a.x, ay = (float)a.y, az = (float)a.z, aw = (float)a.w;
    int st = rp[v], e = rp[v + 1];
    int i = st;
    for (; i + 4 <= e; i += 4) {
        int u0 = col[i], u1 = col[i + 1], u2 = col[i + 2], u3 = col[i + 3];
        f16x4 a0 = z4[(size_t)u0 * 16 + idx];
        f16x4 a1 = z4[(size_t)u1 * 16 + idx];
        f16x4 a2 = z4[(size_t)u2 * 16 + idx];
        f16x4 a3 = z4[(size_t)u3 * 16 + idx];
        ax += ((float)a0.x + (float)a1.x) + ((float)a2.x + (float)a3.x);
        ay += ((float)a0.y + (float)a1.y) + ((float)a2.y + (float)a3.y);
        az += ((float)a0.z + (float)a1.z) + ((float)a2.z + (float)a3.z);
        aw += ((float)a0.w + (float)a1.w) + ((float)a2.w + (float)a3.w);
    }
    for (; i < e; i++) {
        f16x4 aa = z4[(size_t)col[i] * 16 + idx];
        ax += (float)aa.x; ay += (float)aa.y; az += (float)aa.z; aw += (float)aa.w;
    }
    float4 s; s.x = ax; s.y = ay; s.z = az; s.w = aw;
    *(float4*)&zrow[r * ZSTR2 + idx * 4] = s;
    __syncthreads();

    // phase 2: gemm W3, 16 thr/row x 4 outs; epilogue -> hrow (h3)
    {
        float4 acc = {0.f, 0.f, 0.f, 0.f};
#pragma unroll 4
        for (int k = 0; k < 64; k++) {
            float zv = zrow[r * ZSTR2 + k];
            float4 wv = *(const float4*)&Wl[k * 64 + 4 * idx];
            acc.x = fmaf(zv, wv.x, acc.x); acc.y = fmaf(zv, wv.y, acc.y);
            acc.z = fmaf(zv, wv.z, acc.z); acc.w = fmaf(zv, wv.w, acc.w);
        }
        float dv = dinv[v];
        const float4 bb = *(const float4*)&b3[4 * idx];
        float4 o;
        o.x = lrelu(dv * acc.x + bb.x, 0.01f);
        o.y = lrelu(dv * acc.y + bb.y, 0.01f);
        o.z = lrelu(dv * acc.z + bb.z, 0.01f);
        o.w = lrelu(dv * acc.w + bb.w, 0.01f);
        *(float4*)&hrow[r * ZSTR2 + 4 * idx] = o;
    }
    __syncthreads();

    // swap weights: Wl <- Wg1
    for (int i2 = tid; i2 < 4096; i2 += 256) Wl[i2] = Wg1[i2];
    __syncthreads();

    // phase 3: gat gemm Wg1 + dots
    {
        float4 g = {0.f, 0.f, 0.f, 0.f};
#pragma unroll 4
        for (int k = 0; k < 64; k++) {
            float hv = hrow[r * ZSTR2 + k];
            float4 wv = *(const float4*)&Wl[k * 64 + 4 * idx];
            g.x = fmaf(hv, wv.x, g.x); g.y = fmaf(hv, wv.y, g.y);
            g.z = fmaf(hv, wv.z, g.z); g.w = fmaf(hv, wv.w, g.w);
        }
        const float4 v1 = *(const float4*)&av[4 * idx];
        const float4 d1 = *(const float4*)&ad[4 * idx];
        float e1 = g.x * v1.x + g.y * v1.y + g.z * v1.z + g.w * v1.w;
        float e2 = g.x * d1.x + g.y * d1.y + g.z * d1.z + g.w * d1.w;
        e1 += __shfl_xor(e1, 1); e1 += __shfl_xor(e1, 2);
        e1 += __shfl_xor(e1, 4); e1 += __shfl_xor(e1, 8);
        e2 += __shfl_xor(e2, 1); e2 += __shfl_xor(e2, 2);
        e2 += __shfl_xor(e2, 4); e2 += __shfl_xor(e2, 8);
        if (idx == 0) { es[v] = e1; ed[v] = e2; }
        f16x4 h = {(f16)g.x, (f16)g.y, (f16)g.z, (f16)g.w};
        *(f16x4*)(xw + (size_t)v * 64 + 4 * idx) = h;
    }
}

// ---------------- GAT edge softmax weights (fp16 ew) ----------------
__global__ void gat_w_k(const float* __restrict__ es, const float* __restrict__ ed,
                        const int* __restrict__ rp, const int* __restrict__ col,
                        f16* __restrict__ ew, float* __restrict__ wself, float* __restrict__ invden) {
    int v = blockIdx.x * 256 + threadIdx.x;
    if (v >= NN) return;
    float edv = ed[v];
    float eself = lrelu(es[v] + edv, 0.2f);
    float m = eself;
    int s = rp[v], e = rp[v + 1];
    int i = s;
    float lg[32];
    for (; i + 4 <= e; i += 4) {
        int u0 = col[i], u1 = col[i + 1], u2 = col[i + 2], u3 = col[i + 3];
        float t0 = lrelu(es[u0] + edv, 0.2f);
        float t1 = lrelu(es[u1] + edv, 0.2f);
        float t2 = lrelu(es[u2] + edv, 0.2f);
        float t3 = lrelu(es[u3] + edv, 0.2f);
        int k = i - s;
        if (k + 3 < 32) { lg[k] = t0; lg[k + 1] = t1; lg[k + 2] = t2; lg[k + 3] = t3; }
        m = fmaxf(m, fmaxf(fmaxf(t0, t1), fmaxf(t2, t3)));
    }
    for (; i < e; i++) {
        float t = lrelu(es[col[i]] + edv, 0.2f);
        int k = i - s;
        if (k < 32) lg[k] = t;
        m = fmaxf(m, t);
    }
    float wsl = __expf(eself - m);
    float den = wsl;
    for (i = s; i < e; i++) {
        int k = i - s;
        float t = (k < 32) ? lg[k] : lrelu(es[col[i]] + edv, 0.2f);
        float w = __expf(t - m);
        ew[i] = (f16)w;
        den += w;
    }
    wself[v] = wsl;
    invden[v] = 1.f / den;
}

// ---------------- GAT aggregation over fp16 rows (full-row design) ----------------
__global__ __launch_bounds__(256) void gat_agg_h_k(const f16* __restrict__ y, const int* __restrict__ rp,
                                                   const int* __restrict__ col, const f16* __restrict__ ew,
                                                   const float* __restrict__ wself, const float* __restrict__ invden,
                                                   const float* __restrict__ bias, float* __restrict__ out) {
    int gid = blockIdx.x * 256 + threadIdx.x;
    int v = gid >> 4;
    int idx = gid & 15;
    const f16x4* y4 = (const f16x4*)y;
    float ws = wself[v];
    f16x4 self = y4[(size_t)v * 16 + idx];
    float accx = ws * (float)self.x, accy = ws * (float)self.y, accz = ws * (float)self.z, accw = ws * (float)self.w;
    int s = rp[v], e = rp[v + 1];
    int i = s;
    for (; i + 4 <= e; i += 4) {
        int u0 = col[i], u1 = col[i + 1], u2 = col[i + 2], u3 = col[i + 3];
        float w0 = (float)ew[i], w1 = (float)ew[i + 1], w2 = (float)ew[i + 2], w3 = (float)ew[i + 3];
        f16x4 a0 = y4[(size_t)u0 * 16 + idx];
        f16x4 a1 = y4[(size_t)u1 * 16 + idx];
        f16x4 a2 = y4[(size_t)u2 * 16 + idx];
        f16x4 a3 = y4[(size_t)u3 * 16 + idx];
        accx = fmaf(w0, (float)a0.x, fmaf(w1, (float)a1.x, fmaf(w2, (float)a2.x, fmaf(w3, (float)a3.x, accx))));
        accy = fmaf(w0, (float)a0.y, fmaf(w1, (float)a1.y, fmaf(w2, (float)a2.y, fmaf(w3, (float)a3.y, accy))));
        accz = fmaf(w0, (float)a0.z, fmaf(w1, (float)a1.z, fmaf(w2, (float)a2.z, fmaf(w3, (float)a3.z, accz))));
        accw = fmaf(w0, (float)a0.w, fmaf(w1, (float)a1.w, fmaf(w2, (float)a2.w, fmaf(w3, (float)a3.w, accw))));
    }
    for (; i < e; i++) {
        float w = (float)ew[i];
        f16x4 a = y4[(size_t)col[i] * 16 + idx];
        accx = fmaf(w, (float)a.x, accx); accy = fmaf(w, (float)a.y, accy);
        accz = fmaf(w, (float)a.z, accz); accw = fmaf(w, (float)a.w, accw);
    }
    float inv = invden[v];
    const float4* b4 = (const float4*)bias;
    float4 bb = b4[idx];
    float4 r;
    r.x = accx * inv + bb.x; r.y = accy * inv + bb.y;
    r.z = accz * inv + bb.z; r.w = accw * inv + bb.w;
    ((float4*)out)[(size_t)v * 16 + idx] = r;
}

// ---------------- pooling ----------------
__global__ void pool_pieces_k(const float* __restrict__ in, float* __restrict__ out) {
    int gid = blockIdx.x * 256 + threadIdx.x;
    if (gid >= BB * CCROSS * 64) return;
    int f = gid & 63, g = gid >> 6;
    const float* p = in + (size_t)g * PCC * 64 + f;
    float s = 0.f;
#pragma unroll 8
    for (int i = 0; i < PCC; i++) s += p[(size_t)i * 64];
    out[gid] = s * (1.f / 128.f);
}

__global__ void pool_cross_k(const float* __restrict__ in, float* __restrict__ out) {
    int gid = blockIdx.x * 64 + threadIdx.x;
    if (gid >= BB * 64) return;
    int f = gid & 63, b = gid >> 6;
    const float* p = in + (size_t)b * CCROSS * 64 + f;
    float s = 0.f;
#pragma unroll
    for (int i = 0; i < CCROSS; i++) s += p[(size_t)i * 64];
    out[gid] = s * (1.f / 32.f);
}

// ---------------- GAT input gemm (fp32, small cross-graph path) ----------------
template <int KIN, int KOUT>
__global__ void gat_gemm_k(const float* __restrict__ x, const float* __restrict__ W,
                           float* __restrict__ y, const float* __restrict__ av, const float* __restrict__ ad,
                           float* __restrict__ es, float* __restrict__ ed, int n) {
    int v = blockIdx.x * 256 + threadIdx.x;
    if (v >= n) return;
    const float* xr = x + (size_t)v * KIN;
    float acc[KOUT];
#pragma unroll
    for (int j = 0; j < KOUT; j++) acc[j] = 0.f;
#pragma unroll 2
    for (int k = 0; k < KIN; k++) {
        float xv = xr[k];
#pragma unroll
        for (int j = 0; j < KOUT; j++) acc[j] = fmaf(xv, W[k * KOUT + j], acc[j]);
    }
    float e1 = 0.f, e2 = 0.f;
    float4* y4 = (float4*)(y + (size_t)v * KOUT);
#pragma unroll
    for (int j4 = 0; j4 < KOUT / 4; j4++) {
        float4 t;
        t.x = acc[4 * j4 + 0]; t.y = acc[4 * j4 + 1]; t.z = acc[4 * j4 + 2]; t.w = acc[4 * j4 + 3];
        y4[j4] = t;
        e1 = fmaf(t.x, av[4 * j4 + 0], e1); e1 = fmaf(t.y, av[4 * j4 + 1], e1);
        e1 = fmaf(t.z, av[4 * j4 + 2], e1); e1 = fmaf(t.w, av[4 * j4 + 3], e1);
        e2 = fmaf(t.x, ad[4 * j4 + 0], e2); e2 = fmaf(t.y, ad[4 * j4 + 1], e2);
        e2 = fmaf(t.z, ad[4 * j4 + 2], e2); e2 = fmaf(t.w, ad[4 * j4 + 3], e2);
    }
    es[v] = e1; ed[v] = e2;
}

// ---------------- dense cross-graph GAT ----------------
__global__ void cross_att_k(const float* __restrict__ xw, const float* __restrict__ es,
                            const float* __restrict__ ed, const float* __restrict__ bg,
                            float* __restrict__ out) {
    int gid = blockIdx.x * 256 + threadIdx.x;
    if (gid >= BB * CCROSS * 64) return;
    int f = gid & 63;
    int d = (gid >> 6) & 31;
    int g = gid >> 11;
    int base = g * CCROSS;
    float edd = ed[base + d];
    float m = -1e30f;
#pragma unroll
    for (int s = 0; s < CCROSS; s++) {
        float e = lrelu(es[base + s] + edd, 0.2f);
        m = fmaxf(m, e);
    }
    float den = 0.f, acc = 0.f;
#pragma unroll
    for (int s = 0; s < CCROSS; s++) {
        float e = lrelu(es[base + s] + edd, 0.2f);
        float w = __expf(e - m) * ((s == d) ? 1.f : 2.f);
        den += w;
        acc = fmaf(w, xw[(size_t)(base + s) * 64 + f], acc);
    }
    out[gid] = acc / den + bg[f];
}

// ---------------- fused conv branch ----------------
#define S0_STR 264
#define S1_STR 132
#define S2_STR 66
#define S0_OFF 0
#define S1_OFF (3 * S0_STR)
#define S2_OFF (S1_OFF + 32 * S1_STR)
#define SMEM_FLOATS (S2_OFF + 64 * S2_STR)

__global__ __launch_bounds__(256) void conv_fused_k(
        const float* __restrict__ pts, const float* __restrict__ c1W, const float* __restrict__ c1b,
        const float* __restrict__ g1, const float* __restrict__ be1,
        const float* __restrict__ c2W, const float* __restrict__ c2b,
        const float* __restrict__ g2, const float* __restrict__ be2,
        const float* __restrict__ c3W, const float* __restrict__ c3b,
        float* __restrict__ partials) {
    __shared__ float smem[SMEM_FLOATS];
    float* s0 = smem + S0_OFF;
    float* s1 = smem + S1_OFF;
    float* s2 = smem + S2_OFF;
    float* s3 = smem;

    const int b = blockIdx.x >> 3;
    const int q = blockIdx.x & 7;
    const int tid = threadIdx.x;
    const float bnscale = 0.99999500003749968f;

    const int lo0 = 256 * q - 7;
    for (int t = tid; t < 3 * 263; t += 256) {
        int c = t / 263, j = t - c * 263;
        int p = lo0 + j;
        s0[c * S0_STR + j] = (p >= 0 && p < PP) ? pts[((size_t)b * 3 + c) * PP + p] : 0.f;
    }
    __syncthreads();

    const int lo1 = 128 * q - 3;
    for (int t = tid; t < 32 * 131; t += 256) {
        int ch = t / 131, j = t - ch * 131;
        int p1 = lo1 + j;
        float v = 0.f;
        if (p1 >= 0 && p1 < 1024) {
            float acc = c1b[ch];
            const float* w = c1W + ch * 9;
            const float* x0 = s0 + 2 * j;
#pragma unroll
            for (int ci = 0; ci < 3; ci++) {
                acc = fmaf(x0[ci * S0_STR + 0], w[ci * 3 + 0], acc);
                acc = fmaf(x0[ci * S0_STR + 1], w[ci * 3 + 1], acc);
                acc = fmaf(x0[ci * S0_STR + 2], w[ci * 3 + 2], acc);
            }
            acc = lrelu(acc, 0.01f);
            v = fmaf(acc, g1[ch] * bnscale, be1[ch]);
        }
        s1[ch * S1_STR + j] = v;
    }
    __syncthreads();

    const int lo2 = 64 * q - 1;
    for (int t = tid; t < 64 * 65; t += 256) {
        int ch = t / 65, j = t - ch * 65;
        int p2 = lo2 + j;
        float v = 0.f;
        if (p2 >= 0 && p2 < 512) {
            float acc = c2b[ch];
            const float* w = c2W + ch * 96;
            const float* x1 = s1 + 2 * j;
#pragma unroll
            for (int ci = 0; ci < 32; ci++) {
                acc = fmaf(x1[ci * S1_STR + 0], w[ci * 3 + 0], acc);
                acc = fmaf(x1[ci * S1_STR + 1], w[ci * 3 + 1], acc);
                acc = fmaf(x1[ci * S1_STR + 2], w[ci * 3 + 2], acc);
            }
            acc = lrelu(acc, 0.01f);
            v = fmaf(acc, g2[ch] * bnscale, be2[ch]);
        }
        s2[ch * S2_STR + j] = v;
    }
    __syncthreads();

    for (int t = tid; t < 64 * 32; t += 256) {
        int o = t >> 5, j = t & 31;
        float acc = c3b[o];
        const float* w = c3W + o * 192;
        const float* x2 = s2 + 2 * j;
#pragma unroll 16
        for (int ci = 0; ci < 64; ci++) {
            acc = fmaf(x2[ci * S2_STR + 0], w[ci * 3 + 0], acc);
            acc = fmaf(x2[ci * S2_STR + 1], w[ci * 3 + 1], acc);
            acc = fmaf(x2[ci * S2_STR + 2], w[ci * 3 + 2], acc);
        }
        s3[t] = lrelu(acc, 0.01f);
    }
    __syncthreads();

    if (tid < 64) {
        float s = 0.f;
#pragma unroll
        for (int j = 0; j < 32; j++) s += s3[tid * 32 + j];
        partials[((size_t)b * 8 + q) * 64 + tid] = s;
    }
}

// ---------------- head ----------------
__global__ void head_k(const float* __restrict__ hG, const float* __restrict__ partials,
                       const float* __restrict__ Wl2, const float* __restrict__ bl2,
                       const float* __restrict__ Wl3, const float* __restrict__ bl3,
                       float* __restrict__ out) {
    int b = blockIdx.x;
    int f = threadIdx.x;  // 64
    __shared__ float sh[64];
    float p = 0.f;
#pragma unroll
    for (int q = 0; q < 8; q++) p += partials[((size_t)b * 8 + q) * 64 + f];
    float h = hG[b * 64 + f] + p * (1.f / 256.f);
    sh[f] = h;
    __syncthreads();
    float acc = bl2[f];
#pragma unroll
    for (int k = 0; k < 64; k++) acc = fmaf(sh[k], Wl2[k * 64 + f], acc);
    acc = lrelu(acc, 0.01f);
    float pr = acc * Wl3[f];
#pragma unroll
    for (int off = 32; off > 0; off >>= 1) pr += __shfl_down(pr, off, 64);
    if (f == 0) out[b] = 1.f / (1.f + __expf(-(pr + bl3[0])));
}

extern "C" void kernel_launch(void* const* d_in, const int* in_sizes, int n_in,
                              void* d_out, int out_size, void* d_ws, size_t ws_size,
                              hipStream_t stream) {
    const float* x = (const float*)d_in[0];
    const int* ei = (const int*)d_in[1];
    const float* points = (const float*)d_in[2];
    const float* W1 = (const float*)d_in[3];
    const float* b1 = (const float*)d_in[4];
    const float* W2 = (const float*)d_in[5];
    const float* b2 = (const float*)d_in[6];
    const float* W3 = (const float*)d_in[7];
    const float* b3 = (const float*)d_in[8];
    const float* Wg1 = (const float*)d_in[9];
    const float* asrc1 = (const float*)d_in[10];
    const float* adst1 = (const float*)d_in[11];
    const float* bg1 = (const float*)d_in[12];
    const float* Wg2 = (const float*)d_in[13];
    const float* asrc2 = (const float*)d_in[14];
    const float* adst2 = (const float*)d_in[15];
    const float* bg2 = (const float*)d_in[16];
    const float* c1W = (const float*)d_in[17];
    const float* c1b = (const float*)d_in[18];
    const float* g1 = (const float*)d_in[19];
    const float* be1 = (const float*)d_in[20];
    const float* c2W = (const float*)d_in[21];
    const float* c2b = (const float*)d_in[22];
    const float* g2 = (const float*)d_in[23];
    const float* be2 = (const float*)d_in[24];
    const float* c3W = (const float*)d_in[25];
    const float* c3b = (const float*)d_in[26];
    const float* Wl2 = (const float*)d_in[27];
    const float* bl2 = (const float*)d_in[28];
    const float* Wl3 = (const float*)d_in[29];
    const float* bl3 = (const float*)d_in[30];

    const int* src = ei;
    const int* dst = ei + EE;

    // ---- workspace carve-up ----
    char* w = (char*)d_ws;
    size_t off = 0;
    auto A = [&](size_t bytes) -> void* {
        void* p = w + off;
        off = (off + bytes + 255) & ~(size_t)255;
        return p;
    };
    int* colb = (int*)A((size_t)EE * 4);
    int* rp = (int*)A((size_t)(NN + 1) * 4);
    int* gcnt = (int*)A(NBUCK * 4);
    int* bbase = (int*)A(NBUCK * 4);
    float* dinv = (float*)A((size_t)NN * 4);
    float* bufA = (float*)A((size_t)NN * 64 * 4);
    f16* bufH1 = (f16*)A((size_t)NN * 64 * 2);
    f16* bufH2 = (f16*)A((size_t)NN * 64 * 2);
    f16* ew = (f16*)A((size_t)EE * 2);
    float* wself = (float*)A((size_t)NN * 4);
    float* invden = (float*)A((size_t)NN * 4);
    float* es = (float*)A((size_t)NN * 4);
    float* edv = (float*)A((size_t)NN * 4);
    float* pooled = (float*)A((size_t)BB * CCROSS * 64 * 4);
    float* xw2 = (float*)A((size_t)BB * CCROSS * 64 * 4);
    float* es2 = (float*)A((size_t)BB * CCROSS * 4);
    float* ed2 = (float*)A((size_t)BB * CCROSS * 4);
    float* crosso = (float*)A((size_t)BB * CCROSS * 64 * 4);
    float* hG = (float*)A((size_t)BB * 64 * 4);
    float* partials = (float*)A((size_t)BB * 8 * 64 * 4);

    unsigned* buckets = (unsigned*)bufA;   // aliases bufA; dead before bufA's first real use (gat output)

    // ---- CSR build (bucketed) ----
    hipMemsetAsync(gcnt, 0, NBUCK * 4, stream);
    bucket_a_k<<<EE / 8192, 256, 0, stream>>>(src, dst, buckets, gcnt);
    bucket_scan_k<<<1, 256, 0, stream>>>(gcnt, bbase, rp);
    bucket_b_k<<<NBUCK, 256, 0, stream>>>(buckets, gcnt, bbase, rp, dinv, colb);

    // ---- points branch ----
    conv_fused_k<<<BB * 8, 256, 0, stream>>>(points, c1W, c1b, g1, be1, c2W, c2b, g2, be2, c3W, c3b, partials);

    // ---- GCN 1/2/3 + GAT gemm (fused agg+gemm chain, fp16 gather arrays) ----
    zprep_k<<<NN / 256, 256, 0, stream>>>(x, dinv, bufH1);                               // H1 = z1 [NN x 32h]
    fused_agg_gemm_k<19, 32, 0><<<NN / 32, 256, 0, stream>>>(bufH1, rp, colb, W1, dinv, b1, bufH2);  // H2 = z2 [NN x 32h]
    fused_agg_gemm_k<32, 64, 1><<<NN / 32, 256, 0, stream>>>(bufH2, rp, colb, W2, dinv, b2, bufH1);  // H1 = z3 [NN x 64h]
    fused_agg_gemm_gat_k<<<NN / 16, 256, 0, stream>>>(bufH1, rp, colb, W3, dinv, b3, Wg1, asrc1, adst1,
                                                      bufH2, es, edv);                   // H2 = xw [NN x 64h], es/ed

    // ---- GAT 1 softmax + aggregation ----
    gat_w_k<<<NN / 256, 256, 0, stream>>>(es, edv, rp, colb, ew, wself, invden);
    gat_agg_h_k<<<(NN * 16) / 256, 256, 0, stream>>>(bufH2, rp, colb, ew, wself, invden, bg1, bufA);  // bufA = gat out

    // ---- pool pieces -> cross GAT -> pool cross ----
    pool_pieces_k<<<(BB * CCROSS * 64) / 256, 256, 0, stream>>>(bufA, pooled);
    gat_gemm_k<64, 64><<<(BB * CCROSS) / 256, 256, 0, stream>>>(pooled, Wg2, xw2, asrc2, adst2, es2, ed2, BB * CCROSS);
    cross_att_k<<<(BB * CCROSS * 64) / 256, 256, 0, stream>>>(xw2, es2, ed2, bg2, crosso);
    pool_cross_k<<<BB, 64, 0, stream>>>(crosso, hG);

    // ---- head ----
    head_k<<<BB, 64, 0, stream>>>(hG, partials, Wl2, bl2, Wl3, bl3, (float*)d_out);
}

// Round 11
// 596.918 us; speedup vs baseline: 1.1066x; 1.0407x over previous
//
#include <hip/hip_runtime.h>
#include <cstdint>
#include <cstddef>

#define NN 262144
#define EE 2097152
#define BB 64
#define CCROSS 32
#define PCC 128
#define PP 2048
#define NBUCK 256
#define BCAP 12288

typedef _Float16 f16;
typedef __attribute__((ext_vector_type(4))) _Float16 f16x4;
typedef __attribute__((ext_vector_type(8))) _Float16 f16x8;

static __device__ __forceinline__ float lrelu(float x, float s) { return x > 0.f ? x : s * x; }

// ---------------- bucketed CSR build ----------------
__global__ __launch_bounds__(256) void bucket_a_k(const int* __restrict__ src, const int* __restrict__ dst,
                                                  unsigned* __restrict__ buckets, int* __restrict__ gcnt) {
    __shared__ int hist[NBUCK];
    __shared__ int base[NBUCK];
    __shared__ unsigned short rankbuf[8192];
    const int tid = threadIdx.x;
    const int e0 = blockIdx.x * 8192;
    hist[tid] = 0;
    __syncthreads();
    for (int i = tid; i < 8192; i += 256) {
        int d = dst[e0 + i];
        rankbuf[i] = (unsigned short)atomicAdd(&hist[d >> 10], 1);
    }
    __syncthreads();
    base[tid] = tid * BCAP + atomicAdd(&gcnt[tid], hist[tid]);
    __syncthreads();
    for (int i = tid; i < 8192; i += 256) {
        int s = src[e0 + i];
        int d = dst[e0 + i];
        int b = d >> 10;
        buckets[base[b] + rankbuf[i]] = ((unsigned)s << 10) | (unsigned)(d & 1023);
    }
}

__global__ void bucket_scan_k(const int* __restrict__ gcnt, int* __restrict__ bbase, int* __restrict__ rp) {
    __shared__ int tmp[256];
    int tid = threadIdx.x;
    int v = gcnt[tid];
    tmp[tid] = v;
    __syncthreads();
    for (int off = 1; off < 256; off <<= 1) {
        int t = (tid >= off) ? tmp[tid - off] : 0;
        __syncthreads();
        tmp[tid] += t;
        __syncthreads();
    }
    bbase[tid] = tmp[tid] - v;
    if (tid == 0) rp[NN] = EE;
}

__global__ __launch_bounds__(256) void bucket_b_k(const unsigned* __restrict__ buckets, const int* __restrict__ gcnt,
                                                  const int* __restrict__ bbase, int* __restrict__ rp,
                                                  float* __restrict__ dinv, int* __restrict__ col) {
    __shared__ int cnt[1024];
    __shared__ int scan[1024];
    __shared__ int wsum[256];
    const int b = blockIdx.x;
    const int tid = threadIdx.x;
    int n = gcnt[b];
    if (n > BCAP) n = BCAP;
    const unsigned* eb = buckets + (size_t)b * BCAP;
    const int gb = bbase[b];
    for (int i = tid; i < 1024; i += 256) cnt[i] = 0;
    __syncthreads();
    for (int i = tid; i < n; i += 256) atomicAdd(&cnt[eb[i] & 1023], 1);
    __syncthreads();
    int b4 = tid * 4;
    int c0 = cnt[b4], c1 = cnt[b4 + 1], c2 = cnt[b4 + 2], c3 = cnt[b4 + 3];
    int tsum = c0 + c1 + c2 + c3;
    wsum[tid] = tsum;
    __syncthreads();
    for (int off = 1; off < 256; off <<= 1) {
        int t = (tid >= off) ? wsum[tid - off] : 0;
        __syncthreads();
        wsum[tid] += t;
        __syncthreads();
    }
    int excl = wsum[tid] - tsum;
    scan[b4] = excl;
    scan[b4 + 1] = excl + c0;
    scan[b4 + 2] = excl + c0 + c1;
    scan[b4 + 3] = excl + c0 + c1 + c2;
    int vbase = b * 1024 + b4;
    rp[vbase + 0] = gb + scan[b4 + 0];
    rp[vbase + 1] = gb + scan[b4 + 1];
    rp[vbase + 2] = gb + scan[b4 + 2];
    rp[vbase + 3] = gb + scan[b4 + 3];
    dinv[vbase + 0] = rsqrtf((float)(c0 + 1));
    dinv[vbase + 1] = rsqrtf((float)(c1 + 1));
    dinv[vbase + 2] = rsqrtf((float)(c2 + 1));
    dinv[vbase + 3] = rsqrtf((float)(c3 + 1));
    __syncthreads();
    for (int i = tid; i < 1024; i += 256) cnt[i] = 0;
    __syncthreads();
    for (int i = tid; i < n; i += 256) {
        unsigned p = eb[i];
        int dl = p & 1023;
        int r = atomicAdd(&cnt[dl], 1);
        col[gb + scan[dl] + r] = (int)(p >> 10);
    }
}

// ---------------- z-prep: z1[v] = dinv[v]*x[v] fp16, padded 19 -> 32 halfs ----------------
__global__ void zprep_k(const float* __restrict__ x, const float* __restrict__ dinv, f16* __restrict__ z) {
    int v = blockIdx.x * 256 + threadIdx.x;
    if (v >= NN) return;
    float dv = dinv[v];
    const float* xr = x + (size_t)v * 19;
    float vv[20];
#pragma unroll
    for (int k = 0; k < 19; k++) vv[k] = dv * xr[k];
    vv[19] = 0.f;
    f16x4* zr = (f16x4*)(z + (size_t)v * 32);
#pragma unroll
    for (int c = 0; c < 5; c++) {
        f16x4 t = {(f16)vv[4 * c], (f16)vv[4 * c + 1], (f16)vv[4 * c + 2], (f16)vv[4 * c + 3]};
        zr[c] = t;
    }
    f16x4 zz = {(f16)0.f, (f16)0.f, (f16)0.f, (f16)0.f};
#pragma unroll
    for (int c = 5; c < 8; c++) zr[c] = zz;
}

// ---------------- fused agg (64B fp16 rows) + gemm ----------------
#define ZSTR1 36
template <int KINR, int KOUT, int ACT>
__global__ __launch_bounds__(256) void fused_agg_gemm_k(const f16* __restrict__ z, const int* __restrict__ rp,
                                                        const int* __restrict__ col, const float* __restrict__ Wg,
                                                        const float* __restrict__ dinv, const float* __restrict__ bias,
                                                        f16* __restrict__ zout) {
    constexpr int NO = KOUT / 8;
    __shared__ float Wl[32 * KOUT];
    __shared__ float zrow[32 * ZSTR1];
    const int tid = threadIdx.x;
    for (int i = tid; i < 32 * KOUT; i += 256) Wl[i] = (i < KINR * KOUT) ? Wg[i] : 0.f;

    const int r = tid >> 3;
    const int idx = tid & 7;
    const int v = blockIdx.x * 32 + r;
    const f16x4* z4 = (const f16x4*)z;
    f16x4 a = z4[(size_t)v * 8 + idx];
    float ax = (float)a.x, ay = (float)a.y, az = (float)a.z, aw = (float)a.w;
    int st = rp[v], e = rp[v + 1];
    int i = st;
    for (; i + 4 <= e; i += 4) {
        int u0 = col[i], u1 = col[i + 1], u2 = col[i + 2], u3 = col[i + 3];
        f16x4 a0 = z4[(size_t)u0 * 8 + idx];
        f16x4 a1 = z4[(size_t)u1 * 8 + idx];
        f16x4 a2 = z4[(size_t)u2 * 8 + idx];
        f16x4 a3 = z4[(size_t)u3 * 8 + idx];
        ax += ((float)a0.x + (float)a1.x) + ((float)a2.x + (float)a3.x);
        ay += ((float)a0.y + (float)a1.y) + ((float)a2.y + (float)a3.y);
        az += ((float)a0.z + (float)a1.z) + ((float)a2.z + (float)a3.z);
        aw += ((float)a0.w + (float)a1.w) + ((float)a2.w + (float)a3.w);
    }
    for (; i < e; i++) {
        f16x4 aa = z4[(size_t)col[i] * 8 + idx];
        ax += (float)aa.x; ay += (float)aa.y; az += (float)aa.z; aw += (float)aa.w;
    }
    float4 s; s.x = ax; s.y = ay; s.z = az; s.w = aw;
    *(float4*)&zrow[r * ZSTR1 + idx * 4] = s;
    __syncthreads();

    float acc[NO];
#pragma unroll
    for (int j = 0; j < NO; j++) acc[j] = 0.f;
#pragma unroll 4
    for (int k = 0; k < 32; k++) {
        float zv = zrow[r * ZSTR1 + k];
        const float* wr = Wl + k * KOUT + NO * idx;
#pragma unroll
        for (int j = 0; j < NO; j++) acc[j] = fmaf(zv, wr[j], acc[j]);
    }
    float dv = dinv[v];
    f16 hv[NO];
#pragma unroll
    for (int j = 0; j < NO; j++) {
        float o = dv * acc[j] + bias[NO * idx + j];
        o = (ACT == 0) ? fmaxf(o, 0.f) : lrelu(o, 0.01f);
        hv[j] = (f16)(o * dv);
    }
    if constexpr (NO == 4) {
        f16x4 h = {hv[0], hv[1], hv[2], hv[3]};
        *(f16x4*)(zout + (size_t)v * KOUT + NO * idx) = h;
    } else {
        f16x8 h = {hv[0], hv[1], hv[2], hv[3], hv[4], hv[5], hv[6], hv[7]};
        *(f16x8*)(zout + (size_t)v * KOUT + NO * idx) = h;
    }
}

// ---------------- standalone agg over 128B fp16 rows, fp16 out (no barrier, no imbalance coupling) ----------------
__global__ __launch_bounds__(256) void agg_h16_k(const f16* __restrict__ y, const int* __restrict__ rp,
                                                 const int* __restrict__ col, f16* __restrict__ out) {
    int gid = blockIdx.x * 256 + threadIdx.x;
    int v = gid >> 4;
    int idx = gid & 15;
    const f16x4* y4 = (const f16x4*)y;
    f16x4 a = y4[(size_t)v * 16 + idx];
    float ax = (float)a.x, ay = (float)a.y, az = (float)a.z, aw = (float)a.w;
    int s = rp[v], e = rp[v + 1];
    int i = s;
    for (; i + 4 <= e; i += 4) {
        int u0 = col[i], u1 = col[i + 1], u2 = col[i + 2], u3 = col[i + 3];
        f16x4 a0 = y4[(size_t)u0 * 16 + idx];
        f16x4 a1 = y4[(size_t)u1 * 16 + idx];
        f16x4 a2 = y4[(size_t)u2 * 16 + idx];
        f16x4 a3 = y4[(size_t)u3 * 16 + idx];
        ax += ((float)a0.x + (float)a1.x) + ((float)a2.x + (float)a3.x);
        ay += ((float)a0.y + (float)a1.y) + ((float)a2.y + (float)a3.y);
        az += ((float)a0.z + (float)a1.z) + ((float)a2.z + (float)a3.z);
        aw += ((float)a0.w + (float)a1.w) + ((float)a2.w + (float)a3.w);
    }
    for (; i < e; i++) {
        f16x4 aa = y4[(size_t)col[i] * 16 + idx];
        ax += (float)aa.x; ay += (float)aa.y; az += (float)aa.z; aw += (float)aa.w;
    }
    f16x4 r = {(f16)ax, (f16)ay, (f16)az, (f16)aw};
    ((f16x4*)out)[(size_t)v * 16 + idx] = r;
}

// ---------------- compute-only: h3 = lrelu(dinv*(aggz@W3)+b3); xw = h3@Wg1; es/ed dots ----------------
// 64 rows/block, thread tile 4 rows x 4 cols: one W b128 read serves 16 FMAs.
// zin/hh stride 68: 4-row read banks differ by 16 -> 2-way (free); float4 staging stays 16B-aligned.
#define CSTR 68
__global__ __launch_bounds__(256) void gemm3_gat_k(const f16* __restrict__ aggz, const float* __restrict__ W3,
                                                   const float* __restrict__ dinv, const float* __restrict__ b3,
                                                   const float* __restrict__ Wg1, const float* __restrict__ av,
                                                   const float* __restrict__ ad, f16* __restrict__ xw,
                                                   float* __restrict__ es, float* __restrict__ ed) {
    __shared__ float Wl[4096];
    __shared__ float zin[64 * CSTR];
    __shared__ float hh[64 * CSTR];
    const int tid = threadIdx.x;
    const int v0 = blockIdx.x * 64;
    for (int i = tid; i < 4096; i += 256) Wl[i] = W3[i];
    // stage aggz: thread t -> row t/4, k-range (t%4)*16..+16
    {
        int row = tid >> 2;
        int kb = (tid & 3) * 16;
        const f16x8* zp = (const f16x8*)(aggz + (size_t)(v0 + row) * 64 + kb);
        f16x8 z0 = zp[0], z1 = zp[1];
        float* d = &zin[row * CSTR + kb];
        float4 t0 = {(float)z0[0], (float)z0[1], (float)z0[2], (float)z0[3]};
        float4 t1 = {(float)z0[4], (float)z0[5], (float)z0[6], (float)z0[7]};
        float4 t2 = {(float)z1[0], (float)z1[1], (float)z1[2], (float)z1[3]};
        float4 t3 = {(float)z1[4], (float)z1[5], (float)z1[6], (float)z1[7]};
        *(float4*)&d[0] = t0; *(float4*)&d[4] = t1;
        *(float4*)&d[8] = t2; *(float4*)&d[12] = t3;
    }
    __syncthreads();

    const int rg = tid >> 4;   // 0..15 -> rows 4rg..4rg+3
    const int cg = tid & 15;   // 0..15 -> cols 4cg..4cg+3

    // phase 2: gemm W3
    {
        float acc0[4] = {0.f, 0.f, 0.f, 0.f}, acc1[4] = {0.f, 0.f, 0.f, 0.f};
        float acc2[4] = {0.f, 0.f, 0.f, 0.f}, acc3[4] = {0.f, 0.f, 0.f, 0.f};
#pragma unroll 4
        for (int k = 0; k < 64; k++) {
            float z0 = zin[(4 * rg + 0) * CSTR + k];
            float z1 = zin[(4 * rg + 1) * CSTR + k];
            float z2 = zin[(4 * rg + 2) * CSTR + k];
            float z3 = zin[(4 * rg + 3) * CSTR + k];
            float4 wv = *(const float4*)&Wl[k * 64 + 4 * cg];
            acc0[0] = fmaf(z0, wv.x, acc0[0]); acc0[1] = fmaf(z0, wv.y, acc0[1]);
            acc0[2] = fmaf(z0, wv.z, acc0[2]); acc0[3] = fmaf(z0, wv.w, acc0[3]);
            acc1[0] = fmaf(z1, wv.x, acc1[0]); acc1[1] = fmaf(z1, wv.y, acc1[1]);
            acc1[2] = fmaf(z1, wv.z, acc1[2]); acc1[3] = fmaf(z1, wv.w, acc1[3]);
            acc2[0] = fmaf(z2, wv.x, acc2[0]); acc2[1] = fmaf(z2, wv.y, acc2[1]);
            acc2[2] = fmaf(z2, wv.z, acc2[2]); acc2[3] = fmaf(z2, wv.w, acc2[3]);
            acc3[0] = fmaf(z3, wv.x, acc3[0]); acc3[1] = fmaf(z3, wv.y, acc3[1]);
            acc3[2] = fmaf(z3, wv.z, acc3[2]); acc3[3] = fmaf(z3, wv.w, acc3[3]);
        }
        const float4 bb = *(const float4*)&b3[4 * cg];
#pragma unroll
        for (int j = 0; j < 4; j++) {
            float* accj = (j == 0) ? acc0 : (j == 1) ? acc1 : (j == 2) ? acc2 : acc3;
            float dv = dinv[v0 + 4 * rg + j];
            float4 o;
            o.x = lrelu(dv * accj[0] + bb.x, 0.01f);
            o.y = lrelu(dv * accj[1] + bb.y, 0.01f);
            o.z = lrelu(dv * accj[2] + bb.z, 0.01f);
            o.w = lrelu(dv * accj[3] + bb.w, 0.01f);
            *(float4*)&hh[(4 * rg + j) * CSTR + 4 * cg] = o;
        }
    }
    __syncthreads();
    for (int i = tid; i < 4096; i += 256) Wl[i] = Wg1[i];
    __syncthreads();

    // phase 3: gat gemm Wg1 + dots
    {
        float g0[4] = {0.f, 0.f, 0.f, 0.f}, g1[4] = {0.f, 0.f, 0.f, 0.f};
        float g2[4] = {0.f, 0.f, 0.f, 0.f}, g3[4] = {0.f, 0.f, 0.f, 0.f};
#pragma unroll 4
        for (int k = 0; k < 64; k++) {
            float h0 = hh[(4 * rg + 0) * CSTR + k];
            float h1 = hh[(4 * rg + 1) * CSTR + k];
            float h2 = hh[(4 * rg + 2) * CSTR + k];
            float h3 = hh[(4 * rg + 3) * CSTR + k];
            float4 wv = *(const float4*)&Wl[k * 64 + 4 * cg];
            g0[0] = fmaf(h0, wv.x, g0[0]); g0[1] = fmaf(h0, wv.y, g0[1]);
            g0[2] = fmaf(h0, wv.z, g0[2]); g0[3] = fmaf(h0, wv.w, g0[3]);
            g1[0] = fmaf(h1, wv.x, g1[0]); g1[1] = fmaf(h1, wv.y, g1[1]);
            g1[2] = fmaf(h1, wv.z, g1[2]); g1[3] = fmaf(h1, wv.w, g1[3]);
            g2[0] = fmaf(h2, wv.x, g2[0]); g2[1] = fmaf(h2, wv.y, g2[1]);
            g2[2] = fmaf(h2, wv.z, g2[2]); g2[3] = fmaf(h2, wv.w, g2[3]);
            g3[0] = fmaf(h3, wv.x, g3[0]); g3[1] = fmaf(h3, wv.y, g3[1]);
            g3[2] = fmaf(h3, wv.z, g3[2]); g3[3] = fmaf(h3, wv.w, g3[3]);
        }
        const float4 a1 = *(const float4*)&av[4 * cg];
        const float4 d1 = *(const float4*)&ad[4 * cg];
        float e1[4], e2[4];
#pragma unroll
        for (int j = 0; j < 4; j++) {
            float* gj = (j == 0) ? g0 : (j == 1) ? g1 : (j == 2) ? g2 : g3;
            e1[j] = gj[0] * a1.x + gj[1] * a1.y + gj[2] * a1.z + gj[3] * a1.w;
            e2[j] = gj[0] * d1.x + gj[1] * d1.y + gj[2] * d1.z + gj[3] * d1.w;
        }
        // cg occupies lane bits 0..3 -> xor-reduce over 1,2,4,8
#pragma unroll
        for (int j = 0; j < 4; j++) {
            e1[j] += __shfl_xor(e1[j], 1); e1[j] += __shfl_xor(e1[j], 2);
            e1[j] += __shfl_xor(e1[j], 4); e1[j] += __shfl_xor(e1[j], 8);
            e2[j] += __shfl_xor(e2[j], 1); e2[j] += __shfl_xor(e2[j], 2);
            e2[j] += __shfl_xor(e2[j], 4); e2[j] += __shfl_xor(e2[j], 8);
        }
        if (cg == 0) {
#pragma unroll
            for (int j = 0; j < 4; j++) {
                es[v0 + 4 * rg + j] = e1[j];
                ed[v0 + 4 * rg + j] = e2[j];
            }
        }
#pragma unroll
        for (int j = 0; j < 4; j++) {
            float* gj = (j == 0) ? g0 : (j == 1) ? g1 : (j == 2) ? g2 : g3;
            f16x4 h = {(f16)gj[0], (f16)gj[1], (f16)gj[2], (f16)gj[3]};
            *(f16x4*)(xw + (size_t)(v0 + 4 * rg + j) * 64 + 4 * cg) = h;
        }
    }
}

// ---------------- GAT edge softmax weights (fp16 ew) ----------------
__global__ void gat_w_k(const float* __restrict__ es, const float* __restrict__ ed,
                        const int* __restrict__ rp, const int* __restrict__ col,
                        f16* __restrict__ ew, float* __restrict__ wself, float* __restrict__ invden) {
    int v = blockIdx.x * 256 + threadIdx.x;
    if (v >= NN) return;
    float edv = ed[v];
    float eself = lrelu(es[v] + edv, 0.2f);
    float m = eself;
    int s = rp[v], e = rp[v + 1];
    int i = s;
    float lg[32];
    for (; i + 4 <= e; i += 4) {
        int u0 = col[i], u1 = col[i + 1], u2 = col[i + 2], u3 = col[i + 3];
        float t0 = lrelu(es[u0] + edv, 0.2f);
        float t1 = lrelu(es[u1] + edv, 0.2f);
        float t2 = lrelu(es[u2] + edv, 0.2f);
        float t3 = lrelu(es[u3] + edv, 0.2f);
        int k = i - s;
        if (k + 3 < 32) { lg[k] = t0; lg[k + 1] = t1; lg[k + 2] = t2; lg[k + 3] = t3; }
        m = fmaxf(m, fmaxf(fmaxf(t0, t1), fmaxf(t2, t3)));
    }
    for (; i < e; i++) {
        float t = lrelu(es[col[i]] + edv, 0.2f);
        int k = i - s;
        if (k < 32) lg[k] = t;
        m = fmaxf(m, t);
    }
    float wsl = __expf(eself - m);
    float den = wsl;
    for (i = s; i < e; i++) {
        int k = i - s;
        float t = (k < 32) ? lg[k] : lrelu(es[col[i]] + edv, 0.2f);
        float w = __expf(t - m);
        ew[i] = (f16)w;
        den += w;
    }
    wself[v] = wsl;
    invden[v] = 1.f / den;
}

// ---------------- GAT aggregation over fp16 rows ----------------
__global__ __launch_bounds__(256) void gat_agg_h_k(const f16* __restrict__ y, const int* __restrict__ rp,
                                                   const int* __restrict__ col, const f16* __restrict__ ew,
                                                   const float* __restrict__ wself, const float* __restrict__ invden,
                                                   const float* __restrict__ bias, float* __restrict__ out) {
    int gid = blockIdx.x * 256 + threadIdx.x;
    int v = gid >> 4;
    int idx = gid & 15;
    const f16x4* y4 = (const f16x4*)y;
    float ws = wself[v];
    f16x4 self = y4[(size_t)v * 16 + idx];
    float accx = ws * (float)self.x, accy = ws * (float)self.y, accz = ws * (float)self.z, accw = ws * (float)self.w;
    int s = rp[v], e = rp[v + 1];
    int i = s;
    for (; i + 4 <= e; i += 4) {
        int u0 = col[i], u1 = col[i + 1], u2 = col[i + 2], u3 = col[i + 3];
        float w0 = (float)ew[i], w1 = (float)ew[i + 1], w2 = (float)ew[i + 2], w3 = (float)ew[i + 3];
        f16x4 a0 = y4[(size_t)u0 * 16 + idx];
        f16x4 a1 = y4[(size_t)u1 * 16 + idx];
        f16x4 a2 = y4[(size_t)u2 * 16 + idx];
        f16x4 a3 = y4[(size_t)u3 * 16 + idx];
        accx = fmaf(w0, (float)a0.x, fmaf(w1, (float)a1.x, fmaf(w2, (float)a2.x, fmaf(w3, (float)a3.x, accx))));
        accy = fmaf(w0, (float)a0.y, fmaf(w1, (float)a1.y, fmaf(w2, (float)a2.y, fmaf(w3, (float)a3.y, accy))));
        accz = fmaf(w0, (float)a0.z, fmaf(w1, (float)a1.z, fmaf(w2, (float)a2.z, fmaf(w3, (float)a3.z, accz))));
        accw = fmaf(w0, (float)a0.w, fmaf(w1, (float)a1.w, fmaf(w2, (float)a2.w, fmaf(w3, (float)a3.w, accw))));
    }
    for (; i < e; i++) {
        float w = (float)ew[i];
        f16x4 a = y4[(size_t)col[i] * 16 + idx];
        accx = fmaf(w, (float)a.x, accx); accy = fmaf(w, (float)a.y, accy);
        accz = fmaf(w, (float)a.z, accz); accw = fmaf(w, (float)a.w, accw);
    }
    float inv = invden[v];
    const float4* b4 = (const float4*)bias;
    float4 bb = b4[idx];
    float4 r;
    r.x = accx * inv + bb.x; r.y = accy * inv + bb.y;
    r.z = accz * inv + bb.z; r.w = accw * inv + bb.w;
    ((float4*)out)[(size_t)v * 16 + idx] = r;
}

// ---------------- pooling ----------------
__global__ void pool_pieces_k(const float* __restrict__ in, float* __restrict__ out) {
    int gid = blockIdx.x * 256 + threadIdx.x;
    if (gid >= BB * CCROSS * 64) return;
    int f = gid & 63, g = gid >> 6;
    const float* p = in + (size_t)g * PCC * 64 + f;
    float s = 0.f;
#pragma unroll 8
    for (int i = 0; i < PCC; i++) s += p[(size_t)i * 64];
    out[gid] = s * (1.f / 128.f);
}

__global__ void pool_cross_k(const float* __restrict__ in, float* __restrict__ out) {
    int gid = blockIdx.x * 64 + threadIdx.x;
    if (gid >= BB * 64) return;
    int f = gid & 63, b = gid >> 6;
    const float* p = in + (size_t)b * CCROSS * 64 + f;
    float s = 0.f;
#pragma unroll
    for (int i = 0; i < CCROSS; i++) s += p[(size_t)i * 64];
    out[gid] = s * (1.f / 32.f);
}

// ---------------- GAT input gemm (fp32, small cross-graph path) ----------------
template <int KIN, int KOUT>
__global__ void gat_gemm_k(const float* __restrict__ x, const float* __restrict__ W,
                           float* __restrict__ y, const float* __restrict__ av, const float* __restrict__ ad,
                           float* __restrict__ es, float* __restrict__ ed, int n) {
    int v = blockIdx.x * 256 + threadIdx.x;
    if (v >= n) return;
    const float* xr = x + (size_t)v * KIN;
    float acc[KOUT];
#pragma unroll
    for (int j = 0; j < KOUT; j++) acc[j] = 0.f;
#pragma unroll 2
    for (int k = 0; k < KIN; k++) {
        float xv = xr[k];
#pragma unroll
        for (int j = 0; j < KOUT; j++) acc[j] = fmaf(xv, W[k * KOUT + j], acc[j]);
    }
    float e1 = 0.f, e2 = 0.f;
    float4* y4 = (float4*)(y + (size_t)v * KOUT);
#pragma unroll
    for (int j4 = 0; j4 < KOUT / 4; j4++) {
        float4 t;
        t.x = acc[4 * j4 + 0]; t.y = acc[4 * j4 + 1]; t.z = acc[4 * j4 + 2]; t.w = acc[4 * j4 + 3];
        y4[j4] = t;
        e1 = fmaf(t.x, av[4 * j4 + 0], e1); e1 = fmaf(t.y, av[4 * j4 + 1], e1);
        e1 = fmaf(t.z, av[4 * j4 + 2], e1); e1 = fmaf(t.w, av[4 * j4 + 3], e1);
        e2 = fmaf(t.x, ad[4 * j4 + 0], e2); e2 = fmaf(t.y, ad[4 * j4 + 1], e2);
        e2 = fmaf(t.z, ad[4 * j4 + 2], e2); e2 = fmaf(t.w, ad[4 * j4 + 3], e2);
    }
    es[v] = e1; ed[v] = e2;
}

// ---------------- dense cross-graph GAT ----------------
__global__ void cross_att_k(const float* __restrict__ xw, const float* __restrict__ es,
                            const float* __restrict__ ed, const float* __restrict__ bg,
                            float* __restrict__ out) {
    int gid = blockIdx.x * 256 + threadIdx.x;
    if (gid >= BB * CCROSS * 64) return;
    int f = gid & 63;
    int d = (gid >> 6) & 31;
    int g = gid >> 11;
    int base = g * CCROSS;
    float edd = ed[base + d];
    float m = -1e30f;
#pragma unroll
    for (int s = 0; s < CCROSS; s++) {
        float e = lrelu(es[base + s] + edd, 0.2f);
        m = fmaxf(m, e);
    }
    float den = 0.f, acc = 0.f;
#pragma unroll
    for (int s = 0; s < CCROSS; s++) {
        float e = lrelu(es[base + s] + edd, 0.2f);
        float w = __expf(e - m) * ((s == d) ? 1.f : 2.f);
        den += w;
        acc = fmaf(w, xw[(size_t)(base + s) * 64 + f], acc);
    }
    out[gid] = acc / den + bg[f];
}

// ---------------- fused conv branch ----------------
#define S0_STR 264
#define S1_STR 132
#define S2_STR 66
#define S0_OFF 0
#define S1_OFF (3 * S0_STR)
#define S2_OFF (S1_OFF + 32 * S1_STR)
#define SMEM_FLOATS (S2_OFF + 64 * S2_STR)

__global__ __launch_bounds__(256) void conv_fused_k(
        const float* __restrict__ pts, const float* __restrict__ c1W, const float* __restrict__ c1b,
        const float* __restrict__ g1, const float* __restrict__ be1,
        const float* __restrict__ c2W, const float* __restrict__ c2b,
        const float* __restrict__ g2, const float* __restrict__ be2,
        const float* __restrict__ c3W, const float* __restrict__ c3b,
        float* __restrict__ partials) {
    __shared__ float smem[SMEM_FLOATS];
    float* s0 = smem + S0_OFF;
    float* s1 = smem + S1_OFF;
    float* s2 = smem + S2_OFF;
    float* s3 = smem;

    const int b = blockIdx.x >> 3;
    const int q = blockIdx.x & 7;
    const int tid = threadIdx.x;
    const float bnscale = 0.99999500003749968f;

    const int lo0 = 256 * q - 7;
    for (int t = tid; t < 3 * 263; t += 256) {
        int c = t / 263, j = t - c * 263;
        int p = lo0 + j;
        s0[c * S0_STR + j] = (p >= 0 && p < PP) ? pts[((size_t)b * 3 + c) * PP + p] : 0.f;
    }
    __syncthreads();

    const int lo1 = 128 * q - 3;
    for (int t = tid; t < 32 * 131; t += 256) {
        int ch = t / 131, j = t - ch * 131;
        int p1 = lo1 + j;
        float v = 0.f;
        if (p1 >= 0 && p1 < 1024) {
            float acc = c1b[ch];
            const float* w = c1W + ch * 9;
            const float* x0 = s0 + 2 * j;
#pragma unroll
            for (int ci = 0; ci < 3; ci++) {
                acc = fmaf(x0[ci * S0_STR + 0], w[ci * 3 + 0], acc);
                acc = fmaf(x0[ci * S0_STR + 1], w[ci * 3 + 1], acc);
                acc = fmaf(x0[ci * S0_STR + 2], w[ci * 3 + 2], acc);
            }
            acc = lrelu(acc, 0.01f);
            v = fmaf(acc, g1[ch] * bnscale, be1[ch]);
        }
        s1[ch * S1_STR + j] = v;
    }
    __syncthreads();

    const int lo2 = 64 * q - 1;
    for (int t = tid; t < 64 * 65; t += 256) {
        int ch = t / 65, j = t - ch * 65;
        int p2 = lo2 + j;
        float v = 0.f;
        if (p2 >= 0 && p2 < 512) {
            float acc = c2b[ch];
            const float* w = c2W + ch * 96;
            const float* x1 = s1 + 2 * j;
#pragma unroll
            for (int ci = 0; ci < 32; ci++) {
                acc = fmaf(x1[ci * S1_STR + 0], w[ci * 3 + 0], acc);
                acc = fmaf(x1[ci * S1_STR + 1], w[ci * 3 + 1], acc);
                acc = fmaf(x1[ci * S1_STR + 2], w[ci * 3 + 2], acc);
            }
            acc = lrelu(acc, 0.01f);
            v = fmaf(acc, g2[ch] * bnscale, be2[ch]);
        }
        s2[ch * S2_STR + j] = v;
    }
    __syncthreads();

    for (int t = tid; t < 64 * 32; t += 256) {
        int o = t >> 5, j = t & 31;
        float acc = c3b[o];
        const float* w = c3W + o * 192;
        const float* x2 = s2 + 2 * j;
#pragma unroll 16
        for (int ci = 0; ci < 64; ci++) {
            acc = fmaf(x2[ci * S2_STR + 0], w[ci * 3 + 0], acc);
            acc = fmaf(x2[ci * S2_STR + 1], w[ci * 3 + 1], acc);
            acc = fmaf(x2[ci * S2_STR + 2], w[ci * 3 + 2], acc);
        }
        s3[t] = lrelu(acc, 0.01f);
    }
    __syncthreads();

    if (tid < 64) {
        float s = 0.f;
#pragma unroll
        for (int j = 0; j < 32; j++) s += s3[tid * 32 + j];
        partials[((size_t)b * 8 + q) * 64 + tid] = s;
    }
}

// ---------------- head ----------------
__global__ void head_k(const float* __restrict__ hG, const float* __restrict__ partials,
                       const float* __restrict__ Wl2, const float* __restrict__ bl2,
                       const float* __restrict__ Wl3, const float* __restrict__ bl3,
                       float* __restrict__ out) {
    int b = blockIdx.x;
    int f = threadIdx.x;  // 64
    __shared__ float sh[64];
    float p = 0.f;
#pragma unroll
    for (int q = 0; q < 8; q++) p += partials[((size_t)b * 8 + q) * 64 + f];
    float h = hG[b * 64 + f] + p * (1.f / 256.f);
    sh[f] = h;
    __syncthreads();
    float acc = bl2[f];
#pragma unroll
    for (int k = 0; k < 64; k++) acc = fmaf(sh[k], Wl2[k * 64 + f], acc);
    acc = lrelu(acc, 0.01f);
    float pr = acc * Wl3[f];
#pragma unroll
    for (int off = 32; off > 0; off >>= 1) pr += __shfl_down(pr, off, 64);
    if (f == 0) out[b] = 1.f / (1.f + __expf(-(pr + bl3[0])));
}

extern "C" void kernel_launch(void* const* d_in, const int* in_sizes, int n_in,
                              void* d_out, int out_size, void* d_ws, size_t ws_size,
                              hipStream_t stream) {
    const float* x = (const float*)d_in[0];
    const int* ei = (const int*)d_in[1];
    const float* points = (const float*)d_in[2];
    const float* W1 = (const float*)d_in[3];
    const float* b1 = (const float*)d_in[4];
    const float* W2 = (const float*)d_in[5];
    const float* b2 = (const float*)d_in[6];
    const float* W3 = (const float*)d_in[7];
    const float* b3 = (const float*)d_in[8];
    const float* Wg1 = (const float*)d_in[9];
    const float* asrc1 = (const float*)d_in[10];
    const float* adst1 = (const float*)d_in[11];
    const float* bg1 = (const float*)d_in[12];
    const float* Wg2 = (const float*)d_in[13];
    const float* asrc2 = (const float*)d_in[14];
    const float* adst2 = (const float*)d_in[15];
    const float* bg2 = (const float*)d_in[16];
    const float* c1W = (const float*)d_in[17];
    const float* c1b = (const float*)d_in[18];
    const float* g1 = (const float*)d_in[19];
    const float* be1 = (const float*)d_in[20];
    const float* c2W = (const float*)d_in[21];
    const float* c2b = (const float*)d_in[22];
    const float* g2 = (const float*)d_in[23];
    const float* be2 = (const float*)d_in[24];
    const float* c3W = (const float*)d_in[25];
    const float* c3b = (const float*)d_in[26];
    const float* Wl2 = (const float*)d_in[27];
    const float* bl2 = (const float*)d_in[28];
    const float* Wl3 = (const float*)d_in[29];
    const float* bl3 = (const float*)d_in[30];

    const int* src = ei;
    const int* dst = ei + EE;

    // ---- workspace carve-up ----
    char* w = (char*)d_ws;
    size_t off = 0;
    auto A = [&](size_t bytes) -> void* {
        void* p = w + off;
        off = (off + bytes + 255) & ~(size_t)255;
        return p;
    };
    int* colb = (int*)A((size_t)EE * 4);
    int* rp = (int*)A((size_t)(NN + 1) * 4);
    int* gcnt = (int*)A(NBUCK * 4);
    int* bbase = (int*)A(NBUCK * 4);
    float* dinv = (float*)A((size_t)NN * 4);
    float* bufA = (float*)A((size_t)NN * 64 * 4);
    f16* bufH1 = (f16*)A((size_t)NN * 64 * 2);
    f16* bufH2 = (f16*)A((size_t)NN * 64 * 2);
    f16* ew = (f16*)A((size_t)EE * 2);
    float* wself = (float*)A((size_t)NN * 4);
    float* invden = (float*)A((size_t)NN * 4);
    float* es = (float*)A((size_t)NN * 4);
    float* edv = (float*)A((size_t)NN * 4);
    float* pooled = (float*)A((size_t)BB * CCROSS * 64 * 4);
    float* xw2 = (float*)A((size_t)BB * CCROSS * 64 * 4);
    float* es2 = (float*)A((size_t)BB * CCROSS * 4);
    float* ed2 = (float*)A((size_t)BB * CCROSS * 4);
    float* crosso = (float*)A((size_t)BB * CCROSS * 64 * 4);
    float* hG = (float*)A((size_t)BB * 64 * 4);
    float* partials = (float*)A((size_t)BB * 8 * 64 * 4);

    unsigned* buckets = (unsigned*)bufA;   // aliases bufA; dead before bufA's reuse below
    f16* aggH = (f16*)bufA;                // agg(z3) fp16 [NN x 64h]; dead before gat output overwrites bufA

    // ---- CSR build (bucketed) ----
    hipMemsetAsync(gcnt, 0, NBUCK * 4, stream);
    bucket_a_k<<<EE / 8192, 256, 0, stream>>>(src, dst, buckets, gcnt);
    bucket_scan_k<<<1, 256, 0, stream>>>(gcnt, bbase, rp);
    bucket_b_k<<<NBUCK, 256, 0, stream>>>(buckets, gcnt, bbase, rp, dinv, colb);

    // ---- points branch ----
    conv_fused_k<<<BB * 8, 256, 0, stream>>>(points, c1W, c1b, g1, be1, c2W, c2b, g2, be2, c3W, c3b, partials);

    // ---- GCN 1/2 (fused agg+gemm), GCN3+GAT gemm (standalone agg + register-blocked compute) ----
    zprep_k<<<NN / 256, 256, 0, stream>>>(x, dinv, bufH1);                               // H1 = z1 [NN x 32h]
    fused_agg_gemm_k<19, 32, 0><<<NN / 32, 256, 0, stream>>>(bufH1, rp, colb, W1, dinv, b1, bufH2);  // H2 = z2 [NN x 32h]
    fused_agg_gemm_k<32, 64, 1><<<NN / 32, 256, 0, stream>>>(bufH2, rp, colb, W2, dinv, b2, bufH1);  // H1 = z3 [NN x 64h]
    agg_h16_k<<<(NN * 16) / 256, 256, 0, stream>>>(bufH1, rp, colb, aggH);               // aggH = agg(z3)
    gemm3_gat_k<<<NN / 64, 256, 0, stream>>>(aggH, W3, dinv, b3, Wg1, asrc1, adst1,
                                             bufH2, es, edv);                            // H2 = xw, es/ed

    // ---- GAT 1 softmax + aggregation ----
    gat_w_k<<<NN / 256, 256, 0, stream>>>(es, edv, rp, colb, ew, wself, invden);
    gat_agg_h_k<<<(NN * 16) / 256, 256, 0, stream>>>(bufH2, rp, colb, ew, wself, invden, bg1, bufA);  // bufA = gat out

    // ---- pool pieces -> cross GAT -> pool cross ----
    pool_pieces_k<<<(BB * CCROSS * 64) / 256, 256, 0, stream>>>(bufA, pooled);
    gat_gemm_k<64, 64><<<(BB * CCROSS) / 256, 256, 0, stream>>>(pooled, Wg2, xw2, asrc2, adst2, es2, ed2, BB * CCROSS);
    cross_att_k<<<(BB * CCROSS * 64) / 256, 256, 0, stream>>>(xw2, es2, ed2, bg2, crosso);
    pool_cross_k<<<BB, 64, 0, stream>>>(crosso, hG);

    // ---- head ----
    head_k<<<BB, 64, 0, stream>>>(hG, partials, Wl2, bl2, Wl3, bl3, (float*)d_out);
}

// Round 12
// 595.316 us; speedup vs baseline: 1.1096x; 1.0027x over previous
//
#include <hip/hip_runtime.h>
#include <cstdint>
#include <cstddef>

#define NN 262144
#define EE 2097152
#define BB 64
#define CCROSS 32
#define PCC 128
#define PP 2048
#define NBUCK 256
#define BCAP 12288

typedef _Float16 f16;
typedef __attribute__((ext_vector_type(4))) _Float16 f16x4;
typedef __attribute__((ext_vector_type(8))) _Float16 f16x8;

static __device__ __forceinline__ float lrelu(float x, float s) { return x > 0.f ? x : s * x; }

// ---------------- bucketed CSR build ----------------
__global__ __launch_bounds__(256) void bucket_a_k(const int* __restrict__ src, const int* __restrict__ dst,
                                                  unsigned* __restrict__ buckets, int* __restrict__ gcnt) {
    __shared__ int hist[NBUCK];
    __shared__ int base[NBUCK];
    __shared__ unsigned short rankbuf[8192];
    const int tid = threadIdx.x;
    const int e0 = blockIdx.x * 8192;
    hist[tid] = 0;
    __syncthreads();
    for (int i = tid; i < 8192; i += 256) {
        int d = dst[e0 + i];
        rankbuf[i] = (unsigned short)atomicAdd(&hist[d >> 10], 1);
    }
    __syncthreads();
    base[tid] = tid * BCAP + atomicAdd(&gcnt[tid], hist[tid]);
    __syncthreads();
    for (int i = tid; i < 8192; i += 256) {
        int s = src[e0 + i];
        int d = dst[e0 + i];
        int b = d >> 10;
        buckets[base[b] + rankbuf[i]] = ((unsigned)s << 10) | (unsigned)(d & 1023);
    }
}

__global__ void bucket_scan_k(const int* __restrict__ gcnt, int* __restrict__ bbase, int* __restrict__ rp) {
    __shared__ int tmp[256];
    int tid = threadIdx.x;
    int v = gcnt[tid];
    tmp[tid] = v;
    __syncthreads();
    for (int off = 1; off < 256; off <<= 1) {
        int t = (tid >= off) ? tmp[tid - off] : 0;
        __syncthreads();
        tmp[tid] += t;
        __syncthreads();
    }
    bbase[tid] = tmp[tid] - v;
    if (tid == 0) rp[NN] = EE;
}

__global__ __launch_bounds__(256) void bucket_b_k(const unsigned* __restrict__ buckets, const int* __restrict__ gcnt,
                                                  const int* __restrict__ bbase, int* __restrict__ rp,
                                                  float* __restrict__ dinv, int* __restrict__ col) {
    __shared__ int cnt[1024];
    __shared__ int scan[1024];
    __shared__ int wsum[256];
    const int b = blockIdx.x;
    const int tid = threadIdx.x;
    int n = gcnt[b];
    if (n > BCAP) n = BCAP;
    const unsigned* eb = buckets + (size_t)b * BCAP;
    const int gb = bbase[b];
    for (int i = tid; i < 1024; i += 256) cnt[i] = 0;
    __syncthreads();
    for (int i = tid; i < n; i += 256) atomicAdd(&cnt[eb[i] & 1023], 1);
    __syncthreads();
    int b4 = tid * 4;
    int c0 = cnt[b4], c1 = cnt[b4 + 1], c2 = cnt[b4 + 2], c3 = cnt[b4 + 3];
    int tsum = c0 + c1 + c2 + c3;
    wsum[tid] = tsum;
    __syncthreads();
    for (int off = 1; off < 256; off <<= 1) {
        int t = (tid >= off) ? wsum[tid - off] : 0;
        __syncthreads();
        wsum[tid] += t;
        __syncthreads();
    }
    int excl = wsum[tid] - tsum;
    scan[b4] = excl;
    scan[b4 + 1] = excl + c0;
    scan[b4 + 2] = excl + c0 + c1;
    scan[b4 + 3] = excl + c0 + c1 + c2;
    int vbase = b * 1024 + b4;
    rp[vbase + 0] = gb + scan[b4 + 0];
    rp[vbase + 1] = gb + scan[b4 + 1];
    rp[vbase + 2] = gb + scan[b4 + 2];
    rp[vbase + 3] = gb + scan[b4 + 3];
    dinv[vbase + 0] = rsqrtf((float)(c0 + 1));
    dinv[vbase + 1] = rsqrtf((float)(c1 + 1));
    dinv[vbase + 2] = rsqrtf((float)(c2 + 1));
    dinv[vbase + 3] = rsqrtf((float)(c3 + 1));
    __syncthreads();
    for (int i = tid; i < 1024; i += 256) cnt[i] = 0;
    __syncthreads();
    for (int i = tid; i < n; i += 256) {
        unsigned p = eb[i];
        int dl = p & 1023;
        int r = atomicAdd(&cnt[dl], 1);
        col[gb + scan[dl] + r] = (int)(p >> 10);
    }
}

// ---------------- z-prep: z1[v] = dinv[v]*x[v] fp16, padded 19 -> 32 halfs ----------------
__global__ void zprep_k(const float* __restrict__ x, const float* __restrict__ dinv, f16* __restrict__ z) {
    int v = blockIdx.x * 256 + threadIdx.x;
    if (v >= NN) return;
    float dv = dinv[v];
    const float* xr = x + (size_t)v * 19;
    float vv[20];
#pragma unroll
    for (int k = 0; k < 19; k++) vv[k] = dv * xr[k];
    vv[19] = 0.f;
    f16x4* zr = (f16x4*)(z + (size_t)v * 32);
#pragma unroll
    for (int c = 0; c < 5; c++) {
        f16x4 t = {(f16)vv[4 * c], (f16)vv[4 * c + 1], (f16)vv[4 * c + 2], (f16)vv[4 * c + 3]};
        zr[c] = t;
    }
    f16x4 zz = {(f16)0.f, (f16)0.f, (f16)0.f, (f16)0.f};
#pragma unroll
    for (int c = 5; c < 8; c++) zr[c] = zz;
}

// ---------------- fused agg (64B fp16 rows) + gemm ----------------
#define ZSTR1 36
template <int KINR, int KOUT, int ACT>
__global__ __launch_bounds__(256) void fused_agg_gemm_k(const f16* __restrict__ z, const int* __restrict__ rp,
                                                        const int* __restrict__ col, const float* __restrict__ Wg,
                                                        const float* __restrict__ dinv, const float* __restrict__ bias,
                                                        f16* __restrict__ zout) {
    constexpr int NO = KOUT / 8;
    __shared__ float Wl[32 * KOUT];
    __shared__ float zrow[32 * ZSTR1];
    const int tid = threadIdx.x;
    for (int i = tid; i < 32 * KOUT; i += 256) Wl[i] = (i < KINR * KOUT) ? Wg[i] : 0.f;

    const int r = tid >> 3;
    const int idx = tid & 7;
    const int v = blockIdx.x * 32 + r;
    const f16x4* z4 = (const f16x4*)z;
    f16x4 a = z4[(size_t)v * 8 + idx];
    float ax = (float)a.x, ay = (float)a.y, az = (float)a.z, aw = (float)a.w;
    int st = rp[v], e = rp[v + 1];
    int i = st;
    for (; i + 4 <= e; i += 4) {
        int u0 = col[i], u1 = col[i + 1], u2 = col[i + 2], u3 = col[i + 3];
        f16x4 a0 = z4[(size_t)u0 * 8 + idx];
        f16x4 a1 = z4[(size_t)u1 * 8 + idx];
        f16x4 a2 = z4[(size_t)u2 * 8 + idx];
        f16x4 a3 = z4[(size_t)u3 * 8 + idx];
        ax += ((float)a0.x + (float)a1.x) + ((float)a2.x + (float)a3.x);
        ay += ((float)a0.y + (float)a1.y) + ((float)a2.y + (float)a3.y);
        az += ((float)a0.z + (float)a1.z) + ((float)a2.z + (float)a3.z);
        aw += ((float)a0.w + (float)a1.w) + ((float)a2.w + (float)a3.w);
    }
    for (; i < e; i++) {
        f16x4 aa = z4[(size_t)col[i] * 8 + idx];
        ax += (float)aa.x; ay += (float)aa.y; az += (float)aa.z; aw += (float)aa.w;
    }
    float4 s; s.x = ax; s.y = ay; s.z = az; s.w = aw;
    *(float4*)&zrow[r * ZSTR1 + idx * 4] = s;
    __syncthreads();

    float acc[NO];
#pragma unroll
    for (int j = 0; j < NO; j++) acc[j] = 0.f;
#pragma unroll 4
    for (int k = 0; k < 32; k++) {
        float zv = zrow[r * ZSTR1 + k];
        const float* wr = Wl + k * KOUT + NO * idx;
#pragma unroll
        for (int j = 0; j < NO; j++) acc[j] = fmaf(zv, wr[j], acc[j]);
    }
    float dv = dinv[v];
    f16 hv[NO];
#pragma unroll
    for (int j = 0; j < NO; j++) {
        float o = dv * acc[j] + bias[NO * idx + j];
        o = (ACT == 0) ? fmaxf(o, 0.f) : lrelu(o, 0.01f);
        hv[j] = (f16)(o * dv);
    }
    if constexpr (NO == 4) {
        f16x4 h = {hv[0], hv[1], hv[2], hv[3]};
        *(f16x4*)(zout + (size_t)v * KOUT + NO * idx) = h;
    } else {
        f16x8 h = {hv[0], hv[1], hv[2], hv[3], hv[4], hv[5], hv[6], hv[7]};
        *(f16x8*)(zout + (size_t)v * KOUT + NO * idx) = h;
    }
}

// ---------------- standalone agg over 128B fp16 rows, fp16 out ----------------
__global__ __launch_bounds__(256) void agg_h16_k(const f16* __restrict__ y, const int* __restrict__ rp,
                                                 const int* __restrict__ col, f16* __restrict__ out) {
    int gid = blockIdx.x * 256 + threadIdx.x;
    int v = gid >> 4;
    int idx = gid & 15;
    const f16x4* y4 = (const f16x4*)y;
    f16x4 a = y4[(size_t)v * 16 + idx];
    float ax = (float)a.x, ay = (float)a.y, az = (float)a.z, aw = (float)a.w;
    int s = rp[v], e = rp[v + 1];
    int i = s;
    for (; i + 4 <= e; i += 4) {
        int u0 = col[i], u1 = col[i + 1], u2 = col[i + 2], u3 = col[i + 3];
        f16x4 a0 = y4[(size_t)u0 * 16 + idx];
        f16x4 a1 = y4[(size_t)u1 * 16 + idx];
        f16x4 a2 = y4[(size_t)u2 * 16 + idx];
        f16x4 a3 = y4[(size_t)u3 * 16 + idx];
        ax += ((float)a0.x + (float)a1.x) + ((float)a2.x + (float)a3.x);
        ay += ((float)a0.y + (float)a1.y) + ((float)a2.y + (float)a3.y);
        az += ((float)a0.z + (float)a1.z) + ((float)a2.z + (float)a3.z);
        aw += ((float)a0.w + (float)a1.w) + ((float)a2.w + (float)a3.w);
    }
    for (; i < e; i++) {
        f16x4 aa = y4[(size_t)col[i] * 16 + idx];
        ax += (float)aa.x; ay += (float)aa.y; az += (float)aa.z; aw += (float)aa.w;
    }
    f16x4 r = {(f16)ax, (f16)ay, (f16)az, (f16)aw};
    ((f16x4*)out)[(size_t)v * 16 + idx] = r;
}

// ---------------- compute-only: h3 = lrelu(dinv*(aggz@W3)+b3); xw = h3@Wg1; es/ed dots ----------------
// 64 rows/block, thread tile 4 rows x 4 cols, k chunked by 4 (vector LDS reads).
// zin/hh fp16, row stride 72 halfs (144B): row+4 -> bank+16 => 2-way (free). LDS 34816 B -> 4 blocks/CU.
#define HSTR 72
__global__ __launch_bounds__(256) void gemm3_gat_k(const f16* __restrict__ aggz, const float* __restrict__ W3,
                                                   const float* __restrict__ dinv, const float* __restrict__ b3,
                                                   const float* __restrict__ Wg1, const float* __restrict__ av,
                                                   const float* __restrict__ ad, f16* __restrict__ xw,
                                                   float* __restrict__ es, float* __restrict__ ed) {
    __shared__ float Wl[4096];
    __shared__ f16 zin[64 * HSTR];
    __shared__ f16 hh[64 * HSTR];
    const int tid = threadIdx.x;
    const int v0 = blockIdx.x * 64;
    for (int i = tid; i < 4096; i += 256) Wl[i] = W3[i];
    // stage aggz rows directly as fp16: thread t -> row t/4, 16-half chunk (t%4)
    {
        int row = tid >> 2;
        int kb = (tid & 3) * 16;
        const f16x8* zp = (const f16x8*)(aggz + (size_t)(v0 + row) * 64 + kb);
        f16x8 z0 = zp[0], z1 = zp[1];
        *(f16x8*)&zin[row * HSTR + kb] = z0;
        *(f16x8*)&zin[row * HSTR + kb + 8] = z1;
    }
    __syncthreads();

    const int rg = tid >> 4;   // 0..15 -> rows 4rg..4rg+3
    const int cg = tid & 15;   // 0..15 -> cols 4cg..4cg+3

    // phase 2: gemm W3 (k chunks of 4: 4x ds_read_b64 z + 4x b128 W per 64 FMAs)
    {
        float acc0[4] = {0.f, 0.f, 0.f, 0.f}, acc1[4] = {0.f, 0.f, 0.f, 0.f};
        float acc2[4] = {0.f, 0.f, 0.f, 0.f}, acc3[4] = {0.f, 0.f, 0.f, 0.f};
#pragma unroll 4
        for (int kc = 0; kc < 16; kc++) {
            int kb = 4 * kc;
            f16x4 zr0 = *(const f16x4*)&zin[(4 * rg + 0) * HSTR + kb];
            f16x4 zr1 = *(const f16x4*)&zin[(4 * rg + 1) * HSTR + kb];
            f16x4 zr2 = *(const f16x4*)&zin[(4 * rg + 2) * HSTR + kb];
            f16x4 zr3 = *(const f16x4*)&zin[(4 * rg + 3) * HSTR + kb];
#pragma unroll
            for (int kk = 0; kk < 4; kk++) {
                float4 wv = *(const float4*)&Wl[(kb + kk) * 64 + 4 * cg];
                float z0 = (float)zr0[kk], z1 = (float)zr1[kk], z2 = (float)zr2[kk], z3 = (float)zr3[kk];
                acc0[0] = fmaf(z0, wv.x, acc0[0]); acc0[1] = fmaf(z0, wv.y, acc0[1]);
                acc0[2] = fmaf(z0, wv.z, acc0[2]); acc0[3] = fmaf(z0, wv.w, acc0[3]);
                acc1[0] = fmaf(z1, wv.x, acc1[0]); acc1[1] = fmaf(z1, wv.y, acc1[1]);
                acc1[2] = fmaf(z1, wv.z, acc1[2]); acc1[3] = fmaf(z1, wv.w, acc1[3]);
                acc2[0] = fmaf(z2, wv.x, acc2[0]); acc2[1] = fmaf(z2, wv.y, acc2[1]);
                acc2[2] = fmaf(z2, wv.z, acc2[2]); acc2[3] = fmaf(z2, wv.w, acc2[3]);
                acc3[0] = fmaf(z3, wv.x, acc3[0]); acc3[1] = fmaf(z3, wv.y, acc3[1]);
                acc3[2] = fmaf(z3, wv.z, acc3[2]); acc3[3] = fmaf(z3, wv.w, acc3[3]);
            }
        }
        const float4 bb = *(const float4*)&b3[4 * cg];
#pragma unroll
        for (int j = 0; j < 4; j++) {
            float* accj = (j == 0) ? acc0 : (j == 1) ? acc1 : (j == 2) ? acc2 : acc3;
            float dv = dinv[v0 + 4 * rg + j];
            f16x4 o = {(f16)lrelu(dv * accj[0] + bb.x, 0.01f),
                       (f16)lrelu(dv * accj[1] + bb.y, 0.01f),
                       (f16)lrelu(dv * accj[2] + bb.z, 0.01f),
                       (f16)lrelu(dv * accj[3] + bb.w, 0.01f)};
            *(f16x4*)&hh[(4 * rg + j) * HSTR + 4 * cg] = o;
        }
    }
    __syncthreads();
    for (int i = tid; i < 4096; i += 256) Wl[i] = Wg1[i];
    __syncthreads();

    // phase 3: gat gemm Wg1 + dots
    {
        float g0[4] = {0.f, 0.f, 0.f, 0.f}, g1[4] = {0.f, 0.f, 0.f, 0.f};
        float g2[4] = {0.f, 0.f, 0.f, 0.f}, g3[4] = {0.f, 0.f, 0.f, 0.f};
#pragma unroll 4
        for (int kc = 0; kc < 16; kc++) {
            int kb = 4 * kc;
            f16x4 hr0 = *(const f16x4*)&hh[(4 * rg + 0) * HSTR + kb];
            f16x4 hr1 = *(const f16x4*)&hh[(4 * rg + 1) * HSTR + kb];
            f16x4 hr2 = *(const f16x4*)&hh[(4 * rg + 2) * HSTR + kb];
            f16x4 hr3 = *(const f16x4*)&hh[(4 * rg + 3) * HSTR + kb];
#pragma unroll
            for (int kk = 0; kk < 4; kk++) {
                float4 wv = *(const float4*)&Wl[(kb + kk) * 64 + 4 * cg];
                float h0 = (float)hr0[kk], h1 = (float)hr1[kk], h2 = (float)hr2[kk], h3 = (float)hr3[kk];
                g0[0] = fmaf(h0, wv.x, g0[0]); g0[1] = fmaf(h0, wv.y, g0[1]);
                g0[2] = fmaf(h0, wv.z, g0[2]); g0[3] = fmaf(h0, wv.w, g0[3]);
                g1[0] = fmaf(h1, wv.x, g1[0]); g1[1] = fmaf(h1, wv.y, g1[1]);
                g1[2] = fmaf(h1, wv.z, g1[2]); g1[3] = fmaf(h1, wv.w, g1[3]);
                g2[0] = fmaf(h2, wv.x, g2[0]); g2[1] = fmaf(h2, wv.y, g2[1]);
                g2[2] = fmaf(h2, wv.z, g2[2]); g2[3] = fmaf(h2, wv.w, g2[3]);
                g3[0] = fmaf(h3, wv.x, g3[0]); g3[1] = fmaf(h3, wv.y, g3[1]);
                g3[2] = fmaf(h3, wv.z, g3[2]); g3[3] = fmaf(h3, wv.w, g3[3]);
            }
        }
        const float4 a1 = *(const float4*)&av[4 * cg];
        const float4 d1 = *(const float4*)&ad[4 * cg];
        float e1[4], e2[4];
#pragma unroll
        for (int j = 0; j < 4; j++) {
            float* gj = (j == 0) ? g0 : (j == 1) ? g1 : (j == 2) ? g2 : g3;
            e1[j] = gj[0] * a1.x + gj[1] * a1.y + gj[2] * a1.z + gj[3] * a1.w;
            e2[j] = gj[0] * d1.x + gj[1] * d1.y + gj[2] * d1.z + gj[3] * d1.w;
        }
#pragma unroll
        for (int j = 0; j < 4; j++) {
            e1[j] += __shfl_xor(e1[j], 1); e1[j] += __shfl_xor(e1[j], 2);
            e1[j] += __shfl_xor(e1[j], 4); e1[j] += __shfl_xor(e1[j], 8);
            e2[j] += __shfl_xor(e2[j], 1); e2[j] += __shfl_xor(e2[j], 2);
            e2[j] += __shfl_xor(e2[j], 4); e2[j] += __shfl_xor(e2[j], 8);
        }
        if (cg == 0) {
#pragma unroll
            for (int j = 0; j < 4; j++) {
                es[v0 + 4 * rg + j] = e1[j];
                ed[v0 + 4 * rg + j] = e2[j];
            }
        }
#pragma unroll
        for (int j = 0; j < 4; j++) {
            float* gj = (j == 0) ? g0 : (j == 1) ? g1 : (j == 2) ? g2 : g3;
            f16x4 h = {(f16)gj[0], (f16)gj[1], (f16)gj[2], (f16)gj[3]};
            *(f16x4*)(xw + (size_t)(v0 + 4 * rg + j) * 64 + 4 * cg) = h;
        }
    }
}

// ---------------- GAT edge softmax weights (fp16 ew) ----------------
__global__ void gat_w_k(const float* __restrict__ es, const float* __restrict__ ed,
                        const int* __restrict__ rp, const int* __restrict__ col,
                        f16* __restrict__ ew, float* __restrict__ wself, float* __restrict__ invden) {
    int v = blockIdx.x * 256 + threadIdx.x;
    if (v >= NN) return;
    float edv = ed[v];
    float eself = lrelu(es[v] + edv, 0.2f);
    float m = eself;
    int s = rp[v], e = rp[v + 1];
    int i = s;
    float lg[32];
    for (; i + 4 <= e; i += 4) {
        int u0 = col[i], u1 = col[i + 1], u2 = col[i + 2], u3 = col[i + 3];
        float t0 = lrelu(es[u0] + edv, 0.2f);
        float t1 = lrelu(es[u1] + edv, 0.2f);
        float t2 = lrelu(es[u2] + edv, 0.2f);
        float t3 = lrelu(es[u3] + edv, 0.2f);
        int k = i - s;
        if (k + 3 < 32) { lg[k] = t0; lg[k + 1] = t1; lg[k + 2] = t2; lg[k + 3] = t3; }
        m = fmaxf(m, fmaxf(fmaxf(t0, t1), fmaxf(t2, t3)));
    }
    for (; i < e; i++) {
        float t = lrelu(es[col[i]] + edv, 0.2f);
        int k = i - s;
        if (k < 32) lg[k] = t;
        m = fmaxf(m, t);
    }
    float wsl = __expf(eself - m);
    float den = wsl;
    for (i = s; i < e; i++) {
        int k = i - s;
        float t = (k < 32) ? lg[k] : lrelu(es[col[i]] + edv, 0.2f);
        float w = __expf(t - m);
        ew[i] = (f16)w;
        den += w;
    }
    wself[v] = wsl;
    invden[v] = 1.f / den;
}

// ---------------- GAT aggregation over fp16 rows ----------------
__global__ __launch_bounds__(256) void gat_agg_h_k(const f16* __restrict__ y, const int* __restrict__ rp,
                                                   const int* __restrict__ col, const f16* __restrict__ ew,
                                                   const float* __restrict__ wself, const float* __restrict__ invden,
                                                   const float* __restrict__ bias, float* __restrict__ out) {
    int gid = blockIdx.x * 256 + threadIdx.x;
    int v = gid >> 4;
    int idx = gid & 15;
    const f16x4* y4 = (const f16x4*)y;
    float ws = wself[v];
    f16x4 self = y4[(size_t)v * 16 + idx];
    float accx = ws * (float)self.x, accy = ws * (float)self.y, accz = ws * (float)self.z, accw = ws * (float)self.w;
    int s = rp[v], e = rp[v + 1];
    int i = s;
    for (; i + 4 <= e; i += 4) {
        int u0 = col[i], u1 = col[i + 1], u2 = col[i + 2], u3 = col[i + 3];
        float w0 = (float)ew[i], w1 = (float)ew[i + 1], w2 = (float)ew[i + 2], w3 = (float)ew[i + 3];
        f16x4 a0 = y4[(size_t)u0 * 16 + idx];
        f16x4 a1 = y4[(size_t)u1 * 16 + idx];
        f16x4 a2 = y4[(size_t)u2 * 16 + idx];
        f16x4 a3 = y4[(size_t)u3 * 16 + idx];
        accx = fmaf(w0, (float)a0.x, fmaf(w1, (float)a1.x, fmaf(w2, (float)a2.x, fmaf(w3, (float)a3.x, accx))));
        accy = fmaf(w0, (float)a0.y, fmaf(w1, (float)a1.y, fmaf(w2, (float)a2.y, fmaf(w3, (float)a3.y, accy))));
        accz = fmaf(w0, (float)a0.z, fmaf(w1, (float)a1.z, fmaf(w2, (float)a2.z, fmaf(w3, (float)a3.z, accz))));
        accw = fmaf(w0, (float)a0.w, fmaf(w1, (float)a1.w, fmaf(w2, (float)a2.w, fmaf(w3, (float)a3.w, accw))));
    }
    for (; i < e; i++) {
        float w = (float)ew[i];
        f16x4 a = y4[(size_t)col[i] * 16 + idx];
        accx = fmaf(w, (float)a.x, accx); accy = fmaf(w, (float)a.y, accy);
        accz = fmaf(w, (float)a.z, accz); accw = fmaf(w, (float)a.w, accw);
    }
    float inv = invden[v];
    const float4* b4 = (const float4*)bias;
    float4 bb = b4[idx];
    float4 r;
    r.x = accx * inv + bb.x; r.y = accy * inv + bb.y;
    r.z = accz * inv + bb.z; r.w = accw * inv + bb.w;
    ((float4*)out)[(size_t)v * 16 + idx] = r;
}

// ---------------- pooling ----------------
__global__ void pool_pieces_k(const float* __restrict__ in, float* __restrict__ out) {
    int gid = blockIdx.x * 256 + threadIdx.x;
    if (gid >= BB * CCROSS * 64) return;
    int f = gid & 63, g = gid >> 6;
    const float* p = in + (size_t)g * PCC * 64 + f;
    float s = 0.f;
#pragma unroll 8
    for (int i = 0; i < PCC; i++) s += p[(size_t)i * 64];
    out[gid] = s * (1.f / 128.f);
}

__global__ void pool_cross_k(const float* __restrict__ in, float* __restrict__ out) {
    int gid = blockIdx.x * 64 + threadIdx.x;
    if (gid >= BB * 64) return;
    int f = gid & 63, b = gid >> 6;
    const float* p = in + (size_t)b * CCROSS * 64 + f;
    float s = 0.f;
#pragma unroll
    for (int i = 0; i < CCROSS; i++) s += p[(size_t)i * 64];
    out[gid] = s * (1.f / 32.f);
}

// ---------------- GAT input gemm (fp32, small cross-graph path) ----------------
template <int KIN, int KOUT>
__global__ void gat_gemm_k(const float* __restrict__ x, const float* __restrict__ W,
                           float* __restrict__ y, const float* __restrict__ av, const float* __restrict__ ad,
                           float* __restrict__ es, float* __restrict__ ed, int n) {
    int v = blockIdx.x * 256 + threadIdx.x;
    if (v >= n) return;
    const float* xr = x + (size_t)v * KIN;
    float acc[KOUT];
#pragma unroll
    for (int j = 0; j < KOUT; j++) acc[j] = 0.f;
#pragma unroll 2
    for (int k = 0; k < KIN; k++) {
        float xv = xr[k];
#pragma unroll
        for (int j = 0; j < KOUT; j++) acc[j] = fmaf(xv, W[k * KOUT + j], acc[j]);
    }
    float e1 = 0.f, e2 = 0.f;
    float4* y4 = (float4*)(y + (size_t)v * KOUT);
#pragma unroll
    for (int j4 = 0; j4 < KOUT / 4; j4++) {
        float4 t;
        t.x = acc[4 * j4 + 0]; t.y = acc[4 * j4 + 1]; t.z = acc[4 * j4 + 2]; t.w = acc[4 * j4 + 3];
        y4[j4] = t;
        e1 = fmaf(t.x, av[4 * j4 + 0], e1); e1 = fmaf(t.y, av[4 * j4 + 1], e1);
        e1 = fmaf(t.z, av[4 * j4 + 2], e1); e1 = fmaf(t.w, av[4 * j4 + 3], e1);
        e2 = fmaf(t.x, ad[4 * j4 + 0], e2); e2 = fmaf(t.y, ad[4 * j4 + 1], e2);
        e2 = fmaf(t.z, ad[4 * j4 + 2], e2); e2 = fmaf(t.w, ad[4 * j4 + 3], e2);
    }
    es[v] = e1; ed[v] = e2;
}

// ---------------- dense cross-graph GAT ----------------
__global__ void cross_att_k(const float* __restrict__ xw, const float* __restrict__ es,
                            const float* __restrict__ ed, const float* __restrict__ bg,
                            float* __restrict__ out) {
    int gid = blockIdx.x * 256 + threadIdx.x;
    if (gid >= BB * CCROSS * 64) return;
    int f = gid & 63;
    int d = (gid >> 6) & 31;
    int g = gid >> 11;
    int base = g * CCROSS;
    float edd = ed[base + d];
    float m = -1e30f;
#pragma unroll
    for (int s = 0; s < CCROSS; s++) {
        float e = lrelu(es[base + s] + edd, 0.2f);
        m = fmaxf(m, e);
    }
    float den = 0.f, acc = 0.f;
#pragma unroll
    for (int s = 0; s < CCROSS; s++) {
        float e = lrelu(es[base + s] + edd, 0.2f);
        float w = __expf(e - m) * ((s == d) ? 1.f : 2.f);
        den += w;
        acc = fmaf(w, xw[(size_t)(base + s) * 64 + f], acc);
    }
    out[gid] = acc / den + bg[f];
}

// ---------------- fused conv branch ----------------
#define S0_STR 264
#define S1_STR 132
#define S2_STR 66
#define S0_OFF 0
#define S1_OFF (3 * S0_STR)
#define S2_OFF (S1_OFF + 32 * S1_STR)
#define SMEM_FLOATS (S2_OFF + 64 * S2_STR)

__global__ __launch_bounds__(256) void conv_fused_k(
        const float* __restrict__ pts, const float* __restrict__ c1W, const float* __restrict__ c1b,
        const float* __restrict__ g1, const float* __restrict__ be1,
        const float* __restrict__ c2W, const float* __restrict__ c2b,
        const float* __restrict__ g2, const float* __restrict__ be2,
        const float* __restrict__ c3W, const float* __restrict__ c3b,
        float* __restrict__ partials) {
    __shared__ float smem[SMEM_FLOATS];
    float* s0 = smem + S0_OFF;
    float* s1 = smem + S1_OFF;
    float* s2 = smem + S2_OFF;
    float* s3 = smem;

    const int b = blockIdx.x >> 3;
    const int q = blockIdx.x & 7;
    const int tid = threadIdx.x;
    const float bnscale = 0.99999500003749968f;

    const int lo0 = 256 * q - 7;
    for (int t = tid; t < 3 * 263; t += 256) {
        int c = t / 263, j = t - c * 263;
        int p = lo0 + j;
        s0[c * S0_STR + j] = (p >= 0 && p < PP) ? pts[((size_t)b * 3 + c) * PP + p] : 0.f;
    }
    __syncthreads();

    const int lo1 = 128 * q - 3;
    for (int t = tid; t < 32 * 131; t += 256) {
        int ch = t / 131, j = t - ch * 131;
        int p1 = lo1 + j;
        float v = 0.f;
        if (p1 >= 0 && p1 < 1024) {
            float acc = c1b[ch];
            const float* w = c1W + ch * 9;
            const float* x0 = s0 + 2 * j;
#pragma unroll
            for (int ci = 0; ci < 3; ci++) {
                acc = fmaf(x0[ci * S0_STR + 0], w[ci * 3 + 0], acc);
                acc = fmaf(x0[ci * S0_STR + 1], w[ci * 3 + 1], acc);
                acc = fmaf(x0[ci * S0_STR + 2], w[ci * 3 + 2], acc);
            }
            acc = lrelu(acc, 0.01f);
            v = fmaf(acc, g1[ch] * bnscale, be1[ch]);
        }
        s1[ch * S1_STR + j] = v;
    }
    __syncthreads();

    const int lo2 = 64 * q - 1;
    for (int t = tid; t < 64 * 65; t += 256) {
        int ch = t / 65, j = t - ch * 65;
        int p2 = lo2 + j;
        float v = 0.f;
        if (p2 >= 0 && p2 < 512) {
            float acc = c2b[ch];
            const float* w = c2W + ch * 96;
            const float* x1 = s1 + 2 * j;
#pragma unroll
            for (int ci = 0; ci < 32; ci++) {
                acc = fmaf(x1[ci * S1_STR + 0], w[ci * 3 + 0], acc);
                acc = fmaf(x1[ci * S1_STR + 1], w[ci * 3 + 1], acc);
                acc = fmaf(x1[ci * S1_STR + 2], w[ci * 3 + 2], acc);
            }
            acc = lrelu(acc, 0.01f);
            v = fmaf(acc, g2[ch] * bnscale, be2[ch]);
        }
        s2[ch * S2_STR + j] = v;
    }
    __syncthreads();

    for (int t = tid; t < 64 * 32; t += 256) {
        int o = t >> 5, j = t & 31;
        float acc = c3b[o];
        const float* w = c3W + o * 192;
        const float* x2 = s2 + 2 * j;
#pragma unroll 16
        for (int ci = 0; ci < 64; ci++) {
            acc = fmaf(x2[ci * S2_STR + 0], w[ci * 3 + 0], acc);
            acc = fmaf(x2[ci * S2_STR + 1], w[ci * 3 + 1], acc);
            acc = fmaf(x2[ci * S2_STR + 2], w[ci * 3 + 2], acc);
        }
        s3[t] = lrelu(acc, 0.01f);
    }
    __syncthreads();

    if (tid < 64) {
        float s = 0.f;
#pragma unroll
        for (int j = 0; j < 32; j++) s += s3[tid * 32 + j];
        partials[((size_t)b * 8 + q) * 64 + tid] = s;
    }
}

// ---------------- head ----------------
__global__ void head_k(const float* __restrict__ hG, const float* __restrict__ partials,
                       const float* __restrict__ Wl2, const float* __restrict__ bl2,
                       const float* __restrict__ Wl3, const float* __restrict__ bl3,
                       float* __restrict__ out) {
    int b = blockIdx.x;
    int f = threadIdx.x;  // 64
    __shared__ float sh[64];
    float p = 0.f;
#pragma unroll
    for (int q = 0; q < 8; q++) p += partials[((size_t)b * 8 + q) * 64 + f];
    float h = hG[b * 64 + f] + p * (1.f / 256.f);
    sh[f] = h;
    __syncthreads();
    float acc = bl2[f];
#pragma unroll
    for (int k = 0; k < 64; k++) acc = fmaf(sh[k], Wl2[k * 64 + f], acc);
    acc = lrelu(acc, 0.01f);
    float pr = acc * Wl3[f];
#pragma unroll
    for (int off = 32; off > 0; off >>= 1) pr += __shfl_down(pr, off, 64);
    if (f == 0) out[b] = 1.f / (1.f + __expf(-(pr + bl3[0])));
}

extern "C" void kernel_launch(void* const* d_in, const int* in_sizes, int n_in,
                              void* d_out, int out_size, void* d_ws, size_t ws_size,
                              hipStream_t stream) {
    const float* x = (const float*)d_in[0];
    const int* ei = (const int*)d_in[1];
    const float* points = (const float*)d_in[2];
    const float* W1 = (const float*)d_in[3];
    const float* b1 = (const float*)d_in[4];
    const float* W2 = (const float*)d_in[5];
    const float* b2 = (const float*)d_in[6];
    const float* W3 = (const float*)d_in[7];
    const float* b3 = (const float*)d_in[8];
    const float* Wg1 = (const float*)d_in[9];
    const float* asrc1 = (const float*)d_in[10];
    const float* adst1 = (const float*)d_in[11];
    const float* bg1 = (const float*)d_in[12];
    const float* Wg2 = (const float*)d_in[13];
    const float* asrc2 = (const float*)d_in[14];
    const float* adst2 = (const float*)d_in[15];
    const float* bg2 = (const float*)d_in[16];
    const float* c1W = (const float*)d_in[17];
    const float* c1b = (const float*)d_in[18];
    const float* g1 = (const float*)d_in[19];
    const float* be1 = (const float*)d_in[20];
    const float* c2W = (const float*)d_in[21];
    const float* c2b = (const float*)d_in[22];
    const float* g2 = (const float*)d_in[23];
    const float* be2 = (const float*)d_in[24];
    const float* c3W = (const float*)d_in[25];
    const float* c3b = (const float*)d_in[26];
    const float* Wl2 = (const float*)d_in[27];
    const float* bl2 = (const float*)d_in[28];
    const float* Wl3 = (const float*)d_in[29];
    const float* bl3 = (const float*)d_in[30];

    const int* src = ei;
    const int* dst = ei + EE;

    // ---- workspace carve-up ----
    char* w = (char*)d_ws;
    size_t off = 0;
    auto A = [&](size_t bytes) -> void* {
        void* p = w + off;
        off = (off + bytes + 255) & ~(size_t)255;
        return p;
    };
    int* colb = (int*)A((size_t)EE * 4);
    int* rp = (int*)A((size_t)(NN + 1) * 4);
    int* gcnt = (int*)A(NBUCK * 4);
    int* bbase = (int*)A(NBUCK * 4);
    float* dinv = (float*)A((size_t)NN * 4);
    float* bufA = (float*)A((size_t)NN * 64 * 4);
    f16* bufH1 = (f16*)A((size_t)NN * 64 * 2);
    f16* bufH2 = (f16*)A((size_t)NN * 64 * 2);
    f16* ew = (f16*)A((size_t)EE * 2);
    float* wself = (float*)A((size_t)NN * 4);
    float* invden = (float*)A((size_t)NN * 4);
    float* es = (float*)A((size_t)NN * 4);
    float* edv = (float*)A((size_t)NN * 4);
    float* pooled = (float*)A((size_t)BB * CCROSS * 64 * 4);
    float* xw2 = (float*)A((size_t)BB * CCROSS * 64 * 4);
    float* es2 = (float*)A((size_t)BB * CCROSS * 4);
    float* ed2 = (float*)A((size_t)BB * CCROSS * 4);
    float* crosso = (float*)A((size_t)BB * CCROSS * 64 * 4);
    float* hG = (float*)A((size_t)BB * 64 * 4);
    float* partials = (float*)A((size_t)BB * 8 * 64 * 4);

    unsigned* buckets = (unsigned*)bufA;   // aliases bufA; dead before bufA's reuse below
    f16* aggH = (f16*)bufA;                // agg(z3) fp16 [NN x 64h]; dead before gat output overwrites bufA

    // ---- CSR build (bucketed) ----
    hipMemsetAsync(gcnt, 0, NBUCK * 4, stream);
    bucket_a_k<<<EE / 8192, 256, 0, stream>>>(src, dst, buckets, gcnt);
    bucket_scan_k<<<1, 256, 0, stream>>>(gcnt, bbase, rp);
    bucket_b_k<<<NBUCK, 256, 0, stream>>>(buckets, gcnt, bbase, rp, dinv, colb);

    // ---- points branch ----
    conv_fused_k<<<BB * 8, 256, 0, stream>>>(points, c1W, c1b, g1, be1, c2W, c2b, g2, be2, c3W, c3b, partials);

    // ---- GCN 1/2 (fused agg+gemm), GCN3+GAT gemm (standalone agg + register-blocked compute) ----
    zprep_k<<<NN / 256, 256, 0, stream>>>(x, dinv, bufH1);                               // H1 = z1 [NN x 32h]
    fused_agg_gemm_k<19, 32, 0><<<NN / 32, 256, 0, stream>>>(bufH1, rp, colb, W1, dinv, b1, bufH2);  // H2 = z2 [NN x 32h]
    fused_agg_gemm_k<32, 64, 1><<<NN / 32, 256, 0, stream>>>(bufH2, rp, colb, W2, dinv, b2, bufH1);  // H1 = z3 [NN x 64h]
    agg_h16_k<<<(NN * 16) / 256, 256, 0, stream>>>(bufH1, rp, colb, aggH);               // aggH = agg(z3)
    gemm3_gat_k<<<NN / 64, 256, 0, stream>>>(aggH, W3, dinv, b3, Wg1, asrc1, adst1,
                                             bufH2, es, edv);                            // H2 = xw, es/ed

    // ---- GAT 1 softmax + aggregation ----
    gat_w_k<<<NN / 256, 256, 0, stream>>>(es, edv, rp, colb, ew, wself, invden);
    gat_agg_h_k<<<(NN * 16) / 256, 256, 0, stream>>>(bufH2, rp, colb, ew, wself, invden, bg1, bufA);  // bufA = gat out

    // ---- pool pieces -> cross GAT -> pool cross ----
    pool_pieces_k<<<(BB * CCROSS * 64) / 256, 256, 0, stream>>>(bufA, pooled);
    gat_gemm_k<64, 64><<<(BB * CCROSS) / 256, 256, 0, stream>>>(pooled, Wg2, xw2, asrc2, adst2, es2, ed2, BB * CCROSS);
    cross_att_k<<<(BB * CCROSS * 64) / 256, 256, 0, stream>>>(xw2, es2, ed2, bg2, crosso);
    pool_cross_k<<<BB, 64, 0, stream>>>(crosso, hG);

    // ---- head ----
    head_k<<<BB, 64, 0, stream>>>(hG, partials, Wl2, bl2, Wl3, bl3, (float*)d_out);
}

// Round 13
// 555.339 us; speedup vs baseline: 1.1895x; 1.0720x over previous
//
#include <hip/hip_runtime.h>
#include <cstdint>
#include <cstddef>

#define NN 262144
#define EE 2097152
#define BB 64
#define CCROSS 32
#define PCC 128
#define PP 2048
#define NBUCK 256
#define BCAP 12288

typedef _Float16 f16;
typedef __attribute__((ext_vector_type(4))) _Float16 f16x4;
typedef __attribute__((ext_vector_type(8))) _Float16 f16x8;
typedef __attribute__((ext_vector_type(4))) float f32x4;

static __device__ __forceinline__ float lrelu(float x, float s) { return x > 0.f ? x : s * x; }

// ---------------- bucketed CSR build ----------------
__global__ __launch_bounds__(256) void bucket_a_k(const int* __restrict__ src, const int* __restrict__ dst,
                                                  unsigned* __restrict__ buckets, int* __restrict__ gcnt) {
    __shared__ int hist[NBUCK];
    __shared__ int base[NBUCK];
    __shared__ unsigned short rankbuf[8192];
    const int tid = threadIdx.x;
    const int e0 = blockIdx.x * 8192;
    hist[tid] = 0;
    __syncthreads();
    for (int i = tid; i < 8192; i += 256) {
        int d = dst[e0 + i];
        rankbuf[i] = (unsigned short)atomicAdd(&hist[d >> 10], 1);
    }
    __syncthreads();
    base[tid] = tid * BCAP + atomicAdd(&gcnt[tid], hist[tid]);
    __syncthreads();
    for (int i = tid; i < 8192; i += 256) {
        int s = src[e0 + i];
        int d = dst[e0 + i];
        int b = d >> 10;
        buckets[base[b] + rankbuf[i]] = ((unsigned)s << 10) | (unsigned)(d & 1023);
    }
}

__global__ void bucket_scan_k(const int* __restrict__ gcnt, int* __restrict__ bbase, int* __restrict__ rp) {
    __shared__ int tmp[256];
    int tid = threadIdx.x;
    int v = gcnt[tid];
    tmp[tid] = v;
    __syncthreads();
    for (int off = 1; off < 256; off <<= 1) {
        int t = (tid >= off) ? tmp[tid - off] : 0;
        __syncthreads();
        tmp[tid] += t;
        __syncthreads();
    }
    bbase[tid] = tmp[tid] - v;
    if (tid == 0) rp[NN] = EE;
}

__global__ __launch_bounds__(256) void bucket_b_k(const unsigned* __restrict__ buckets, const int* __restrict__ gcnt,
                                                  const int* __restrict__ bbase, int* __restrict__ rp,
                                                  float* __restrict__ dinv, int* __restrict__ col) {
    __shared__ int cnt[1024];
    __shared__ int scan[1024];
    __shared__ int wsum[256];
    const int b = blockIdx.x;
    const int tid = threadIdx.x;
    int n = gcnt[b];
    if (n > BCAP) n = BCAP;
    const unsigned* eb = buckets + (size_t)b * BCAP;
    const int gb = bbase[b];
    for (int i = tid; i < 1024; i += 256) cnt[i] = 0;
    __syncthreads();
    for (int i = tid; i < n; i += 256) atomicAdd(&cnt[eb[i] & 1023], 1);
    __syncthreads();
    int b4 = tid * 4;
    int c0 = cnt[b4], c1 = cnt[b4 + 1], c2 = cnt[b4 + 2], c3 = cnt[b4 + 3];
    int tsum = c0 + c1 + c2 + c3;
    wsum[tid] = tsum;
    __syncthreads();
    for (int off = 1; off < 256; off <<= 1) {
        int t = (tid >= off) ? wsum[tid - off] : 0;
        __syncthreads();
        wsum[tid] += t;
        __syncthreads();
    }
    int excl = wsum[tid] - tsum;
    scan[b4] = excl;
    scan[b4 + 1] = excl + c0;
    scan[b4 + 2] = excl + c0 + c1;
    scan[b4 + 3] = excl + c0 + c1 + c2;
    int vbase = b * 1024 + b4;
    rp[vbase + 0] = gb + scan[b4 + 0];
    rp[vbase + 1] = gb + scan[b4 + 1];
    rp[vbase + 2] = gb + scan[b4 + 2];
    rp[vbase + 3] = gb + scan[b4 + 3];
    dinv[vbase + 0] = rsqrtf((float)(c0 + 1));
    dinv[vbase + 1] = rsqrtf((float)(c1 + 1));
    dinv[vbase + 2] = rsqrtf((float)(c2 + 1));
    dinv[vbase + 3] = rsqrtf((float)(c3 + 1));
    __syncthreads();
    for (int i = tid; i < 1024; i += 256) cnt[i] = 0;
    __syncthreads();
    for (int i = tid; i < n; i += 256) {
        unsigned p = eb[i];
        int dl = p & 1023;
        int r = atomicAdd(&cnt[dl], 1);
        col[gb + scan[dl] + r] = (int)(p >> 10);
    }
}

// ---------------- z-prep ----------------
__global__ void zprep_k(const float* __restrict__ x, const float* __restrict__ dinv, f16* __restrict__ z) {
    int v = blockIdx.x * 256 + threadIdx.x;
    if (v >= NN) return;
    float dv = dinv[v];
    const float* xr = x + (size_t)v * 19;
    float vv[20];
#pragma unroll
    for (int k = 0; k < 19; k++) vv[k] = dv * xr[k];
    vv[19] = 0.f;
    f16x4* zr = (f16x4*)(z + (size_t)v * 32);
#pragma unroll
    for (int c = 0; c < 5; c++) {
        f16x4 t = {(f16)vv[4 * c], (f16)vv[4 * c + 1], (f16)vv[4 * c + 2], (f16)vv[4 * c + 3]};
        zr[c] = t;
    }
    f16x4 zz = {(f16)0.f, (f16)0.f, (f16)0.f, (f16)0.f};
#pragma unroll
    for (int c = 5; c < 8; c++) zr[c] = zz;
}

// ---------------- fused agg (64B fp16 rows) + gemm ----------------
#define ZSTR1 36
template <int KINR, int KOUT, int ACT>
__global__ __launch_bounds__(256) void fused_agg_gemm_k(const f16* __restrict__ z, const int* __restrict__ rp,
                                                        const int* __restrict__ col, const float* __restrict__ Wg,
                                                        const float* __restrict__ dinv, const float* __restrict__ bias,
                                                        f16* __restrict__ zout) {
    constexpr int NO = KOUT / 8;
    __shared__ float Wl[32 * KOUT];
    __shared__ float zrow[32 * ZSTR1];
    const int tid = threadIdx.x;
    for (int i = tid; i < 32 * KOUT; i += 256) Wl[i] = (i < KINR * KOUT) ? Wg[i] : 0.f;

    const int r = tid >> 3;
    const int idx = tid & 7;
    const int v = blockIdx.x * 32 + r;
    const f16x4* z4 = (const f16x4*)z;
    f16x4 a = z4[(size_t)v * 8 + idx];
    float ax = (float)a.x, ay = (float)a.y, az = (float)a.z, aw = (float)a.w;
    int st = rp[v], e = rp[v + 1];
    int i = st;
    for (; i + 4 <= e; i += 4) {
        int u0 = col[i], u1 = col[i + 1], u2 = col[i + 2], u3 = col[i + 3];
        f16x4 a0 = z4[(size_t)u0 * 8 + idx];
        f16x4 a1 = z4[(size_t)u1 * 8 + idx];
        f16x4 a2 = z4[(size_t)u2 * 8 + idx];
        f16x4 a3 = z4[(size_t)u3 * 8 + idx];
        ax += ((float)a0.x + (float)a1.x) + ((float)a2.x + (float)a3.x);
        ay += ((float)a0.y + (float)a1.y) + ((float)a2.y + (float)a3.y);
        az += ((float)a0.z + (float)a1.z) + ((float)a2.z + (float)a3.z);
        aw += ((float)a0.w + (float)a1.w) + ((float)a2.w + (float)a3.w);
    }
    for (; i < e; i++) {
        f16x4 aa = z4[(size_t)col[i] * 8 + idx];
        ax += (float)aa.x; ay += (float)aa.y; az += (float)aa.z; aw += (float)aa.w;
    }
    float4 s; s.x = ax; s.y = ay; s.z = az; s.w = aw;
    *(float4*)&zrow[r * ZSTR1 + idx * 4] = s;
    __syncthreads();

    float acc[NO];
#pragma unroll
    for (int j = 0; j < NO; j++) acc[j] = 0.f;
#pragma unroll 4
    for (int k = 0; k < 32; k++) {
        float zv = zrow[r * ZSTR1 + k];
        const float* wr = Wl + k * KOUT + NO * idx;
#pragma unroll
        for (int j = 0; j < NO; j++) acc[j] = fmaf(zv, wr[j], acc[j]);
    }
    float dv = dinv[v];
    f16 hv[NO];
#pragma unroll
    for (int j = 0; j < NO; j++) {
        float o = dv * acc[j] + bias[NO * idx + j];
        o = (ACT == 0) ? fmaxf(o, 0.f) : lrelu(o, 0.01f);
        hv[j] = (f16)(o * dv);
    }
    if constexpr (NO == 4) {
        f16x4 h = {hv[0], hv[1], hv[2], hv[3]};
        *(f16x4*)(zout + (size_t)v * KOUT + NO * idx) = h;
    } else {
        f16x8 h = {hv[0], hv[1], hv[2], hv[3], hv[4], hv[5], hv[6], hv[7]};
        *(f16x8*)(zout + (size_t)v * KOUT + NO * idx) = h;
    }
}

// ---------------- standalone agg over 128B fp16 rows, fp16 out ----------------
__global__ __launch_bounds__(256) void agg_h16_k(const f16* __restrict__ y, const int* __restrict__ rp,
                                                 const int* __restrict__ col, f16* __restrict__ out) {
    int gid = blockIdx.x * 256 + threadIdx.x;
    int v = gid >> 4;
    int idx = gid & 15;
    const f16x4* y4 = (const f16x4*)y;
    f16x4 a = y4[(size_t)v * 16 + idx];
    float ax = (float)a.x, ay = (float)a.y, az = (float)a.z, aw = (float)a.w;
    int s = rp[v], e = rp[v + 1];
    int i = s;
    for (; i + 4 <= e; i += 4) {
        int u0 = col[i], u1 = col[i + 1], u2 = col[i + 2], u3 = col[i + 3];
        f16x4 a0 = y4[(size_t)u0 * 16 + idx];
        f16x4 a1 = y4[(size_t)u1 * 16 + idx];
        f16x4 a2 = y4[(size_t)u2 * 16 + idx];
        f16x4 a3 = y4[(size_t)u3 * 16 + idx];
        ax += ((float)a0.x + (float)a1.x) + ((float)a2.x + (float)a3.x);
        ay += ((float)a0.y + (float)a1.y) + ((float)a2.y + (float)a3.y);
        az += ((float)a0.z + (float)a1.z) + ((float)a2.z + (float)a3.z);
        aw += ((float)a0.w + (float)a1.w) + ((float)a2.w + (float)a3.w);
    }
    for (; i < e; i++) {
        f16x4 aa = y4[(size_t)col[i] * 16 + idx];
        ax += (float)aa.x; ay += (float)aa.y; az += (float)aa.z; aw += (float)aa.w;
    }
    f16x4 r = {(f16)ax, (f16)ay, (f16)az, (f16)aw};
    ((f16x4*)out)[(size_t)v * 16 + idx] = r;
}

// ---------------- pack W (64x64 fp32 row-major k x n) into fp16 B-fragment order ----------------
// Bpack[(kt*4+c)*512 + l*8 + j] = W[(kt*32 + (l>>4)*8 + j)*64 + 16c + (l&15)]
__global__ void pack_w_k(const float* __restrict__ W, f16* __restrict__ out) {
    int o = blockIdx.x * 256 + threadIdx.x;
    if (o >= 4096) return;
    int frag = o >> 9;         // 0..7 = kt*4 + c
    int kt = frag >> 2;
    int c = frag & 3;
    int idx = o & 511;
    int l = idx >> 3;
    int j = idx & 7;
    int k = kt * 32 + ((l >> 4) << 3) + j;
    int n = 16 * c + (l & 15);
    out[o] = (f16)W[k * 64 + n];
}

// ---------------- MFMA compute: h3 = lrelu(dinv*(aggz@W3)+b3); xw = h3@Wg1; es/ed dots ----------------
// 64 rows/block = 4 waves; wave w rows 16w..16w+16. v_mfma_f32_16x16x32_f16, K=64 -> 2 steps, N=64 -> 4 col tiles.
// A: m=lane&15, k=quad*8+j (f16x8 from LDS). B: n=lane&15, k=quad*8+j (prepacked). C/D: col=lane&15, row=quad*4+reg.
#define HSTR 72
__global__ __launch_bounds__(256) void gemm3_gat_k(const f16* __restrict__ aggz, const f16* __restrict__ w3p,
                                                   const float* __restrict__ dinv, const float* __restrict__ b3,
                                                   const f16* __restrict__ wgp, const float* __restrict__ av,
                                                   const float* __restrict__ ad, f16* __restrict__ xw,
                                                   float* __restrict__ es, float* __restrict__ ed) {
    __shared__ f16 zin[64 * HSTR];
    __shared__ f16 hh[64 * HSTR];
    const int tid = threadIdx.x;
    const int v0 = blockIdx.x * 64;
    // stage aggz rows as fp16: thread t -> row t/4, 16-half chunk (t%4)
    {
        int row = tid >> 2;
        int kb = (tid & 3) * 16;
        const f16x8* zp = (const f16x8*)(aggz + (size_t)(v0 + row) * 64 + kb);
        f16x8 z0 = zp[0], z1 = zp[1];
        *(f16x8*)&zin[row * HSTR + kb] = z0;
        *(f16x8*)&zin[row * HSTR + kb + 8] = z1;
    }
    __syncthreads();

    const int w = tid >> 6;   // wave 0..3
    const int l = tid & 63;   // lane
    const int m = l & 15;
    const int q = l >> 4;     // quad
    const int r0 = 16 * w;

    f32x4 acc0 = {0.f, 0.f, 0.f, 0.f}, acc1 = acc0, acc2 = acc0, acc3 = acc0;
#pragma unroll
    for (int kt = 0; kt < 2; kt++) {
        f16x8 afrag = *(const f16x8*)&zin[(r0 + m) * HSTR + kt * 32 + q * 8];
        f16x8 b0 = *(const f16x8*)&w3p[((kt * 4 + 0) << 9) + l * 8];
        f16x8 b1 = *(const f16x8*)&w3p[((kt * 4 + 1) << 9) + l * 8];
        f16x8 b2 = *(const f16x8*)&w3p[((kt * 4 + 2) << 9) + l * 8];
        f16x8 b3f = *(const f16x8*)&w3p[((kt * 4 + 3) << 9) + l * 8];
        acc0 = __builtin_amdgcn_mfma_f32_16x16x32_f16(afrag, b0, acc0, 0, 0, 0);
        acc1 = __builtin_amdgcn_mfma_f32_16x16x32_f16(afrag, b1, acc1, 0, 0, 0);
        acc2 = __builtin_amdgcn_mfma_f32_16x16x32_f16(afrag, b2, acc2, 0, 0, 0);
        acc3 = __builtin_amdgcn_mfma_f32_16x16x32_f16(afrag, b3f, acc3, 0, 0, 0);
    }
    // epilogue 1 -> hh (fp16)
    {
        float dv0 = dinv[v0 + r0 + q * 4 + 0];
        float dv1 = dinv[v0 + r0 + q * 4 + 1];
        float dv2 = dinv[v0 + r0 + q * 4 + 2];
        float dv3 = dinv[v0 + r0 + q * 4 + 3];
#pragma unroll
        for (int c = 0; c < 4; c++) {
            const f32x4* ac = (c == 0) ? &acc0 : (c == 1) ? &acc1 : (c == 2) ? &acc2 : &acc3;
            float bb = b3[16 * c + m];
            hh[(r0 + q * 4 + 0) * HSTR + 16 * c + m] = (f16)lrelu(dv0 * (*ac)[0] + bb, 0.01f);
            hh[(r0 + q * 4 + 1) * HSTR + 16 * c + m] = (f16)lrelu(dv1 * (*ac)[1] + bb, 0.01f);
            hh[(r0 + q * 4 + 2) * HSTR + 16 * c + m] = (f16)lrelu(dv2 * (*ac)[2] + bb, 0.01f);
            hh[(r0 + q * 4 + 3) * HSTR + 16 * c + m] = (f16)lrelu(dv3 * (*ac)[3] + bb, 0.01f);
        }
    }
    __syncthreads();

    acc0 = (f32x4){0.f, 0.f, 0.f, 0.f}; acc1 = acc0; acc2 = acc0; acc3 = acc0;
#pragma unroll
    for (int kt = 0; kt < 2; kt++) {
        f16x8 afrag = *(const f16x8*)&hh[(r0 + m) * HSTR + kt * 32 + q * 8];
        f16x8 b0 = *(const f16x8*)&wgp[((kt * 4 + 0) << 9) + l * 8];
        f16x8 b1 = *(const f16x8*)&wgp[((kt * 4 + 1) << 9) + l * 8];
        f16x8 b2 = *(const f16x8*)&wgp[((kt * 4 + 2) << 9) + l * 8];
        f16x8 b3f = *(const f16x8*)&wgp[((kt * 4 + 3) << 9) + l * 8];
        acc0 = __builtin_amdgcn_mfma_f32_16x16x32_f16(afrag, b0, acc0, 0, 0, 0);
        acc1 = __builtin_amdgcn_mfma_f32_16x16x32_f16(afrag, b1, acc1, 0, 0, 0);
        acc2 = __builtin_amdgcn_mfma_f32_16x16x32_f16(afrag, b2, acc2, 0, 0, 0);
        acc3 = __builtin_amdgcn_mfma_f32_16x16x32_f16(afrag, b3f, acc3, 0, 0, 0);
    }
    // epilogue 2: xw (fp16) + es/ed
    {
        float e1[4] = {0.f, 0.f, 0.f, 0.f}, e2[4] = {0.f, 0.f, 0.f, 0.f};
#pragma unroll
        for (int c = 0; c < 4; c++) {
            const f32x4* ac = (c == 0) ? &acc0 : (c == 1) ? &acc1 : (c == 2) ? &acc2 : &acc3;
            float a1 = av[16 * c + m];
            float d1 = ad[16 * c + m];
#pragma unroll
            for (int reg = 0; reg < 4; reg++) {
                float g = (*ac)[reg];
                e1[reg] = fmaf(g, a1, e1[reg]);
                e2[reg] = fmaf(g, d1, e2[reg]);
                xw[(size_t)(v0 + r0 + q * 4 + reg) * 64 + 16 * c + m] = (f16)g;
            }
        }
#pragma unroll
        for (int reg = 0; reg < 4; reg++) {
            e1[reg] += __shfl_xor(e1[reg], 1); e1[reg] += __shfl_xor(e1[reg], 2);
            e1[reg] += __shfl_xor(e1[reg], 4); e1[reg] += __shfl_xor(e1[reg], 8);
            e2[reg] += __shfl_xor(e2[reg], 1); e2[reg] += __shfl_xor(e2[reg], 2);
            e2[reg] += __shfl_xor(e2[reg], 4); e2[reg] += __shfl_xor(e2[reg], 8);
        }
        if (m == 0) {
#pragma unroll
            for (int reg = 0; reg < 4; reg++) {
                es[v0 + r0 + q * 4 + reg] = e1[reg];
                ed[v0 + r0 + q * 4 + reg] = e2[reg];
            }
        }
    }
}

// ---------------- GAT edge softmax weights (fp16 ew) ----------------
__global__ void gat_w_k(const float* __restrict__ es, const float* __restrict__ ed,
                        const int* __restrict__ rp, const int* __restrict__ col,
                        f16* __restrict__ ew, float* __restrict__ wself, float* __restrict__ invden) {
    int v = blockIdx.x * 256 + threadIdx.x;
    if (v >= NN) return;
    float edv = ed[v];
    float eself = lrelu(es[v] + edv, 0.2f);
    float m = eself;
    int s = rp[v], e = rp[v + 1];
    int i = s;
    float lg[32];
    for (; i + 4 <= e; i += 4) {
        int u0 = col[i], u1 = col[i + 1], u2 = col[i + 2], u3 = col[i + 3];
        float t0 = lrelu(es[u0] + edv, 0.2f);
        float t1 = lrelu(es[u1] + edv, 0.2f);
        float t2 = lrelu(es[u2] + edv, 0.2f);
        float t3 = lrelu(es[u3] + edv, 0.2f);
        int k = i - s;
        if (k + 3 < 32) { lg[k] = t0; lg[k + 1] = t1; lg[k + 2] = t2; lg[k + 3] = t3; }
        m = fmaxf(m, fmaxf(fmaxf(t0, t1), fmaxf(t2, t3)));
    }
    for (; i < e; i++) {
        float t = lrelu(es[col[i]] + edv, 0.2f);
        int k = i - s;
        if (k < 32) lg[k] = t;
        m = fmaxf(m, t);
    }
    float wsl = __expf(eself - m);
    float den = wsl;
    for (i = s; i < e; i++) {
        int k = i - s;
        float t = (k < 32) ? lg[k] : lrelu(es[col[i]] + edv, 0.2f);
        float w = __expf(t - m);
        ew[i] = (f16)w;
        den += w;
    }
    wself[v] = wsl;
    invden[v] = 1.f / den;
}

// ---------------- GAT aggregation over fp16 rows ----------------
__global__ __launch_bounds__(256) void gat_agg_h_k(const f16* __restrict__ y, const int* __restrict__ rp,
                                                   const int* __restrict__ col, const f16* __restrict__ ew,
                                                   const float* __restrict__ wself, const float* __restrict__ invden,
                                                   const float* __restrict__ bias, float* __restrict__ out) {
    int gid = blockIdx.x * 256 + threadIdx.x;
    int v = gid >> 4;
    int idx = gid & 15;
    const f16x4* y4 = (const f16x4*)y;
    float ws = wself[v];
    f16x4 self = y4[(size_t)v * 16 + idx];
    float accx = ws * (float)self.x, accy = ws * (float)self.y, accz = ws * (float)self.z, accw = ws * (float)self.w;
    int s = rp[v], e = rp[v + 1];
    int i = s;
    for (; i + 4 <= e; i += 4) {
        int u0 = col[i], u1 = col[i + 1], u2 = col[i + 2], u3 = col[i + 3];
        float w0 = (float)ew[i], w1 = (float)ew[i + 1], w2 = (float)ew[i + 2], w3 = (float)ew[i + 3];
        f16x4 a0 = y4[(size_t)u0 * 16 + idx];
        f16x4 a1 = y4[(size_t)u1 * 16 + idx];
        f16x4 a2 = y4[(size_t)u2 * 16 + idx];
        f16x4 a3 = y4[(size_t)u3 * 16 + idx];
        accx = fmaf(w0, (float)a0.x, fmaf(w1, (float)a1.x, fmaf(w2, (float)a2.x, fmaf(w3, (float)a3.x, accx))));
        accy = fmaf(w0, (float)a0.y, fmaf(w1, (float)a1.y, fmaf(w2, (float)a2.y, fmaf(w3, (float)a3.y, accy))));
        accz = fmaf(w0, (float)a0.z, fmaf(w1, (float)a1.z, fmaf(w2, (float)a2.z, fmaf(w3, (float)a3.z, accz))));
        accw = fmaf(w0, (float)a0.w, fmaf(w1, (float)a1.w, fmaf(w2, (float)a2.w, fmaf(w3, (float)a3.w, accw))));
    }
    for (; i < e; i++) {
        float w = (float)ew[i];
        f16x4 a = y4[(size_t)col[i] * 16 + idx];
        accx = fmaf(w, (float)a.x, accx); accy = fmaf(w, (float)a.y, accy);
        accz = fmaf(w, (float)a.z, accz); accw = fmaf(w, (float)a.w, accw);
    }
    float inv = invden[v];
    const float4* b4 = (const float4*)bias;
    float4 bb = b4[idx];
    float4 r;
    r.x = accx * inv + bb.x; r.y = accy * inv + bb.y;
    r.z = accz * inv + bb.z; r.w = accw * inv + bb.w;
    ((float4*)out)[(size_t)v * 16 + idx] = r;
}

// ---------------- pooling ----------------
__global__ void pool_pieces_k(const float* __restrict__ in, float* __restrict__ out) {
    int gid = blockIdx.x * 256 + threadIdx.x;
    if (gid >= BB * CCROSS * 64) return;
    int f = gid & 63, g = gid >> 6;
    const float* p = in + (size_t)g * PCC * 64 + f;
    float s = 0.f;
#pragma unroll 8
    for (int i = 0; i < PCC; i++) s += p[(size_t)i * 64];
    out[gid] = s * (1.f / 128.f);
}

__global__ void pool_cross_k(const float* __restrict__ in, float* __restrict__ out) {
    int gid = blockIdx.x * 64 + threadIdx.x;
    if (gid >= BB * 64) return;
    int f = gid & 63, b = gid >> 6;
    const float* p = in + (size_t)b * CCROSS * 64 + f;
    float s = 0.f;
#pragma unroll
    for (int i = 0; i < CCROSS; i++) s += p[(size_t)i * 64];
    out[gid] = s * (1.f / 32.f);
}

// ---------------- GAT input gemm (fp32, small cross-graph path) ----------------
template <int KIN, int KOUT>
__global__ void gat_gemm_k(const float* __restrict__ x, const float* __restrict__ W,
                           float* __restrict__ y, const float* __restrict__ av, const float* __restrict__ ad,
                           float* __restrict__ es, float* __restrict__ ed, int n) {
    int v = blockIdx.x * 256 + threadIdx.x;
    if (v >= n) return;
    const float* xr = x + (size_t)v * KIN;
    float acc[KOUT];
#pragma unroll
    for (int j = 0; j < KOUT; j++) acc[j] = 0.f;
#pragma unroll 2
    for (int k = 0; k < KIN; k++) {
        float xv = xr[k];
#pragma unroll
        for (int j = 0; j < KOUT; j++) acc[j] = fmaf(xv, W[k * KOUT + j], acc[j]);
    }
    float e1 = 0.f, e2 = 0.f;
    float4* y4 = (float4*)(y + (size_t)v * KOUT);
#pragma unroll
    for (int j4 = 0; j4 < KOUT / 4; j4++) {
        float4 t;
        t.x = acc[4 * j4 + 0]; t.y = acc[4 * j4 + 1]; t.z = acc[4 * j4 + 2]; t.w = acc[4 * j4 + 3];
        y4[j4] = t;
        e1 = fmaf(t.x, av[4 * j4 + 0], e1); e1 = fmaf(t.y, av[4 * j4 + 1], e1);
        e1 = fmaf(t.z, av[4 * j4 + 2], e1); e1 = fmaf(t.w, av[4 * j4 + 3], e1);
        e2 = fmaf(t.x, ad[4 * j4 + 0], e2); e2 = fmaf(t.y, ad[4 * j4 + 1], e2);
        e2 = fmaf(t.z, ad[4 * j4 + 2], e2); e2 = fmaf(t.w, ad[4 * j4 + 3], e2);
    }
    es[v] = e1; ed[v] = e2;
}

// ---------------- dense cross-graph GAT ----------------
__global__ void cross_att_k(const float* __restrict__ xw, const float* __restrict__ es,
                            const float* __restrict__ ed, const float* __restrict__ bg,
                            float* __restrict__ out) {
    int gid = blockIdx.x * 256 + threadIdx.x;
    if (gid >= BB * CCROSS * 64) return;
    int f = gid & 63;
    int d = (gid >> 6) & 31;
    int g = gid >> 11;
    int base = g * CCROSS;
    float edd = ed[base + d];
    float m = -1e30f;
#pragma unroll
    for (int s = 0; s < CCROSS; s++) {
        float e = lrelu(es[base + s] + edd, 0.2f);
        m = fmaxf(m, e);
    }
    float den = 0.f, acc = 0.f;
#pragma unroll
    for (int s = 0; s < CCROSS; s++) {
        float e = lrelu(es[base + s] + edd, 0.2f);
        float w = __expf(e - m) * ((s == d) ? 1.f : 2.f);
        den += w;
        acc = fmaf(w, xw[(size_t)(base + s) * 64 + f], acc);
    }
    out[gid] = acc / den + bg[f];
}

// ---------------- fused conv branch ----------------
#define S0_STR 264
#define S1_STR 132
#define S2_STR 66
#define S0_OFF 0
#define S1_OFF (3 * S0_STR)
#define S2_OFF (S1_OFF + 32 * S1_STR)
#define SMEM_FLOATS (S2_OFF + 64 * S2_STR)

__global__ __launch_bounds__(256) void conv_fused_k(
        const float* __restrict__ pts, const float* __restrict__ c1W, const float* __restrict__ c1b,
        const float* __restrict__ g1, const float* __restrict__ be1,
        const float* __restrict__ c2W, const float* __restrict__ c2b,
        const float* __restrict__ g2, const float* __restrict__ be2,
        const float* __restrict__ c3W, const float* __restrict__ c3b,
        float* __restrict__ partials) {
    __shared__ float smem[SMEM_FLOATS];
    float* s0 = smem + S0_OFF;
    float* s1 = smem + S1_OFF;
    float* s2 = smem + S2_OFF;
    float* s3 = smem;

    const int b = blockIdx.x >> 3;
    const int q = blockIdx.x & 7;
    const int tid = threadIdx.x;
    const float bnscale = 0.99999500003749968f;

    const int lo0 = 256 * q - 7;
    for (int t = tid; t < 3 * 263; t += 256) {
        int c = t / 263, j = t - c * 263;
        int p = lo0 + j;
        s0[c * S0_STR + j] = (p >= 0 && p < PP) ? pts[((size_t)b * 3 + c) * PP + p] : 0.f;
    }
    __syncthreads();

    const int lo1 = 128 * q - 3;
    for (int t = tid; t < 32 * 131; t += 256) {
        int ch = t / 131, j = t - ch * 131;
        int p1 = lo1 + j;
        float v = 0.f;
        if (p1 >= 0 && p1 < 1024) {
            float acc = c1b[ch];
            const float* w = c1W + ch * 9;
            const float* x0 = s0 + 2 * j;
#pragma unroll
            for (int ci = 0; ci < 3; ci++) {
                acc = fmaf(x0[ci * S0_STR + 0], w[ci * 3 + 0], acc);
                acc = fmaf(x0[ci * S0_STR + 1], w[ci * 3 + 1], acc);
                acc = fmaf(x0[ci * S0_STR + 2], w[ci * 3 + 2], acc);
            }
            acc = lrelu(acc, 0.01f);
            v = fmaf(acc, g1[ch] * bnscale, be1[ch]);
        }
        s1[ch * S1_STR + j] = v;
    }
    __syncthreads();

    const int lo2 = 64 * q - 1;
    for (int t = tid; t < 64 * 65; t += 256) {
        int ch = t / 65, j = t - ch * 65;
        int p2 = lo2 + j;
        float v = 0.f;
        if (p2 >= 0 && p2 < 512) {
            float acc = c2b[ch];
            const float* w = c2W + ch * 96;
            const float* x1 = s1 + 2 * j;
#pragma unroll
            for (int ci = 0; ci < 32; ci++) {
                acc = fmaf(x1[ci * S1_STR + 0], w[ci * 3 + 0], acc);
                acc = fmaf(x1[ci * S1_STR + 1], w[ci * 3 + 1], acc);
                acc = fmaf(x1[ci * S1_STR + 2], w[ci * 3 + 2], acc);
            }
            acc = lrelu(acc, 0.01f);
            v = fmaf(acc, g2[ch] * bnscale, be2[ch]);
        }
        s2[ch * S2_STR + j] = v;
    }
    __syncthreads();

    for (int t = tid; t < 64 * 32; t += 256) {
        int o = t >> 5, j = t & 31;
        float acc = c3b[o];
        const float* w = c3W + o * 192;
        const float* x2 = s2 + 2 * j;
#pragma unroll 16
        for (int ci = 0; ci < 64; ci++) {
            acc = fmaf(x2[ci * S2_STR + 0], w[ci * 3 + 0], acc);
            acc = fmaf(x2[ci * S2_STR + 1], w[ci * 3 + 1], acc);
            acc = fmaf(x2[ci * S2_STR + 2], w[ci * 3 + 2], acc);
        }
        s3[t] = lrelu(acc, 0.01f);
    }
    __syncthreads();

    if (tid < 64) {
        float s = 0.f;
#pragma unroll
        for (int j = 0; j < 32; j++) s += s3[tid * 32 + j];
        partials[((size_t)b * 8 + q) * 64 + tid] = s;
    }
}

// ---------------- head ----------------
__global__ void head_k(const float* __restrict__ hG, const float* __restrict__ partials,
                       const float* __restrict__ Wl2, const float* __restrict__ bl2,
                       const float* __restrict__ Wl3, const float* __restrict__ bl3,
                       float* __restrict__ out) {
    int b = blockIdx.x;
    int f = threadIdx.x;  // 64
    __shared__ float sh[64];
    float p = 0.f;
#pragma unroll
    for (int q = 0; q < 8; q++) p += partials[((size_t)b * 8 + q) * 64 + f];
    float h = hG[b * 64 + f] + p * (1.f / 256.f);
    sh[f] = h;
    __syncthreads();
    float acc = bl2[f];
#pragma unroll
    for (int k = 0; k < 64; k++) acc = fmaf(sh[k], Wl2[k * 64 + f], acc);
    acc = lrelu(acc, 0.01f);
    float pr = acc * Wl3[f];
#pragma unroll
    for (int off = 32; off > 0; off >>= 1) pr += __shfl_down(pr, off, 64);
    if (f == 0) out[b] = 1.f / (1.f + __expf(-(pr + bl3[0])));
}

extern "C" void kernel_launch(void* const* d_in, const int* in_sizes, int n_in,
                              void* d_out, int out_size, void* d_ws, size_t ws_size,
                              hipStream_t stream) {
    const float* x = (const float*)d_in[0];
    const int* ei = (const int*)d_in[1];
    const float* points = (const float*)d_in[2];
    const float* W1 = (const float*)d_in[3];
    const float* b1 = (const float*)d_in[4];
    const float* W2 = (const float*)d_in[5];
    const float* b2 = (const float*)d_in[6];
    const float* W3 = (const float*)d_in[7];
    const float* b3 = (const float*)d_in[8];
    const float* Wg1 = (const float*)d_in[9];
    const float* asrc1 = (const float*)d_in[10];
    const float* adst1 = (const float*)d_in[11];
    const float* bg1 = (const float*)d_in[12];
    const float* Wg2 = (const float*)d_in[13];
    const float* asrc2 = (const float*)d_in[14];
    const float* adst2 = (const float*)d_in[15];
    const float* bg2 = (const float*)d_in[16];
    const float* c1W = (const float*)d_in[17];
    const float* c1b = (const float*)d_in[18];
    const float* g1 = (const float*)d_in[19];
    const float* be1 = (const float*)d_in[20];
    const float* c2W = (const float*)d_in[21];
    const float* c2b = (const float*)d_in[22];
    const float* g2 = (const float*)d_in[23];
    const float* be2 = (const float*)d_in[24];
    const float* c3W = (const float*)d_in[25];
    const float* c3b = (const float*)d_in[26];
    const float* Wl2 = (const float*)d_in[27];
    const float* bl2 = (const float*)d_in[28];
    const float* Wl3 = (const float*)d_in[29];
    const float* bl3 = (const float*)d_in[30];

    const int* src = ei;
    const int* dst = ei + EE;

    // ---- workspace carve-up ----
    char* w = (char*)d_ws;
    size_t off = 0;
    auto A = [&](size_t bytes) -> void* {
        void* p = w + off;
        off = (off + bytes + 255) & ~(size_t)255;
        return p;
    };
    int* colb = (int*)A((size_t)EE * 4);
    int* rp = (int*)A((size_t)(NN + 1) * 4);
    int* gcnt = (int*)A(NBUCK * 4);
    int* bbase = (int*)A(NBUCK * 4);
    float* dinv = (float*)A((size_t)NN * 4);
    float* bufA = (float*)A((size_t)NN * 64 * 4);
    f16* bufH1 = (f16*)A((size_t)NN * 64 * 2);
    f16* bufH2 = (f16*)A((size_t)NN * 64 * 2);
    f16* ew = (f16*)A((size_t)EE * 2);
    float* wself = (float*)A((size_t)NN * 4);
    float* invden = (float*)A((size_t)NN * 4);
    float* es = (float*)A((size_t)NN * 4);
    float* edv = (float*)A((size_t)NN * 4);
    f16* w3p = (f16*)A(4096 * 2);
    f16* wgp = (f16*)A(4096 * 2);
    float* pooled = (float*)A((size_t)BB * CCROSS * 64 * 4);
    float* xw2 = (float*)A((size_t)BB * CCROSS * 64 * 4);
    float* es2 = (float*)A((size_t)BB * CCROSS * 4);
    float* ed2 = (float*)A((size_t)BB * CCROSS * 4);
    float* crosso = (float*)A((size_t)BB * CCROSS * 64 * 4);
    float* hG = (float*)A((size_t)BB * 64 * 4);
    float* partials = (float*)A((size_t)BB * 8 * 64 * 4);

    unsigned* buckets = (unsigned*)bufA;   // aliases bufA; dead before bufA's reuse below
    f16* aggH = (f16*)bufA;                // agg(z3) fp16 [NN x 64h]; dead before gat output overwrites bufA

    // ---- CSR build (bucketed) ----
    hipMemsetAsync(gcnt, 0, NBUCK * 4, stream);
    bucket_a_k<<<EE / 8192, 256, 0, stream>>>(src, dst, buckets, gcnt);
    bucket_scan_k<<<1, 256, 0, stream>>>(gcnt, bbase, rp);
    bucket_b_k<<<NBUCK, 256, 0, stream>>>(buckets, gcnt, bbase, rp, dinv, colb);

    // ---- points branch + weight packing ----
    conv_fused_k<<<BB * 8, 256, 0, stream>>>(points, c1W, c1b, g1, be1, c2W, c2b, g2, be2, c3W, c3b, partials);
    pack_w_k<<<16, 256, 0, stream>>>(W3, w3p);
    pack_w_k<<<16, 256, 0, stream>>>(Wg1, wgp);

    // ---- GCN 1/2 (fused agg+gemm), GCN3+GAT gemm (standalone agg + MFMA compute) ----
    zprep_k<<<NN / 256, 256, 0, stream>>>(x, dinv, bufH1);                               // H1 = z1 [NN x 32h]
    fused_agg_gemm_k<19, 32, 0><<<NN / 32, 256, 0, stream>>>(bufH1, rp, colb, W1, dinv, b1, bufH2);  // H2 = z2
    fused_agg_gemm_k<32, 64, 1><<<NN / 32, 256, 0, stream>>>(bufH2, rp, colb, W2, dinv, b2, bufH1);  // H1 = z3
    agg_h16_k<<<(NN * 16) / 256, 256, 0, stream>>>(bufH1, rp, colb, aggH);               // aggH = agg(z3)
    gemm3_gat_k<<<NN / 64, 256, 0, stream>>>(aggH, w3p, dinv, b3, wgp, asrc1, adst1,
                                             bufH2, es, edv);                            // H2 = xw, es/ed

    // ---- GAT 1 softmax + aggregation ----
    gat_w_k<<<NN / 256, 256, 0, stream>>>(es, edv, rp, colb, ew, wself, invden);
    gat_agg_h_k<<<(NN * 16) / 256, 256, 0, stream>>>(bufH2, rp, colb, ew, wself, invden, bg1, bufA);  // bufA = gat out

    // ---- pool pieces -> cross GAT -> pool cross ----
    pool_pieces_k<<<(BB * CCROSS * 64) / 256, 256, 0, stream>>>(bufA, pooled);
    gat_gemm_k<64, 64><<<(BB * CCROSS) / 256, 256, 0, stream>>>(pooled, Wg2, xw2, asrc2, adst2, es2, ed2, BB * CCROSS);
    cross_att_k<<<(BB * CCROSS * 64) / 256, 256, 0, stream>>>(xw2, es2, ed2, bg2, crosso);
    pool_cross_k<<<BB, 64, 0, stream>>>(crosso, hG);

    // ---- head ----
    head_k<<<BB, 64, 0, stream>>>(hG, partials, Wl2, bl2, Wl3, bl3, (float*)d_out);
}

// Round 14
// 545.895 us; speedup vs baseline: 1.2101x; 1.0173x over previous
//
#include <hip/hip_runtime.h>
#include <cstdint>
#include <cstddef>

#define NN 262144
#define EE 2097152
#define BB 64
#define CCROSS 32
#define PCC 128
#define PP 2048
#define NBUCK 256
#define BCAP 12288

typedef _Float16 f16;
typedef __attribute__((ext_vector_type(4))) _Float16 f16x4;
typedef __attribute__((ext_vector_type(8))) _Float16 f16x8;
typedef __attribute__((ext_vector_type(4))) float f32x4;

static __device__ __forceinline__ float lrelu(float x, float s) { return x > 0.f ? x : s * x; }

// ---------------- bucketed CSR build ----------------
__global__ __launch_bounds__(256) void bucket_a_k(const int* __restrict__ src, const int* __restrict__ dst,
                                                  unsigned* __restrict__ buckets, int* __restrict__ gcnt) {
    __shared__ int hist[NBUCK];
    __shared__ int base[NBUCK];
    __shared__ unsigned short rankbuf[8192];
    const int tid = threadIdx.x;
    const int e0 = blockIdx.x * 8192;
    hist[tid] = 0;
    __syncthreads();
    for (int i = tid; i < 8192; i += 256) {
        int d = dst[e0 + i];
        rankbuf[i] = (unsigned short)atomicAdd(&hist[d >> 10], 1);
    }
    __syncthreads();
    base[tid] = tid * BCAP + atomicAdd(&gcnt[tid], hist[tid]);
    __syncthreads();
    for (int i = tid; i < 8192; i += 256) {
        int s = src[e0 + i];
        int d = dst[e0 + i];
        int b = d >> 10;
        buckets[base[b] + rankbuf[i]] = ((unsigned)s << 10) | (unsigned)(d & 1023);
    }
}

__global__ void bucket_scan_k(const int* __restrict__ gcnt, int* __restrict__ bbase, int* __restrict__ rp) {
    __shared__ int tmp[256];
    int tid = threadIdx.x;
    int v = gcnt[tid];
    tmp[tid] = v;
    __syncthreads();
    for (int off = 1; off < 256; off <<= 1) {
        int t = (tid >= off) ? tmp[tid - off] : 0;
        __syncthreads();
        tmp[tid] += t;
        __syncthreads();
    }
    bbase[tid] = tmp[tid] - v;
    if (tid == 0) rp[NN] = EE;
}

__global__ __launch_bounds__(256) void bucket_b_k(const unsigned* __restrict__ buckets, const int* __restrict__ gcnt,
                                                  const int* __restrict__ bbase, int* __restrict__ rp,
                                                  float* __restrict__ dinv, int* __restrict__ col) {
    __shared__ int cnt[1024];
    __shared__ int scan[1024];
    __shared__ int wsum[256];
    const int b = blockIdx.x;
    const int tid = threadIdx.x;
    int n = gcnt[b];
    if (n > BCAP) n = BCAP;
    const unsigned* eb = buckets + (size_t)b * BCAP;
    const int gb = bbase[b];
    for (int i = tid; i < 1024; i += 256) cnt[i] = 0;
    __syncthreads();
    for (int i = tid; i < n; i += 256) atomicAdd(&cnt[eb[i] & 1023], 1);
    __syncthreads();
    int b4 = tid * 4;
    int c0 = cnt[b4], c1 = cnt[b4 + 1], c2 = cnt[b4 + 2], c3 = cnt[b4 + 3];
    int tsum = c0 + c1 + c2 + c3;
    wsum[tid] = tsum;
    __syncthreads();
    for (int off = 1; off < 256; off <<= 1) {
        int t = (tid >= off) ? wsum[tid - off] : 0;
        __syncthreads();
        wsum[tid] += t;
        __syncthreads();
    }
    int excl = wsum[tid] - tsum;
    scan[b4] = excl;
    scan[b4 + 1] = excl + c0;
    scan[b4 + 2] = excl + c0 + c1;
    scan[b4 + 3] = excl + c0 + c1 + c2;
    int vbase = b * 1024 + b4;
    rp[vbase + 0] = gb + scan[b4 + 0];
    rp[vbase + 1] = gb + scan[b4 + 1];
    rp[vbase + 2] = gb + scan[b4 + 2];
    rp[vbase + 3] = gb + scan[b4 + 3];
    dinv[vbase + 0] = rsqrtf((float)(c0 + 1));
    dinv[vbase + 1] = rsqrtf((float)(c1 + 1));
    dinv[vbase + 2] = rsqrtf((float)(c2 + 1));
    dinv[vbase + 3] = rsqrtf((float)(c3 + 1));
    __syncthreads();
    for (int i = tid; i < 1024; i += 256) cnt[i] = 0;
    __syncthreads();
    for (int i = tid; i < n; i += 256) {
        unsigned p = eb[i];
        int dl = p & 1023;
        int r = atomicAdd(&cnt[dl], 1);
        col[gb + scan[dl] + r] = (int)(p >> 10);
    }
}

// ---------------- z-prep ----------------
__global__ void zprep_k(const float* __restrict__ x, const float* __restrict__ dinv, f16* __restrict__ z) {
    int v = blockIdx.x * 256 + threadIdx.x;
    if (v >= NN) return;
    float dv = dinv[v];
    const float* xr = x + (size_t)v * 19;
    float vv[20];
#pragma unroll
    for (int k = 0; k < 19; k++) vv[k] = dv * xr[k];
    vv[19] = 0.f;
    f16x4* zr = (f16x4*)(z + (size_t)v * 32);
#pragma unroll
    for (int c = 0; c < 5; c++) {
        f16x4 t = {(f16)vv[4 * c], (f16)vv[4 * c + 1], (f16)vv[4 * c + 2], (f16)vv[4 * c + 3]};
        zr[c] = t;
    }
    f16x4 zz = {(f16)0.f, (f16)0.f, (f16)0.f, (f16)0.f};
#pragma unroll
    for (int c = 5; c < 8; c++) zr[c] = zz;
}

// ---------------- fused agg (64B fp16 rows) + gemm ----------------
#define ZSTR1 36
template <int KINR, int KOUT, int ACT>
__global__ __launch_bounds__(256) void fused_agg_gemm_k(const f16* __restrict__ z, const int* __restrict__ rp,
                                                        const int* __restrict__ col, const float* __restrict__ Wg,
                                                        const float* __restrict__ dinv, const float* __restrict__ bias,
                                                        f16* __restrict__ zout) {
    constexpr int NO = KOUT / 8;
    __shared__ float Wl[32 * KOUT];
    __shared__ float zrow[32 * ZSTR1];
    const int tid = threadIdx.x;
    for (int i = tid; i < 32 * KOUT; i += 256) Wl[i] = (i < KINR * KOUT) ? Wg[i] : 0.f;

    const int r = tid >> 3;
    const int idx = tid & 7;
    const int v = blockIdx.x * 32 + r;
    const f16x4* z4 = (const f16x4*)z;
    f16x4 a = z4[(size_t)v * 8 + idx];
    float ax = (float)a.x, ay = (float)a.y, az = (float)a.z, aw = (float)a.w;
    int st = rp[v], e = rp[v + 1];
    int i = st;
    for (; i + 4 <= e; i += 4) {
        int u0 = col[i], u1 = col[i + 1], u2 = col[i + 2], u3 = col[i + 3];
        f16x4 a0 = z4[(size_t)u0 * 8 + idx];
        f16x4 a1 = z4[(size_t)u1 * 8 + idx];
        f16x4 a2 = z4[(size_t)u2 * 8 + idx];
        f16x4 a3 = z4[(size_t)u3 * 8 + idx];
        ax += ((float)a0.x + (float)a1.x) + ((float)a2.x + (float)a3.x);
        ay += ((float)a0.y + (float)a1.y) + ((float)a2.y + (float)a3.y);
        az += ((float)a0.z + (float)a1.z) + ((float)a2.z + (float)a3.z);
        aw += ((float)a0.w + (float)a1.w) + ((float)a2.w + (float)a3.w);
    }
    for (; i < e; i++) {
        f16x4 aa = z4[(size_t)col[i] * 8 + idx];
        ax += (float)aa.x; ay += (float)aa.y; az += (float)aa.z; aw += (float)aa.w;
    }
    float4 s; s.x = ax; s.y = ay; s.z = az; s.w = aw;
    *(float4*)&zrow[r * ZSTR1 + idx * 4] = s;
    __syncthreads();

    float acc[NO];
#pragma unroll
    for (int j = 0; j < NO; j++) acc[j] = 0.f;
#pragma unroll 4
    for (int k = 0; k < 32; k++) {
        float zv = zrow[r * ZSTR1 + k];
        const float* wr = Wl + k * KOUT + NO * idx;
#pragma unroll
        for (int j = 0; j < NO; j++) acc[j] = fmaf(zv, wr[j], acc[j]);
    }
    float dv = dinv[v];
    f16 hv[NO];
#pragma unroll
    for (int j = 0; j < NO; j++) {
        float o = dv * acc[j] + bias[NO * idx + j];
        o = (ACT == 0) ? fmaxf(o, 0.f) : lrelu(o, 0.01f);
        hv[j] = (f16)(o * dv);
    }
    if constexpr (NO == 4) {
        f16x4 h = {hv[0], hv[1], hv[2], hv[3]};
        *(f16x4*)(zout + (size_t)v * KOUT + NO * idx) = h;
    } else {
        f16x8 h = {hv[0], hv[1], hv[2], hv[3], hv[4], hv[5], hv[6], hv[7]};
        *(f16x8*)(zout + (size_t)v * KOUT + NO * idx) = h;
    }
}

// ---------------- standalone agg over 128B fp16 rows, fp16 out (8 lanes/row, f16x8 loads) ----------------
__global__ __launch_bounds__(256) void agg_h16_k(const f16* __restrict__ y, const int* __restrict__ rp,
                                                 const int* __restrict__ col, f16* __restrict__ out) {
    int gid = blockIdx.x * 256 + threadIdx.x;
    int v = gid >> 3;
    int idx = gid & 7;
    const f16x8* y8 = (const f16x8*)y;
    f16x8 a = y8[(size_t)v * 8 + idx];
    float acc[8];
#pragma unroll
    for (int j = 0; j < 8; j++) acc[j] = (float)a[j];
    int s = rp[v], e = rp[v + 1];
    int i = s;
    for (; i + 4 <= e; i += 4) {
        int u0 = col[i], u1 = col[i + 1], u2 = col[i + 2], u3 = col[i + 3];
        f16x8 a0 = y8[(size_t)u0 * 8 + idx];
        f16x8 a1 = y8[(size_t)u1 * 8 + idx];
        f16x8 a2 = y8[(size_t)u2 * 8 + idx];
        f16x8 a3 = y8[(size_t)u3 * 8 + idx];
#pragma unroll
        for (int j = 0; j < 8; j++)
            acc[j] += ((float)a0[j] + (float)a1[j]) + ((float)a2[j] + (float)a3[j]);
    }
    for (; i < e; i++) {
        f16x8 aa = y8[(size_t)col[i] * 8 + idx];
#pragma unroll
        for (int j = 0; j < 8; j++) acc[j] += (float)aa[j];
    }
    f16x8 r;
#pragma unroll
    for (int j = 0; j < 8; j++) r[j] = (f16)acc[j];
    ((f16x8*)out)[(size_t)v * 8 + idx] = r;
}

// ---------------- pack W (64x64 fp32 row-major k x n) into fp16 B-fragment order ----------------
__global__ void pack_w_k(const float* __restrict__ W, f16* __restrict__ out) {
    int o = blockIdx.x * 256 + threadIdx.x;
    if (o >= 4096) return;
    int frag = o >> 9;
    int kt = frag >> 2;
    int c = frag & 3;
    int idx = o & 511;
    int l = idx >> 3;
    int j = idx & 7;
    int k = kt * 32 + ((l >> 4) << 3) + j;
    int n = 16 * c + (l & 15);
    out[o] = (f16)W[k * 64 + n];
}

// ---------------- MFMA compute: h3 = lrelu(dinv*(aggz@W3)+b3); xw = h3@Wg1; es/ed dots ----------------
#define HSTR 72
__global__ __launch_bounds__(256) void gemm3_gat_k(const f16* __restrict__ aggz, const f16* __restrict__ w3p,
                                                   const float* __restrict__ dinv, const float* __restrict__ b3,
                                                   const f16* __restrict__ wgp, const float* __restrict__ av,
                                                   const float* __restrict__ ad, f16* __restrict__ xw,
                                                   float* __restrict__ es, float* __restrict__ ed) {
    __shared__ f16 zin[64 * HSTR];
    __shared__ f16 hh[64 * HSTR];
    const int tid = threadIdx.x;
    const int v0 = blockIdx.x * 64;
    {
        int row = tid >> 2;
        int kb = (tid & 3) * 16;
        const f16x8* zp = (const f16x8*)(aggz + (size_t)(v0 + row) * 64 + kb);
        f16x8 z0 = zp[0], z1 = zp[1];
        *(f16x8*)&zin[row * HSTR + kb] = z0;
        *(f16x8*)&zin[row * HSTR + kb + 8] = z1;
    }
    __syncthreads();

    const int w = tid >> 6;
    const int l = tid & 63;
    const int m = l & 15;
    const int q = l >> 4;
    const int r0 = 16 * w;

    f32x4 acc0 = {0.f, 0.f, 0.f, 0.f}, acc1 = acc0, acc2 = acc0, acc3 = acc0;
#pragma unroll
    for (int kt = 0; kt < 2; kt++) {
        f16x8 afrag = *(const f16x8*)&zin[(r0 + m) * HSTR + kt * 32 + q * 8];
        f16x8 b0 = *(const f16x8*)&w3p[((kt * 4 + 0) << 9) + l * 8];
        f16x8 b1 = *(const f16x8*)&w3p[((kt * 4 + 1) << 9) + l * 8];
        f16x8 b2 = *(const f16x8*)&w3p[((kt * 4 + 2) << 9) + l * 8];
        f16x8 b3f = *(const f16x8*)&w3p[((kt * 4 + 3) << 9) + l * 8];
        acc0 = __builtin_amdgcn_mfma_f32_16x16x32_f16(afrag, b0, acc0, 0, 0, 0);
        acc1 = __builtin_amdgcn_mfma_f32_16x16x32_f16(afrag, b1, acc1, 0, 0, 0);
        acc2 = __builtin_amdgcn_mfma_f32_16x16x32_f16(afrag, b2, acc2, 0, 0, 0);
        acc3 = __builtin_amdgcn_mfma_f32_16x16x32_f16(afrag, b3f, acc3, 0, 0, 0);
    }
    {
        float dv0 = dinv[v0 + r0 + q * 4 + 0];
        float dv1 = dinv[v0 + r0 + q * 4 + 1];
        float dv2 = dinv[v0 + r0 + q * 4 + 2];
        float dv3 = dinv[v0 + r0 + q * 4 + 3];
#pragma unroll
        for (int c = 0; c < 4; c++) {
            const f32x4* ac = (c == 0) ? &acc0 : (c == 1) ? &acc1 : (c == 2) ? &acc2 : &acc3;
            float bb = b3[16 * c + m];
            hh[(r0 + q * 4 + 0) * HSTR + 16 * c + m] = (f16)lrelu(dv0 * (*ac)[0] + bb, 0.01f);
            hh[(r0 + q * 4 + 1) * HSTR + 16 * c + m] = (f16)lrelu(dv1 * (*ac)[1] + bb, 0.01f);
            hh[(r0 + q * 4 + 2) * HSTR + 16 * c + m] = (f16)lrelu(dv2 * (*ac)[2] + bb, 0.01f);
            hh[(r0 + q * 4 + 3) * HSTR + 16 * c + m] = (f16)lrelu(dv3 * (*ac)[3] + bb, 0.01f);
        }
    }
    __syncthreads();

    acc0 = (f32x4){0.f, 0.f, 0.f, 0.f}; acc1 = acc0; acc2 = acc0; acc3 = acc0;
#pragma unroll
    for (int kt = 0; kt < 2; kt++) {
        f16x8 afrag = *(const f16x8*)&hh[(r0 + m) * HSTR + kt * 32 + q * 8];
        f16x8 b0 = *(const f16x8*)&wgp[((kt * 4 + 0) << 9) + l * 8];
        f16x8 b1 = *(const f16x8*)&wgp[((kt * 4 + 1) << 9) + l * 8];
        f16x8 b2 = *(const f16x8*)&wgp[((kt * 4 + 2) << 9) + l * 8];
        f16x8 b3f = *(const f16x8*)&wgp[((kt * 4 + 3) << 9) + l * 8];
        acc0 = __builtin_amdgcn_mfma_f32_16x16x32_f16(afrag, b0, acc0, 0, 0, 0);
        acc1 = __builtin_amdgcn_mfma_f32_16x16x32_f16(afrag, b1, acc1, 0, 0, 0);
        acc2 = __builtin_amdgcn_mfma_f32_16x16x32_f16(afrag, b2, acc2, 0, 0, 0);
        acc3 = __builtin_amdgcn_mfma_f32_16x16x32_f16(afrag, b3f, acc3, 0, 0, 0);
    }
    {
        float e1[4] = {0.f, 0.f, 0.f, 0.f}, e2[4] = {0.f, 0.f, 0.f, 0.f};
#pragma unroll
        for (int c = 0; c < 4; c++) {
            const f32x4* ac = (c == 0) ? &acc0 : (c == 1) ? &acc1 : (c == 2) ? &acc2 : &acc3;
            float a1 = av[16 * c + m];
            float d1 = ad[16 * c + m];
#pragma unroll
            for (int reg = 0; reg < 4; reg++) {
                float g = (*ac)[reg];
                e1[reg] = fmaf(g, a1, e1[reg]);
                e2[reg] = fmaf(g, d1, e2[reg]);
                xw[(size_t)(v0 + r0 + q * 4 + reg) * 64 + 16 * c + m] = (f16)g;
            }
        }
#pragma unroll
        for (int reg = 0; reg < 4; reg++) {
            e1[reg] += __shfl_xor(e1[reg], 1); e1[reg] += __shfl_xor(e1[reg], 2);
            e1[reg] += __shfl_xor(e1[reg], 4); e1[reg] += __shfl_xor(e1[reg], 8);
            e2[reg] += __shfl_xor(e2[reg], 1); e2[reg] += __shfl_xor(e2[reg], 2);
            e2[reg] += __shfl_xor(e2[reg], 4); e2[reg] += __shfl_xor(e2[reg], 8);
        }
        if (m == 0) {
#pragma unroll
            for (int reg = 0; reg < 4; reg++) {
                es[v0 + r0 + q * 4 + reg] = e1[reg];
                ed[v0 + r0 + q * 4 + reg] = e2[reg];
            }
        }
    }
}

// ---------------- GAT edge softmax weights (fp16 ew) ----------------
__global__ void gat_w_k(const float* __restrict__ es, const float* __restrict__ ed,
                        const int* __restrict__ rp, const int* __restrict__ col,
                        f16* __restrict__ ew, float* __restrict__ wself, float* __restrict__ invden) {
    int v = blockIdx.x * 256 + threadIdx.x;
    if (v >= NN) return;
    float edv = ed[v];
    float eself = lrelu(es[v] + edv, 0.2f);
    float m = eself;
    int s = rp[v], e = rp[v + 1];
    int i = s;
    float lg[32];
    for (; i + 4 <= e; i += 4) {
        int u0 = col[i], u1 = col[i + 1], u2 = col[i + 2], u3 = col[i + 3];
        float t0 = lrelu(es[u0] + edv, 0.2f);
        float t1 = lrelu(es[u1] + edv, 0.2f);
        float t2 = lrelu(es[u2] + edv, 0.2f);
        float t3 = lrelu(es[u3] + edv, 0.2f);
        int k = i - s;
        if (k + 3 < 32) { lg[k] = t0; lg[k + 1] = t1; lg[k + 2] = t2; lg[k + 3] = t3; }
        m = fmaxf(m, fmaxf(fmaxf(t0, t1), fmaxf(t2, t3)));
    }
    for (; i < e; i++) {
        float t = lrelu(es[col[i]] + edv, 0.2f);
        int k = i - s;
        if (k < 32) lg[k] = t;
        m = fmaxf(m, t);
    }
    float wsl = __expf(eself - m);
    float den = wsl;
    for (i = s; i < e; i++) {
        int k = i - s;
        float t = (k < 32) ? lg[k] : lrelu(es[col[i]] + edv, 0.2f);
        float w = __expf(t - m);
        ew[i] = (f16)w;
        den += w;
    }
    wself[v] = wsl;
    invden[v] = 1.f / den;
}

// ---------------- GAT aggregation over fp16 rows (8 lanes/row, f16x8 loads) ----------------
__global__ __launch_bounds__(256) void gat_agg_h_k(const f16* __restrict__ y, const int* __restrict__ rp,
                                                   const int* __restrict__ col, const f16* __restrict__ ew,
                                                   const float* __restrict__ wself, const float* __restrict__ invden,
                                                   const float* __restrict__ bias, float* __restrict__ out) {
    int gid = blockIdx.x * 256 + threadIdx.x;
    int v = gid >> 3;
    int idx = gid & 7;
    const f16x8* y8 = (const f16x8*)y;
    float ws = wself[v];
    f16x8 self = y8[(size_t)v * 8 + idx];
    float acc[8];
#pragma unroll
    for (int j = 0; j < 8; j++) acc[j] = ws * (float)self[j];
    int s = rp[v], e = rp[v + 1];
    int i = s;
    for (; i + 4 <= e; i += 4) {
        int u0 = col[i], u1 = col[i + 1], u2 = col[i + 2], u3 = col[i + 3];
        float w0 = (float)ew[i], w1 = (float)ew[i + 1], w2 = (float)ew[i + 2], w3 = (float)ew[i + 3];
        f16x8 a0 = y8[(size_t)u0 * 8 + idx];
        f16x8 a1 = y8[(size_t)u1 * 8 + idx];
        f16x8 a2 = y8[(size_t)u2 * 8 + idx];
        f16x8 a3 = y8[(size_t)u3 * 8 + idx];
#pragma unroll
        for (int j = 0; j < 8; j++)
            acc[j] = fmaf(w0, (float)a0[j], fmaf(w1, (float)a1[j], fmaf(w2, (float)a2[j], fmaf(w3, (float)a3[j], acc[j]))));
    }
    for (; i < e; i++) {
        float w = (float)ew[i];
        f16x8 aa = y8[(size_t)col[i] * 8 + idx];
#pragma unroll
        for (int j = 0; j < 8; j++) acc[j] = fmaf(w, (float)aa[j], acc[j]);
    }
    float inv = invden[v];
    const float4* b4 = (const float4*)(bias + 8 * idx);
    float4 bb0 = b4[0], bb1 = b4[1];
    float4 o0, o1;
    o0.x = acc[0] * inv + bb0.x; o0.y = acc[1] * inv + bb0.y;
    o0.z = acc[2] * inv + bb0.z; o0.w = acc[3] * inv + bb0.w;
    o1.x = acc[4] * inv + bb1.x; o1.y = acc[5] * inv + bb1.y;
    o1.z = acc[6] * inv + bb1.z; o1.w = acc[7] * inv + bb1.w;
    float4* op = (float4*)(out + (size_t)v * 64 + 8 * idx);
    op[0] = o0; op[1] = o1;
}

// ---------------- pooling ----------------
__global__ void pool_pieces_k(const float* __restrict__ in, float* __restrict__ out) {
    int gid = blockIdx.x * 256 + threadIdx.x;
    if (gid >= BB * CCROSS * 64) return;
    int f = gid & 63, g = gid >> 6;
    const float* p = in + (size_t)g * PCC * 64 + f;
    float s = 0.f;
#pragma unroll 8
    for (int i = 0; i < PCC; i++) s += p[(size_t)i * 64];
    out[gid] = s * (1.f / 128.f);
}

__global__ void pool_cross_k(const float* __restrict__ in, float* __restrict__ out) {
    int gid = blockIdx.x * 64 + threadIdx.x;
    if (gid >= BB * 64) return;
    int f = gid & 63, b = gid >> 6;
    const float* p = in + (size_t)b * CCROSS * 64 + f;
    float s = 0.f;
#pragma unroll
    for (int i = 0; i < CCROSS; i++) s += p[(size_t)i * 64];
    out[gid] = s * (1.f / 32.f);
}

// ---------------- GAT input gemm (fp32, small cross-graph path) ----------------
template <int KIN, int KOUT>
__global__ void gat_gemm_k(const float* __restrict__ x, const float* __restrict__ W,
                           float* __restrict__ y, const float* __restrict__ av, const float* __restrict__ ad,
                           float* __restrict__ es, float* __restrict__ ed, int n) {
    int v = blockIdx.x * 256 + threadIdx.x;
    if (v >= n) return;
    const float* xr = x + (size_t)v * KIN;
    float acc[KOUT];
#pragma unroll
    for (int j = 0; j < KOUT; j++) acc[j] = 0.f;
#pragma unroll 2
    for (int k = 0; k < KIN; k++) {
        float xv = xr[k];
#pragma unroll
        for (int j = 0; j < KOUT; j++) acc[j] = fmaf(xv, W[k * KOUT + j], acc[j]);
    }
    float e1 = 0.f, e2 = 0.f;
    float4* y4 = (float4*)(y + (size_t)v * KOUT);
#pragma unroll
    for (int j4 = 0; j4 < KOUT / 4; j4++) {
        float4 t;
        t.x = acc[4 * j4 + 0]; t.y = acc[4 * j4 + 1]; t.z = acc[4 * j4 + 2]; t.w = acc[4 * j4 + 3];
        y4[j4] = t;
        e1 = fmaf(t.x, av[4 * j4 + 0], e1); e1 = fmaf(t.y, av[4 * j4 + 1], e1);
        e1 = fmaf(t.z, av[4 * j4 + 2], e1); e1 = fmaf(t.w, av[4 * j4 + 3], e1);
        e2 = fmaf(t.x, ad[4 * j4 + 0], e2); e2 = fmaf(t.y, ad[4 * j4 + 1], e2);
        e2 = fmaf(t.z, ad[4 * j4 + 2], e2); e2 = fmaf(t.w, ad[4 * j4 + 3], e2);
    }
    es[v] = e1; ed[v] = e2;
}

// ---------------- dense cross-graph GAT ----------------
__global__ void cross_att_k(const float* __restrict__ xw, const float* __restrict__ es,
                            const float* __restrict__ ed, const float* __restrict__ bg,
                            float* __restrict__ out) {
    int gid = blockIdx.x * 256 + threadIdx.x;
    if (gid >= BB * CCROSS * 64) return;
    int f = gid & 63;
    int d = (gid >> 6) & 31;
    int g = gid >> 11;
    int base = g * CCROSS;
    float edd = ed[base + d];
    float m = -1e30f;
#pragma unroll
    for (int s = 0; s < CCROSS; s++) {
        float e = lrelu(es[base + s] + edd, 0.2f);
        m = fmaxf(m, e);
    }
    float den = 0.f, acc = 0.f;
#pragma unroll
    for (int s = 0; s < CCROSS; s++) {
        float e = lrelu(es[base + s] + edd, 0.2f);
        float w = __expf(e - m) * ((s == d) ? 1.f : 2.f);
        den += w;
        acc = fmaf(w, xw[(size_t)(base + s) * 64 + f], acc);
    }
    out[gid] = acc / den + bg[f];
}

// ---------------- fused conv branch ----------------
#define S0_STR 264
#define S1_STR 132
#define S2_STR 66
#define S0_OFF 0
#define S1_OFF (3 * S0_STR)
#define S2_OFF (S1_OFF + 32 * S1_STR)
#define SMEM_FLOATS (S2_OFF + 64 * S2_STR)

__global__ __launch_bounds__(256) void conv_fused_k(
        const float* __restrict__ pts, const float* __restrict__ c1W, const float* __restrict__ c1b,
        const float* __restrict__ g1, const float* __restrict__ be1,
        const float* __restrict__ c2W, const float* __restrict__ c2b,
        const float* __restrict__ g2, const float* __restrict__ be2,
        const float* __restrict__ c3W, const float* __restrict__ c3b,
        float* __restrict__ partials) {
    __shared__ float smem[SMEM_FLOATS];
    float* s0 = smem + S0_OFF;
    float* s1 = smem + S1_OFF;
    float* s2 = smem + S2_OFF;
    float* s3 = smem;

    const int b = blockIdx.x >> 3;
    const int q = blockIdx.x & 7;
    const int tid = threadIdx.x;
    const float bnscale = 0.99999500003749968f;

    const int lo0 = 256 * q - 7;
    for (int t = tid; t < 3 * 263; t += 256) {
        int c = t / 263, j = t - c * 263;
        int p = lo0 + j;
        s0[c * S0_STR + j] = (p >= 0 && p < PP) ? pts[((size_t)b * 3 + c) * PP + p] : 0.f;
    }
    __syncthreads();

    const int lo1 = 128 * q - 3;
    for (int t = tid; t < 32 * 131; t += 256) {
        int ch = t / 131, j = t - ch * 131;
        int p1 = lo1 + j;
        float v = 0.f;
        if (p1 >= 0 && p1 < 1024) {
            float acc = c1b[ch];
            const float* w = c1W + ch * 9;
            const float* x0 = s0 + 2 * j;
#pragma unroll
            for (int ci = 0; ci < 3; ci++) {
                acc = fmaf(x0[ci * S0_STR + 0], w[ci * 3 + 0], acc);
                acc = fmaf(x0[ci * S0_STR + 1], w[ci * 3 + 1], acc);
                acc = fmaf(x0[ci * S0_STR + 2], w[ci * 3 + 2], acc);
            }
            acc = lrelu(acc, 0.01f);
            v = fmaf(acc, g1[ch] * bnscale, be1[ch]);
        }
        s1[ch * S1_STR + j] = v;
    }
    __syncthreads();

    const int lo2 = 64 * q - 1;
    for (int t = tid; t < 64 * 65; t += 256) {
        int ch = t / 65, j = t - ch * 65;
        int p2 = lo2 + j;
        float v = 0.f;
        if (p2 >= 0 && p2 < 512) {
            float acc = c2b[ch];
            const float* w = c2W + ch * 96;
            const float* x1 = s1 + 2 * j;
#pragma unroll
            for (int ci = 0; ci < 32; ci++) {
                acc = fmaf(x1[ci * S1_STR + 0], w[ci * 3 + 0], acc);
                acc = fmaf(x1[ci * S1_STR + 1], w[ci * 3 + 1], acc);
                acc = fmaf(x1[ci * S1_STR + 2], w[ci * 3 + 2], acc);
            }
            acc = lrelu(acc, 0.01f);
            v = fmaf(acc, g2[ch] * bnscale, be2[ch]);
        }
        s2[ch * S2_STR + j] = v;
    }
    __syncthreads();

    for (int t = tid; t < 64 * 32; t += 256) {
        int o = t >> 5, j = t & 31;
        float acc = c3b[o];
        const float* w = c3W + o * 192;
        const float* x2 = s2 + 2 * j;
#pragma unroll 16
        for (int ci = 0; ci < 64; ci++) {
            acc = fmaf(x2[ci * S2_STR + 0], w[ci * 3 + 0], acc);
            acc = fmaf(x2[ci * S2_STR + 1], w[ci * 3 + 1], acc);
            acc = fmaf(x2[ci * S2_STR + 2], w[ci * 3 + 2], acc);
        }
        s3[t] = lrelu(acc, 0.01f);
    }
    __syncthreads();

    if (tid < 64) {
        float s = 0.f;
#pragma unroll
        for (int j = 0; j < 32; j++) s += s3[tid * 32 + j];
        partials[((size_t)b * 8 + q) * 64 + tid] = s;
    }
}

// ---------------- head ----------------
__global__ void head_k(const float* __restrict__ hG, const float* __restrict__ partials,
                       const float* __restrict__ Wl2, const float* __restrict__ bl2,
                       const float* __restrict__ Wl3, const float* __restrict__ bl3,
                       float* __restrict__ out) {
    int b = blockIdx.x;
    int f = threadIdx.x;  // 64
    __shared__ float sh[64];
    float p = 0.f;
#pragma unroll
    for (int q = 0; q < 8; q++) p += partials[((size_t)b * 8 + q) * 64 + f];
    float h = hG[b * 64 + f] + p * (1.f / 256.f);
    sh[f] = h;
    __syncthreads();
    float acc = bl2[f];
#pragma unroll
    for (int k = 0; k < 64; k++) acc = fmaf(sh[k], Wl2[k * 64 + f], acc);
    acc = lrelu(acc, 0.01f);
    float pr = acc * Wl3[f];
#pragma unroll
    for (int off = 32; off > 0; off >>= 1) pr += __shfl_down(pr, off, 64);
    if (f == 0) out[b] = 1.f / (1.f + __expf(-(pr + bl3[0])));
}

extern "C" void kernel_launch(void* const* d_in, const int* in_sizes, int n_in,
                              void* d_out, int out_size, void* d_ws, size_t ws_size,
                              hipStream_t stream) {
    const float* x = (const float*)d_in[0];
    const int* ei = (const int*)d_in[1];
    const float* points = (const float*)d_in[2];
    const float* W1 = (const float*)d_in[3];
    const float* b1 = (const float*)d_in[4];
    const float* W2 = (const float*)d_in[5];
    const float* b2 = (const float*)d_in[6];
    const float* W3 = (const float*)d_in[7];
    const float* b3 = (const float*)d_in[8];
    const float* Wg1 = (const float*)d_in[9];
    const float* asrc1 = (const float*)d_in[10];
    const float* adst1 = (const float*)d_in[11];
    const float* bg1 = (const float*)d_in[12];
    const float* Wg2 = (const float*)d_in[13];
    const float* asrc2 = (const float*)d_in[14];
    const float* adst2 = (const float*)d_in[15];
    const float* bg2 = (const float*)d_in[16];
    const float* c1W = (const float*)d_in[17];
    const float* c1b = (const float*)d_in[18];
    const float* g1 = (const float*)d_in[19];
    const float* be1 = (const float*)d_in[20];
    const float* c2W = (const float*)d_in[21];
    const float* c2b = (const float*)d_in[22];
    const float* g2 = (const float*)d_in[23];
    const float* be2 = (const float*)d_in[24];
    const float* c3W = (const float*)d_in[25];
    const float* c3b = (const float*)d_in[26];
    const float* Wl2 = (const float*)d_in[27];
    const float* bl2 = (const float*)d_in[28];
    const float* Wl3 = (const float*)d_in[29];
    const float* bl3 = (const float*)d_in[30];

    const int* src = ei;
    const int* dst = ei + EE;

    // ---- workspace carve-up ----
    char* w = (char*)d_ws;
    size_t off = 0;
    auto A = [&](size_t bytes) -> void* {
        void* p = w + off;
        off = (off + bytes + 255) & ~(size_t)255;
        return p;
    };
    int* colb = (int*)A((size_t)EE * 4);
    int* rp = (int*)A((size_t)(NN + 1) * 4);
    int* gcnt = (int*)A(NBUCK * 4);
    int* bbase = (int*)A(NBUCK * 4);
    float* dinv = (float*)A((size_t)NN * 4);
    float* bufA = (float*)A((size_t)NN * 64 * 4);
    f16* bufH1 = (f16*)A((size_t)NN * 64 * 2);
    f16* bufH2 = (f16*)A((size_t)NN * 64 * 2);
    f16* ew = (f16*)A((size_t)EE * 2);
    float* wself = (float*)A((size_t)NN * 4);
    float* invden = (float*)A((size_t)NN * 4);
    float* es = (float*)A((size_t)NN * 4);
    float* edv = (float*)A((size_t)NN * 4);
    f16* w3p = (f16*)A(4096 * 2);
    f16* wgp = (f16*)A(4096 * 2);
    float* pooled = (float*)A((size_t)BB * CCROSS * 64 * 4);
    float* xw2 = (float*)A((size_t)BB * CCROSS * 64 * 4);
    float* es2 = (float*)A((size_t)BB * CCROSS * 4);
    float* ed2 = (float*)A((size_t)BB * CCROSS * 4);
    float* crosso = (float*)A((size_t)BB * CCROSS * 64 * 4);
    float* hG = (float*)A((size_t)BB * 64 * 4);
    float* partials = (float*)A((size_t)BB * 8 * 64 * 4);

    unsigned* buckets = (unsigned*)bufA;   // aliases bufA; dead before bufA's reuse below
    f16* aggH = (f16*)bufA;                // agg(z3) fp16 [NN x 64h]; dead before gat output overwrites bufA

    // ---- CSR build (bucketed) ----
    hipMemsetAsync(gcnt, 0, NBUCK * 4, stream);
    bucket_a_k<<<EE / 8192, 256, 0, stream>>>(src, dst, buckets, gcnt);
    bucket_scan_k<<<1, 256, 0, stream>>>(gcnt, bbase, rp);
    bucket_b_k<<<NBUCK, 256, 0, stream>>>(buckets, gcnt, bbase, rp, dinv, colb);

    // ---- points branch + weight packing ----
    conv_fused_k<<<BB * 8, 256, 0, stream>>>(points, c1W, c1b, g1, be1, c2W, c2b, g2, be2, c3W, c3b, partials);
    pack_w_k<<<16, 256, 0, stream>>>(W3, w3p);
    pack_w_k<<<16, 256, 0, stream>>>(Wg1, wgp);

    // ---- GCN 1/2 (fused agg+gemm), GCN3+GAT gemm (standalone agg + MFMA compute) ----
    zprep_k<<<NN / 256, 256, 0, stream>>>(x, dinv, bufH1);                               // H1 = z1 [NN x 32h]
    fused_agg_gemm_k<19, 32, 0><<<NN / 32, 256, 0, stream>>>(bufH1, rp, colb, W1, dinv, b1, bufH2);  // H2 = z2
    fused_agg_gemm_k<32, 64, 1><<<NN / 32, 256, 0, stream>>>(bufH2, rp, colb, W2, dinv, b2, bufH1);  // H1 = z3
    agg_h16_k<<<(NN * 8) / 256, 256, 0, stream>>>(bufH1, rp, colb, aggH);                // aggH = agg(z3)
    gemm3_gat_k<<<NN / 64, 256, 0, stream>>>(aggH, w3p, dinv, b3, wgp, asrc1, adst1,
                                             bufH2, es, edv);                            // H2 = xw, es/ed

    // ---- GAT 1 softmax + aggregation ----
    gat_w_k<<<NN / 256, 256, 0, stream>>>(es, edv, rp, colb, ew, wself, invden);
    gat_agg_h_k<<<(NN * 8) / 256, 256, 0, stream>>>(bufH2, rp, colb, ew, wself, invden, bg1, bufA);  // bufA = gat out

    // ---- pool pieces -> cross GAT -> pool cross ----
    pool_pieces_k<<<(BB * CCROSS * 64) / 256, 256, 0, stream>>>(bufA, pooled);
    gat_gemm_k<64, 64><<<(BB * CCROSS) / 256, 256, 0, stream>>>(pooled, Wg2, xw2, asrc2, adst2, es2, ed2, BB * CCROSS);
    cross_att_k<<<(BB * CCROSS * 64) / 256, 256, 0, stream>>>(xw2, es2, ed2, bg2, crosso);
    pool_cross_k<<<BB, 64, 0, stream>>>(crosso, hG);

    // ---- head ----
    head_k<<<BB, 64, 0, stream>>>(hG, partials, Wl2, bl2, Wl3, bl3, (float*)d_out);
}

// Round 15
// 539.817 us; speedup vs baseline: 1.2237x; 1.0113x over previous
//
#include <hip/hip_runtime.h>
#include <cstdint>
#include <cstddef>

#define NN 262144
#define EE 2097152
#define BB 64
#define CCROSS 32
#define PCC 128
#define PP 2048
#define NBUCK 256
#define BCAP 12288

typedef _Float16 f16;
typedef __attribute__((ext_vector_type(4))) _Float16 f16x4;
typedef __attribute__((ext_vector_type(8))) _Float16 f16x8;
typedef __attribute__((ext_vector_type(4))) float f32x4;

static __device__ __forceinline__ float lrelu(float x, float s) { return x > 0.f ? x : s * x; }

// ---------------- bucketed CSR build ----------------
__global__ __launch_bounds__(256) void bucket_a_k(const int* __restrict__ src, const int* __restrict__ dst,
                                                  unsigned* __restrict__ buckets, int* __restrict__ gcnt) {
    __shared__ int hist[NBUCK];
    __shared__ int base[NBUCK];
    __shared__ unsigned short rankbuf[8192];
    const int tid = threadIdx.x;
    const int e0 = blockIdx.x * 8192;
    hist[tid] = 0;
    __syncthreads();
    for (int i = tid; i < 8192; i += 256) {
        int d = dst[e0 + i];
        rankbuf[i] = (unsigned short)atomicAdd(&hist[d >> 10], 1);
    }
    __syncthreads();
    base[tid] = tid * BCAP + atomicAdd(&gcnt[tid], hist[tid]);
    __syncthreads();
    for (int i = tid; i < 8192; i += 256) {
        int s = src[e0 + i];
        int d = dst[e0 + i];
        int b = d >> 10;
        buckets[base[b] + rankbuf[i]] = ((unsigned)s << 10) | (unsigned)(d & 1023);
    }
}

__global__ void bucket_scan_k(const int* __restrict__ gcnt, int* __restrict__ bbase, int* __restrict__ rp) {
    __shared__ int tmp[256];
    int tid = threadIdx.x;
    int v = gcnt[tid];
    tmp[tid] = v;
    __syncthreads();
    for (int off = 1; off < 256; off <<= 1) {
        int t = (tid >= off) ? tmp[tid - off] : 0;
        __syncthreads();
        tmp[tid] += t;
        __syncthreads();
    }
    bbase[tid] = tmp[tid] - v;
    if (tid == 0) rp[NN] = EE;
}

__global__ __launch_bounds__(256) void bucket_b_k(const unsigned* __restrict__ buckets, const int* __restrict__ gcnt,
                                                  const int* __restrict__ bbase, int* __restrict__ rp,
                                                  float* __restrict__ dinv, int* __restrict__ col) {
    __shared__ int cnt[1024];
    __shared__ int scan[1024];
    __shared__ int wsum[256];
    const int b = blockIdx.x;
    const int tid = threadIdx.x;
    int n = gcnt[b];
    if (n > BCAP) n = BCAP;
    const unsigned* eb = buckets + (size_t)b * BCAP;
    const int gb = bbase[b];
    for (int i = tid; i < 1024; i += 256) cnt[i] = 0;
    __syncthreads();
    for (int i = tid; i < n; i += 256) atomicAdd(&cnt[eb[i] & 1023], 1);
    __syncthreads();
    int b4 = tid * 4;
    int c0 = cnt[b4], c1 = cnt[b4 + 1], c2 = cnt[b4 + 2], c3 = cnt[b4 + 3];
    int tsum = c0 + c1 + c2 + c3;
    wsum[tid] = tsum;
    __syncthreads();
    for (int off = 1; off < 256; off <<= 1) {
        int t = (tid >= off) ? wsum[tid - off] : 0;
        __syncthreads();
        wsum[tid] += t;
        __syncthreads();
    }
    int excl = wsum[tid] - tsum;
    scan[b4] = excl;
    scan[b4 + 1] = excl + c0;
    scan[b4 + 2] = excl + c0 + c1;
    scan[b4 + 3] = excl + c0 + c1 + c2;
    int vbase = b * 1024 + b4;
    rp[vbase + 0] = gb + scan[b4 + 0];
    rp[vbase + 1] = gb + scan[b4 + 1];
    rp[vbase + 2] = gb + scan[b4 + 2];
    rp[vbase + 3] = gb + scan[b4 + 3];
    dinv[vbase + 0] = rsqrtf((float)(c0 + 1));
    dinv[vbase + 1] = rsqrtf((float)(c1 + 1));
    dinv[vbase + 2] = rsqrtf((float)(c2 + 1));
    dinv[vbase + 3] = rsqrtf((float)(c3 + 1));
    __syncthreads();
    for (int i = tid; i < 1024; i += 256) cnt[i] = 0;
    __syncthreads();
    for (int i = tid; i < n; i += 256) {
        unsigned p = eb[i];
        int dl = p & 1023;
        int r = atomicAdd(&cnt[dl], 1);
        col[gb + scan[dl] + r] = (int)(p >> 10);
    }
}

// ---------------- z-prep ----------------
__global__ void zprep_k(const float* __restrict__ x, const float* __restrict__ dinv, f16* __restrict__ z) {
    int v = blockIdx.x * 256 + threadIdx.x;
    if (v >= NN) return;
    float dv = dinv[v];
    const float* xr = x + (size_t)v * 19;
    float vv[20];
#pragma unroll
    for (int k = 0; k < 19; k++) vv[k] = dv * xr[k];
    vv[19] = 0.f;
    f16x4* zr = (f16x4*)(z + (size_t)v * 32);
#pragma unroll
    for (int c = 0; c < 5; c++) {
        f16x4 t = {(f16)vv[4 * c], (f16)vv[4 * c + 1], (f16)vv[4 * c + 2], (f16)vv[4 * c + 3]};
        zr[c] = t;
    }
    f16x4 zz = {(f16)0.f, (f16)0.f, (f16)0.f, (f16)0.f};
#pragma unroll
    for (int c = 5; c < 8; c++) zr[c] = zz;
}

// ---------------- fused agg (64B fp16 rows) + gemm, wide-gather version ----------------
// 64 rows/block; phase1: 4 lanes/row x f16x8 (16B) loads; phase2: 4 thr/row x KOUT/4 outs.
#define ZSTR1 36
template <int KINR, int KOUT, int ACT>
__global__ __launch_bounds__(256) void fused_agg_gemm_k(const f16* __restrict__ z, const int* __restrict__ rp,
                                                        const int* __restrict__ col, const float* __restrict__ Wg,
                                                        const float* __restrict__ dinv, const float* __restrict__ bias,
                                                        f16* __restrict__ zout) {
    constexpr int NO = KOUT / 4;
    __shared__ float Wl[32 * KOUT];
    __shared__ float zrow[64 * ZSTR1];
    const int tid = threadIdx.x;
    for (int i = tid; i < 32 * KOUT; i += 256) Wl[i] = (i < KINR * KOUT) ? Wg[i] : 0.f;

    const int r = tid >> 2;
    const int idx = tid & 3;
    const int v = blockIdx.x * 64 + r;
    const f16x8* z8 = (const f16x8*)z;
    f16x8 a = z8[(size_t)v * 4 + idx];
    float acc8[8];
#pragma unroll
    for (int j = 0; j < 8; j++) acc8[j] = (float)a[j];
    int st = rp[v], e = rp[v + 1];
    int i = st;
    for (; i + 4 <= e; i += 4) {
        int u0 = col[i], u1 = col[i + 1], u2 = col[i + 2], u3 = col[i + 3];
        f16x8 a0 = z8[(size_t)u0 * 4 + idx];
        f16x8 a1 = z8[(size_t)u1 * 4 + idx];
        f16x8 a2 = z8[(size_t)u2 * 4 + idx];
        f16x8 a3 = z8[(size_t)u3 * 4 + idx];
#pragma unroll
        for (int j = 0; j < 8; j++)
            acc8[j] += ((float)a0[j] + (float)a1[j]) + ((float)a2[j] + (float)a3[j]);
    }
    for (; i < e; i++) {
        f16x8 aa = z8[(size_t)col[i] * 4 + idx];
#pragma unroll
        for (int j = 0; j < 8; j++) acc8[j] += (float)aa[j];
    }
    float4 s0, s1;
    s0.x = acc8[0]; s0.y = acc8[1]; s0.z = acc8[2]; s0.w = acc8[3];
    s1.x = acc8[4]; s1.y = acc8[5]; s1.z = acc8[6]; s1.w = acc8[7];
    *(float4*)&zrow[r * ZSTR1 + idx * 8] = s0;
    *(float4*)&zrow[r * ZSTR1 + idx * 8 + 4] = s1;
    __syncthreads();

    // phase 2: 4 threads/row, NO = KOUT/4 outs each
    float acc[NO];
#pragma unroll
    for (int j = 0; j < NO; j++) acc[j] = 0.f;
#pragma unroll 4
    for (int k = 0; k < 32; k++) {
        float zv = zrow[r * ZSTR1 + k];
        const float* wr = Wl + k * KOUT + NO * idx;
#pragma unroll
        for (int j = 0; j < NO; j++) acc[j] = fmaf(zv, wr[j], acc[j]);
    }
    float dv = dinv[v];
    f16 hv[NO];
#pragma unroll
    for (int j = 0; j < NO; j++) {
        float o = dv * acc[j] + bias[NO * idx + j];
        o = (ACT == 0) ? fmaxf(o, 0.f) : lrelu(o, 0.01f);
        hv[j] = (f16)(o * dv);
    }
    if constexpr (NO == 8) {
        f16x8 h = {hv[0], hv[1], hv[2], hv[3], hv[4], hv[5], hv[6], hv[7]};
        *(f16x8*)(zout + (size_t)v * KOUT + NO * idx) = h;
    } else {
        f16x8 h0 = {hv[0], hv[1], hv[2], hv[3], hv[4], hv[5], hv[6], hv[7]};
        f16x8 h1 = {hv[8], hv[9], hv[10], hv[11], hv[12], hv[13], hv[14], hv[15]};
        f16x8* yo = (f16x8*)(zout + (size_t)v * KOUT + NO * idx);
        yo[0] = h0; yo[1] = h1;
    }
}

// ---------------- standalone agg over 128B fp16 rows, fp16 out (8 lanes/row, f16x8 loads) ----------------
__global__ __launch_bounds__(256) void agg_h16_k(const f16* __restrict__ y, const int* __restrict__ rp,
                                                 const int* __restrict__ col, f16* __restrict__ out) {
    int gid = blockIdx.x * 256 + threadIdx.x;
    int v = gid >> 3;
    int idx = gid & 7;
    const f16x8* y8 = (const f16x8*)y;
    f16x8 a = y8[(size_t)v * 8 + idx];
    float acc[8];
#pragma unroll
    for (int j = 0; j < 8; j++) acc[j] = (float)a[j];
    int s = rp[v], e = rp[v + 1];
    int i = s;
    for (; i + 4 <= e; i += 4) {
        int u0 = col[i], u1 = col[i + 1], u2 = col[i + 2], u3 = col[i + 3];
        f16x8 a0 = y8[(size_t)u0 * 8 + idx];
        f16x8 a1 = y8[(size_t)u1 * 8 + idx];
        f16x8 a2 = y8[(size_t)u2 * 8 + idx];
        f16x8 a3 = y8[(size_t)u3 * 8 + idx];
#pragma unroll
        for (int j = 0; j < 8; j++)
            acc[j] += ((float)a0[j] + (float)a1[j]) + ((float)a2[j] + (float)a3[j]);
    }
    for (; i < e; i++) {
        f16x8 aa = y8[(size_t)col[i] * 8 + idx];
#pragma unroll
        for (int j = 0; j < 8; j++) acc[j] += (float)aa[j];
    }
    f16x8 r;
#pragma unroll
    for (int j = 0; j < 8; j++) r[j] = (f16)acc[j];
    ((f16x8*)out)[(size_t)v * 8 + idx] = r;
}

// ---------------- pack W (64x64 fp32 row-major k x n) into fp16 B-fragment order ----------------
__global__ void pack_w_k(const float* __restrict__ W, f16* __restrict__ out) {
    int o = blockIdx.x * 256 + threadIdx.x;
    if (o >= 4096) return;
    int frag = o >> 9;
    int kt = frag >> 2;
    int c = frag & 3;
    int idx = o & 511;
    int l = idx >> 3;
    int j = idx & 7;
    int k = kt * 32 + ((l >> 4) << 3) + j;
    int n = 16 * c + (l & 15);
    out[o] = (f16)W[k * 64 + n];
}

// ---------------- MFMA compute: h3 = lrelu(dinv*(aggz@W3)+b3); xw = h3@Wg1; es/ed dots ----------------
#define HSTR 72
__global__ __launch_bounds__(256) void gemm3_gat_k(const f16* __restrict__ aggz, const f16* __restrict__ w3p,
                                                   const float* __restrict__ dinv, const float* __restrict__ b3,
                                                   const f16* __restrict__ wgp, const float* __restrict__ av,
                                                   const float* __restrict__ ad, f16* __restrict__ xw,
                                                   float* __restrict__ es, float* __restrict__ ed) {
    __shared__ f16 zin[64 * HSTR];
    __shared__ f16 hh[64 * HSTR];
    const int tid = threadIdx.x;
    const int v0 = blockIdx.x * 64;
    {
        int row = tid >> 2;
        int kb = (tid & 3) * 16;
        const f16x8* zp = (const f16x8*)(aggz + (size_t)(v0 + row) * 64 + kb);
        f16x8 z0 = zp[0], z1 = zp[1];
        *(f16x8*)&zin[row * HSTR + kb] = z0;
        *(f16x8*)&zin[row * HSTR + kb + 8] = z1;
    }
    __syncthreads();

    const int w = tid >> 6;
    const int l = tid & 63;
    const int m = l & 15;
    const int q = l >> 4;
    const int r0 = 16 * w;

    f32x4 acc0 = {0.f, 0.f, 0.f, 0.f}, acc1 = acc0, acc2 = acc0, acc3 = acc0;
#pragma unroll
    for (int kt = 0; kt < 2; kt++) {
        f16x8 afrag = *(const f16x8*)&zin[(r0 + m) * HSTR + kt * 32 + q * 8];
        f16x8 b0 = *(const f16x8*)&w3p[((kt * 4 + 0) << 9) + l * 8];
        f16x8 b1 = *(const f16x8*)&w3p[((kt * 4 + 1) << 9) + l * 8];
        f16x8 b2 = *(const f16x8*)&w3p[((kt * 4 + 2) << 9) + l * 8];
        f16x8 b3f = *(const f16x8*)&w3p[((kt * 4 + 3) << 9) + l * 8];
        acc0 = __builtin_amdgcn_mfma_f32_16x16x32_f16(afrag, b0, acc0, 0, 0, 0);
        acc1 = __builtin_amdgcn_mfma_f32_16x16x32_f16(afrag, b1, acc1, 0, 0, 0);
        acc2 = __builtin_amdgcn_mfma_f32_16x16x32_f16(afrag, b2, acc2, 0, 0, 0);
        acc3 = __builtin_amdgcn_mfma_f32_16x16x32_f16(afrag, b3f, acc3, 0, 0, 0);
    }
    {
        float dv0 = dinv[v0 + r0 + q * 4 + 0];
        float dv1 = dinv[v0 + r0 + q * 4 + 1];
        float dv2 = dinv[v0 + r0 + q * 4 + 2];
        float dv3 = dinv[v0 + r0 + q * 4 + 3];
#pragma unroll
        for (int c = 0; c < 4; c++) {
            const f32x4* ac = (c == 0) ? &acc0 : (c == 1) ? &acc1 : (c == 2) ? &acc2 : &acc3;
            float bb = b3[16 * c + m];
            hh[(r0 + q * 4 + 0) * HSTR + 16 * c + m] = (f16)lrelu(dv0 * (*ac)[0] + bb, 0.01f);
            hh[(r0 + q * 4 + 1) * HSTR + 16 * c + m] = (f16)lrelu(dv1 * (*ac)[1] + bb, 0.01f);
            hh[(r0 + q * 4 + 2) * HSTR + 16 * c + m] = (f16)lrelu(dv2 * (*ac)[2] + bb, 0.01f);
            hh[(r0 + q * 4 + 3) * HSTR + 16 * c + m] = (f16)lrelu(dv3 * (*ac)[3] + bb, 0.01f);
        }
    }
    __syncthreads();

    acc0 = (f32x4){0.f, 0.f, 0.f, 0.f}; acc1 = acc0; acc2 = acc0; acc3 = acc0;
#pragma unroll
    for (int kt = 0; kt < 2; kt++) {
        f16x8 afrag = *(const f16x8*)&hh[(r0 + m) * HSTR + kt * 32 + q * 8];
        f16x8 b0 = *(const f16x8*)&wgp[((kt * 4 + 0) << 9) + l * 8];
        f16x8 b1 = *(const f16x8*)&wgp[((kt * 4 + 1) << 9) + l * 8];
        f16x8 b2 = *(const f16x8*)&wgp[((kt * 4 + 2) << 9) + l * 8];
        f16x8 b3f = *(const f16x8*)&wgp[((kt * 4 + 3) << 9) + l * 8];
        acc0 = __builtin_amdgcn_mfma_f32_16x16x32_f16(afrag, b0, acc0, 0, 0, 0);
        acc1 = __builtin_amdgcn_mfma_f32_16x16x32_f16(afrag, b1, acc1, 0, 0, 0);
        acc2 = __builtin_amdgcn_mfma_f32_16x16x32_f16(afrag, b2, acc2, 0, 0, 0);
        acc3 = __builtin_amdgcn_mfma_f32_16x16x32_f16(afrag, b3f, acc3, 0, 0, 0);
    }
    {
        float e1[4] = {0.f, 0.f, 0.f, 0.f}, e2[4] = {0.f, 0.f, 0.f, 0.f};
#pragma unroll
        for (int c = 0; c < 4; c++) {
            const f32x4* ac = (c == 0) ? &acc0 : (c == 1) ? &acc1 : (c == 2) ? &acc2 : &acc3;
            float a1 = av[16 * c + m];
            float d1 = ad[16 * c + m];
#pragma unroll
            for (int reg = 0; reg < 4; reg++) {
                float g = (*ac)[reg];
                e1[reg] = fmaf(g, a1, e1[reg]);
                e2[reg] = fmaf(g, d1, e2[reg]);
                xw[(size_t)(v0 + r0 + q * 4 + reg) * 64 + 16 * c + m] = (f16)g;
            }
        }
#pragma unroll
        for (int reg = 0; reg < 4; reg++) {
            e1[reg] += __shfl_xor(e1[reg], 1); e1[reg] += __shfl_xor(e1[reg], 2);
            e1[reg] += __shfl_xor(e1[reg], 4); e1[reg] += __shfl_xor(e1[reg], 8);
            e2[reg] += __shfl_xor(e2[reg], 1); e2[reg] += __shfl_xor(e2[reg], 2);
            e2[reg] += __shfl_xor(e2[reg], 4); e2[reg] += __shfl_xor(e2[reg], 8);
        }
        if (m == 0) {
#pragma unroll
            for (int reg = 0; reg < 4; reg++) {
                es[v0 + r0 + q * 4 + reg] = e1[reg];
                ed[v0 + r0 + q * 4 + reg] = e2[reg];
            }
        }
    }
}

// ---------------- GAT edge softmax weights (fp16 ew) ----------------
__global__ void gat_w_k(const float* __restrict__ es, const float* __restrict__ ed,
                        const int* __restrict__ rp, const int* __restrict__ col,
                        f16* __restrict__ ew, float* __restrict__ wself, float* __restrict__ invden) {
    int v = blockIdx.x * 256 + threadIdx.x;
    if (v >= NN) return;
    float edv = ed[v];
    float eself = lrelu(es[v] + edv, 0.2f);
    float m = eself;
    int s = rp[v], e = rp[v + 1];
    int i = s;
    float lg[32];
    for (; i + 4 <= e; i += 4) {
        int u0 = col[i], u1 = col[i + 1], u2 = col[i + 2], u3 = col[i + 3];
        float t0 = lrelu(es[u0] + edv, 0.2f);
        float t1 = lrelu(es[u1] + edv, 0.2f);
        float t2 = lrelu(es[u2] + edv, 0.2f);
        float t3 = lrelu(es[u3] + edv, 0.2f);
        int k = i - s;
        if (k + 3 < 32) { lg[k] = t0; lg[k + 1] = t1; lg[k + 2] = t2; lg[k + 3] = t3; }
        m = fmaxf(m, fmaxf(fmaxf(t0, t1), fmaxf(t2, t3)));
    }
    for (; i < e; i++) {
        float t = lrelu(es[col[i]] + edv, 0.2f);
        int k = i - s;
        if (k < 32) lg[k] = t;
        m = fmaxf(m, t);
    }
    float wsl = __expf(eself - m);
    float den = wsl;
    for (i = s; i < e; i++) {
        int k = i - s;
        float t = (k < 32) ? lg[k] : lrelu(es[col[i]] + edv, 0.2f);
        float w = __expf(t - m);
        ew[i] = (f16)w;
        den += w;
    }
    wself[v] = wsl;
    invden[v] = 1.f / den;
}

// ---------------- GAT aggregation over fp16 rows (8 lanes/row, f16x8 loads) ----------------
__global__ __launch_bounds__(256) void gat_agg_h_k(const f16* __restrict__ y, const int* __restrict__ rp,
                                                   const int* __restrict__ col, const f16* __restrict__ ew,
                                                   const float* __restrict__ wself, const float* __restrict__ invden,
                                                   const float* __restrict__ bias, float* __restrict__ out) {
    int gid = blockIdx.x * 256 + threadIdx.x;
    int v = gid >> 3;
    int idx = gid & 7;
    const f16x8* y8 = (const f16x8*)y;
    float ws = wself[v];
    f16x8 self = y8[(size_t)v * 8 + idx];
    float acc[8];
#pragma unroll
    for (int j = 0; j < 8; j++) acc[j] = ws * (float)self[j];
    int s = rp[v], e = rp[v + 1];
    int i = s;
    for (; i + 4 <= e; i += 4) {
        int u0 = col[i], u1 = col[i + 1], u2 = col[i + 2], u3 = col[i + 3];
        float w0 = (float)ew[i], w1 = (float)ew[i + 1], w2 = (float)ew[i + 2], w3 = (float)ew[i + 3];
        f16x8 a0 = y8[(size_t)u0 * 8 + idx];
        f16x8 a1 = y8[(size_t)u1 * 8 + idx];
        f16x8 a2 = y8[(size_t)u2 * 8 + idx];
        f16x8 a3 = y8[(size_t)u3 * 8 + idx];
#pragma unroll
        for (int j = 0; j < 8; j++)
            acc[j] = fmaf(w0, (float)a0[j], fmaf(w1, (float)a1[j], fmaf(w2, (float)a2[j], fmaf(w3, (float)a3[j], acc[j]))));
    }
    for (; i < e; i++) {
        float w = (float)ew[i];
        f16x8 aa = y8[(size_t)col[i] * 8 + idx];
#pragma unroll
        for (int j = 0; j < 8; j++) acc[j] = fmaf(w, (float)aa[j], acc[j]);
    }
    float inv = invden[v];
    const float4* b4 = (const float4*)(bias + 8 * idx);
    float4 bb0 = b4[0], bb1 = b4[1];
    float4 o0, o1;
    o0.x = acc[0] * inv + bb0.x; o0.y = acc[1] * inv + bb0.y;
    o0.z = acc[2] * inv + bb0.z; o0.w = acc[3] * inv + bb0.w;
    o1.x = acc[4] * inv + bb1.x; o1.y = acc[5] * inv + bb1.y;
    o1.z = acc[6] * inv + bb1.z; o1.w = acc[7] * inv + bb1.w;
    float4* op = (float4*)(out + (size_t)v * 64 + 8 * idx);
    op[0] = o0; op[1] = o1;
}

// ---------------- pooling ----------------
__global__ void pool_pieces_k(const float* __restrict__ in, float* __restrict__ out) {
    int gid = blockIdx.x * 256 + threadIdx.x;
    if (gid >= BB * CCROSS * 64) return;
    int f = gid & 63, g = gid >> 6;
    const float* p = in + (size_t)g * PCC * 64 + f;
    float s = 0.f;
#pragma unroll 8
    for (int i = 0; i < PCC; i++) s += p[(size_t)i * 64];
    out[gid] = s * (1.f / 128.f);
}

__global__ void pool_cross_k(const float* __restrict__ in, float* __restrict__ out) {
    int gid = blockIdx.x * 64 + threadIdx.x;
    if (gid >= BB * 64) return;
    int f = gid & 63, b = gid >> 6;
    const float* p = in + (size_t)b * CCROSS * 64 + f;
    float s = 0.f;
#pragma unroll
    for (int i = 0; i < CCROSS; i++) s += p[(size_t)i * 64];
    out[gid] = s * (1.f / 32.f);
}

// ---------------- GAT input gemm (fp32, small cross-graph path) ----------------
template <int KIN, int KOUT>
__global__ void gat_gemm_k(const float* __restrict__ x, const float* __restrict__ W,
                           float* __restrict__ y, const float* __restrict__ av, const float* __restrict__ ad,
                           float* __restrict__ es, float* __restrict__ ed, int n) {
    int v = blockIdx.x * 256 + threadIdx.x;
    if (v >= n) return;
    const float* xr = x + (size_t)v * KIN;
    float acc[KOUT];
#pragma unroll
    for (int j = 0; j < KOUT; j++) acc[j] = 0.f;
#pragma unroll 2
    for (int k = 0; k < KIN; k++) {
        float xv = xr[k];
#pragma unroll
        for (int j = 0; j < KOUT; j++) acc[j] = fmaf(xv, W[k * KOUT + j], acc[j]);
    }
    float e1 = 0.f, e2 = 0.f;
    float4* y4 = (float4*)(y + (size_t)v * KOUT);
#pragma unroll
    for (int j4 = 0; j4 < KOUT / 4; j4++) {
        float4 t;
        t.x = acc[4 * j4 + 0]; t.y = acc[4 * j4 + 1]; t.z = acc[4 * j4 + 2]; t.w = acc[4 * j4 + 3];
        y4[j4] = t;
        e1 = fmaf(t.x, av[4 * j4 + 0], e1); e1 = fmaf(t.y, av[4 * j4 + 1], e1);
        e1 = fmaf(t.z, av[4 * j4 + 2], e1); e1 = fmaf(t.w, av[4 * j4 + 3], e1);
        e2 = fmaf(t.x, ad[4 * j4 + 0], e2); e2 = fmaf(t.y, ad[4 * j4 + 1], e2);
        e2 = fmaf(t.z, ad[4 * j4 + 2], e2); e2 = fmaf(t.w, ad[4 * j4 + 3], e2);
    }
    es[v] = e1; ed[v] = e2;
}

// ---------------- dense cross-graph GAT ----------------
__global__ void cross_att_k(const float* __restrict__ xw, const float* __restrict__ es,
                            const float* __restrict__ ed, const float* __restrict__ bg,
                            float* __restrict__ out) {
    int gid = blockIdx.x * 256 + threadIdx.x;
    if (gid >= BB * CCROSS * 64) return;
    int f = gid & 63;
    int d = (gid >> 6) & 31;
    int g = gid >> 11;
    int base = g * CCROSS;
    float edd = ed[base + d];
    float m = -1e30f;
#pragma unroll
    for (int s = 0; s < CCROSS; s++) {
        float e = lrelu(es[base + s] + edd, 0.2f);
        m = fmaxf(m, e);
    }
    float den = 0.f, acc = 0.f;
#pragma unroll
    for (int s = 0; s < CCROSS; s++) {
        float e = lrelu(es[base + s] + edd, 0.2f);
        float w = __expf(e - m) * ((s == d) ? 1.f : 2.f);
        den += w;
        acc = fmaf(w, xw[(size_t)(base + s) * 64 + f], acc);
    }
    out[gid] = acc / den + bg[f];
}

// ---------------- fused conv branch ----------------
#define S0_STR 264
#define S1_STR 132
#define S2_STR 66
#define S0_OFF 0
#define S1_OFF (3 * S0_STR)
#define S2_OFF (S1_OFF + 32 * S1_STR)
#define SMEM_FLOATS (S2_OFF + 64 * S2_STR)

__global__ __launch_bounds__(256) void conv_fused_k(
        const float* __restrict__ pts, const float* __restrict__ c1W, const float* __restrict__ c1b,
        const float* __restrict__ g1, const float* __restrict__ be1,
        const float* __restrict__ c2W, const float* __restrict__ c2b,
        const float* __restrict__ g2, const float* __restrict__ be2,
        const float* __restrict__ c3W, const float* __restrict__ c3b,
        float* __restrict__ partials) {
    __shared__ float smem[SMEM_FLOATS];
    float* s0 = smem + S0_OFF;
    float* s1 = smem + S1_OFF;
    float* s2 = smem + S2_OFF;
    float* s3 = smem;

    const int b = blockIdx.x >> 3;
    const int q = blockIdx.x & 7;
    const int tid = threadIdx.x;
    const float bnscale = 0.99999500003749968f;

    const int lo0 = 256 * q - 7;
    for (int t = tid; t < 3 * 263; t += 256) {
        int c = t / 263, j = t - c * 263;
        int p = lo0 + j;
        s0[c * S0_STR + j] = (p >= 0 && p < PP) ? pts[((size_t)b * 3 + c) * PP + p] : 0.f;
    }
    __syncthreads();

    const int lo1 = 128 * q - 3;
    for (int t = tid; t < 32 * 131; t += 256) {
        int ch = t / 131, j = t - ch * 131;
        int p1 = lo1 + j;
        float v = 0.f;
        if (p1 >= 0 && p1 < 1024) {
            float acc = c1b[ch];
            const float* w = c1W + ch * 9;
            const float* x0 = s0 + 2 * j;
#pragma unroll
            for (int ci = 0; ci < 3; ci++) {
                acc = fmaf(x0[ci * S0_STR + 0], w[ci * 3 + 0], acc);
                acc = fmaf(x0[ci * S0_STR + 1], w[ci * 3 + 1], acc);
                acc = fmaf(x0[ci * S0_STR + 2], w[ci * 3 + 2], acc);
            }
            acc = lrelu(acc, 0.01f);
            v = fmaf(acc, g1[ch] * bnscale, be1[ch]);
        }
        s1[ch * S1_STR + j] = v;
    }
    __syncthreads();

    const int lo2 = 64 * q - 1;
    for (int t = tid; t < 64 * 65; t += 256) {
        int ch = t / 65, j = t - ch * 65;
        int p2 = lo2 + j;
        float v = 0.f;
        if (p2 >= 0 && p2 < 512) {
            float acc = c2b[ch];
            const float* w = c2W + ch * 96;
            const float* x1 = s1 + 2 * j;
#pragma unroll
            for (int ci = 0; ci < 32; ci++) {
                acc = fmaf(x1[ci * S1_STR + 0], w[ci * 3 + 0], acc);
                acc = fmaf(x1[ci * S1_STR + 1], w[ci * 3 + 1], acc);
                acc = fmaf(x1[ci * S1_STR + 2], w[ci * 3 + 2], acc);
            }
            acc = lrelu(acc, 0.01f);
            v = fmaf(acc, g2[ch] * bnscale, be2[ch]);
        }
        s2[ch * S2_STR + j] = v;
    }
    __syncthreads();

    for (int t = tid; t < 64 * 32; t += 256) {
        int o = t >> 5, j = t & 31;
        float acc = c3b[o];
        const float* w = c3W + o * 192;
        const float* x2 = s2 + 2 * j;
#pragma unroll 16
        for (int ci = 0; ci < 64; ci++) {
            acc = fmaf(x2[ci * S2_STR + 0], w[ci * 3 + 0], acc);
            acc = fmaf(x2[ci * S2_STR + 1], w[ci * 3 + 1], acc);
            acc = fmaf(x2[ci * S2_STR + 2], w[ci * 3 + 2], acc);
        }
        s3[t] = lrelu(acc, 0.01f);
    }
    __syncthreads();

    if (tid < 64) {
        float s = 0.f;
#pragma unroll
        for (int j = 0; j < 32; j++) s += s3[tid * 32 + j];
        partials[((size_t)b * 8 + q) * 64 + tid] = s;
    }
}

// ---------------- head ----------------
__global__ void head_k(const float* __restrict__ hG, const float* __restrict__ partials,
                       const float* __restrict__ Wl2, const float* __restrict__ bl2,
                       const float* __restrict__ Wl3, const float* __restrict__ bl3,
                       float* __restrict__ out) {
    int b = blockIdx.x;
    int f = threadIdx.x;  // 64
    __shared__ float sh[64];
    float p = 0.f;
#pragma unroll
    for (int q = 0; q < 8; q++) p += partials[((size_t)b * 8 + q) * 64 + f];
    float h = hG[b * 64 + f] + p * (1.f / 256.f);
    sh[f] = h;
    __syncthreads();
    float acc = bl2[f];
#pragma unroll
    for (int k = 0; k < 64; k++) acc = fmaf(sh[k], Wl2[k * 64 + f], acc);
    acc = lrelu(acc, 0.01f);
    float pr = acc * Wl3[f];
#pragma unroll
    for (int off = 32; off > 0; off >>= 1) pr += __shfl_down(pr, off, 64);
    if (f == 0) out[b] = 1.f / (1.f + __expf(-(pr + bl3[0])));
}

extern "C" void kernel_launch(void* const* d_in, const int* in_sizes, int n_in,
                              void* d_out, int out_size, void* d_ws, size_t ws_size,
                              hipStream_t stream) {
    const float* x = (const float*)d_in[0];
    const int* ei = (const int*)d_in[1];
    const float* points = (const float*)d_in[2];
    const float* W1 = (const float*)d_in[3];
    const float* b1 = (const float*)d_in[4];
    const float* W2 = (const float*)d_in[5];
    const float* b2 = (const float*)d_in[6];
    const float* W3 = (const float*)d_in[7];
    const float* b3 = (const float*)d_in[8];
    const float* Wg1 = (const float*)d_in[9];
    const float* asrc1 = (const float*)d_in[10];
    const float* adst1 = (const float*)d_in[11];
    const float* bg1 = (const float*)d_in[12];
    const float* Wg2 = (const float*)d_in[13];
    const float* asrc2 = (const float*)d_in[14];
    const float* adst2 = (const float*)d_in[15];
    const float* bg2 = (const float*)d_in[16];
    const float* c1W = (const float*)d_in[17];
    const float* c1b = (const float*)d_in[18];
    const float* g1 = (const float*)d_in[19];
    const float* be1 = (const float*)d_in[20];
    const float* c2W = (const float*)d_in[21];
    const float* c2b = (const float*)d_in[22];
    const float* g2 = (const float*)d_in[23];
    const float* be2 = (const float*)d_in[24];
    const float* c3W = (const float*)d_in[25];
    const float* c3b = (const float*)d_in[26];
    const float* Wl2 = (const float*)d_in[27];
    const float* bl2 = (const float*)d_in[28];
    const float* Wl3 = (const float*)d_in[29];
    const float* bl3 = (const float*)d_in[30];

    const int* src = ei;
    const int* dst = ei + EE;

    // ---- workspace carve-up ----
    char* w = (char*)d_ws;
    size_t off = 0;
    auto A = [&](size_t bytes) -> void* {
        void* p = w + off;
        off = (off + bytes + 255) & ~(size_t)255;
        return p;
    };
    int* colb = (int*)A((size_t)EE * 4);
    int* rp = (int*)A((size_t)(NN + 1) * 4);
    int* gcnt = (int*)A(NBUCK * 4);
    int* bbase = (int*)A(NBUCK * 4);
    float* dinv = (float*)A((size_t)NN * 4);
    float* bufA = (float*)A((size_t)NN * 64 * 4);
    f16* bufH1 = (f16*)A((size_t)NN * 64 * 2);
    f16* bufH2 = (f16*)A((size_t)NN * 64 * 2);
    f16* ew = (f16*)A((size_t)EE * 2);
    float* wself = (float*)A((size_t)NN * 4);
    float* invden = (float*)A((size_t)NN * 4);
    float* es = (float*)A((size_t)NN * 4);
    float* edv = (float*)A((size_t)NN * 4);
    f16* w3p = (f16*)A(4096 * 2);
    f16* wgp = (f16*)A(4096 * 2);
    float* pooled = (float*)A((size_t)BB * CCROSS * 64 * 4);
    float* xw2 = (float*)A((size_t)BB * CCROSS * 64 * 4);
    float* es2 = (float*)A((size_t)BB * CCROSS * 4);
    float* ed2 = (float*)A((size_t)BB * CCROSS * 4);
    float* crosso = (float*)A((size_t)BB * CCROSS * 64 * 4);
    float* hG = (float*)A((size_t)BB * 64 * 4);
    float* partials = (float*)A((size_t)BB * 8 * 64 * 4);

    unsigned* buckets = (unsigned*)bufA;   // aliases bufA; dead before bufA's reuse below
    f16* aggH = (f16*)bufA;                // agg(z3) fp16 [NN x 64h]; dead before gat output overwrites bufA

    // ---- CSR build (bucketed) ----
    hipMemsetAsync(gcnt, 0, NBUCK * 4, stream);
    bucket_a_k<<<EE / 8192, 256, 0, stream>>>(src, dst, buckets, gcnt);
    bucket_scan_k<<<1, 256, 0, stream>>>(gcnt, bbase, rp);
    bucket_b_k<<<NBUCK, 256, 0, stream>>>(buckets, gcnt, bbase, rp, dinv, colb);

    // ---- points branch + weight packing ----
    conv_fused_k<<<BB * 8, 256, 0, stream>>>(points, c1W, c1b, g1, be1, c2W, c2b, g2, be2, c3W, c3b, partials);
    pack_w_k<<<16, 256, 0, stream>>>(W3, w3p);
    pack_w_k<<<16, 256, 0, stream>>>(Wg1, wgp);

    // ---- GCN 1/2 (fused agg+gemm, wide gather), GCN3+GAT gemm (standalone agg + MFMA compute) ----
    zprep_k<<<NN / 256, 256, 0, stream>>>(x, dinv, bufH1);                               // H1 = z1 [NN x 32h]
    fused_agg_gemm_k<19, 32, 0><<<NN / 64, 256, 0, stream>>>(bufH1, rp, colb, W1, dinv, b1, bufH2);  // H2 = z2
    fused_agg_gemm_k<32, 64, 1><<<NN / 64, 256, 0, stream>>>(bufH2, rp, colb, W2, dinv, b2, bufH1);  // H1 = z3
    agg_h16_k<<<(NN * 8) / 256, 256, 0, stream>>>(bufH1, rp, colb, aggH);                // aggH = agg(z3)
    gemm3_gat_k<<<NN / 64, 256, 0, stream>>>(aggH, w3p, dinv, b3, wgp, asrc1, adst1,
                                             bufH2, es, edv);                            // H2 = xw, es/ed

    // ---- GAT 1 softmax + aggregation ----
    gat_w_k<<<NN / 256, 256, 0, stream>>>(es, edv, rp, colb, ew, wself, invden);
    gat_agg_h_k<<<(NN * 8) / 256, 256, 0, stream>>>(bufH2, rp, colb, ew, wself, invden, bg1, bufA);  // bufA = gat out

    // ---- pool pieces -> cross GAT -> pool cross ----
    pool_pieces_k<<<(BB * CCROSS * 64) / 256, 256, 0, stream>>>(bufA, pooled);
    gat_gemm_k<64, 64><<<(BB * CCROSS) / 256, 256, 0, stream>>>(pooled, Wg2, xw2, asrc2, adst2, es2, ed2, BB * CCROSS);
    cross_att_k<<<(BB * CCROSS * 64) / 256, 256, 0, stream>>>(xw2, es2, ed2, bg2, crosso);
    pool_cross_k<<<BB, 64, 0, stream>>>(crosso, hG);

    // ---- head ----
    head_k<<<BB, 64, 0, stream>>>(hG, partials, Wl2, bl2, Wl3, bl3, (float*)d_out);
}